// Round 1
// baseline (2996.579 us; speedup 1.0000x reference)
//
#include <hip/hip_runtime.h>

constexpr int BB  = 2;
constexpr int TT  = 2048;
constexpr int CC  = 1024;
constexpr int HH  = 16;
constexpr int DHH = 64;
constexpr int HID = 4096;
constexpr int M   = BB * TT;   // 4096 rows

// ---------------- LayerNorm: one block (256 thr) per row, C=1024 ----------------
__global__ __launch_bounds__(256) void ln_kernel(const float* __restrict__ x,
                                                 const float* __restrict__ g,
                                                 const float* __restrict__ b,
                                                 float* __restrict__ y) {
  const int row = blockIdx.x;
  const float4* xr = reinterpret_cast<const float4*>(x + (size_t)row * CC);
  float4* yr = reinterpret_cast<float4*>(y + (size_t)row * CC);
  float4 v = xr[threadIdx.x];
  float s  = v.x + v.y + v.z + v.w;
  float ss = v.x * v.x + v.y * v.y + v.z * v.z + v.w * v.w;
#pragma unroll
  for (int off = 32; off; off >>= 1) {
    s  += __shfl_down(s, off);
    ss += __shfl_down(ss, off);
  }
  __shared__ float red[16];
  const int wid = threadIdx.x >> 6, lane = threadIdx.x & 63;
  if (lane == 0) { red[wid] = s; red[8 + wid] = ss; }
  __syncthreads();
  if (threadIdx.x == 0) {
    red[0] = red[0] + red[1] + red[2] + red[3];
    red[8] = red[8] + red[9] + red[10] + red[11];
  }
  __syncthreads();
  const float mu   = red[0] * (1.0f / CC);
  const float var  = red[8] * (1.0f / CC) - mu * mu;
  const float rstd = rsqrtf(var + 1e-5f);
  float4 gg = reinterpret_cast<const float4*>(g)[threadIdx.x];
  float4 bb = reinterpret_cast<const float4*>(b)[threadIdx.x];
  float4 o;
  o.x = (v.x - mu) * rstd * gg.x + bb.x;
  o.y = (v.y - mu) * rstd * gg.y + bb.y;
  o.z = (v.z - mu) * rstd * gg.z + bb.z;
  o.w = (v.w - mu) * rstd * gg.w + bb.w;
  yr[threadIdx.x] = o;
}

// ---------------- fp32 GEMM: C[M,N] = A[M,K] @ W[K,N] + bias (+res, +relu) ------
// 64x64 tile, BK=16, 256 threads, 4x4 per thread via float4 LDS reads.
template <bool RELU, bool RES>
__global__ __launch_bounds__(256) void gemm_kernel(const float* __restrict__ A,
                                                   const float* __restrict__ W,
                                                   const float* __restrict__ bias,
                                                   const float* __restrict__ res,
                                                   float* __restrict__ Cout,
                                                   int N, int K) {
  __shared__ float As[16][68];
  __shared__ float Ws[16][68];
  const int t  = threadIdx.x;
  const int tx = t & 15, ty = t >> 4;
  const int row0 = blockIdx.y * 64, col0 = blockIdx.x * 64;
  float acc[4][4] = {};

  for (int k0 = 0; k0 < K; k0 += 16) {
    __syncthreads();
    {
      const int kk = t & 15, mm = t >> 4;
#pragma unroll
      for (int i = 0; i < 4; ++i)
        As[kk][mm + 16 * i] = A[(size_t)(row0 + mm + 16 * i) * K + k0 + kk];
      const int kw = t >> 6, nn = t & 63;
#pragma unroll
      for (int i = 0; i < 4; ++i)
        Ws[kw + 4 * i][nn] = W[(size_t)(k0 + kw + 4 * i) * N + col0 + nn];
    }
    __syncthreads();
#pragma unroll
    for (int kk = 0; kk < 16; ++kk) {
      float4 a4 = reinterpret_cast<const float4*>(&As[kk][0])[ty];
      float4 b4 = reinterpret_cast<const float4*>(&Ws[kk][0])[tx];
      const float a[4]  = {a4.x, a4.y, a4.z, a4.w};
      const float bv[4] = {b4.x, b4.y, b4.z, b4.w};
#pragma unroll
      for (int i = 0; i < 4; ++i)
#pragma unroll
        for (int j = 0; j < 4; ++j)
          acc[i][j] += a[i] * bv[j];
    }
  }

  const float4 bias4 = *reinterpret_cast<const float4*>(bias + col0 + tx * 4);
#pragma unroll
  for (int i = 0; i < 4; ++i) {
    const size_t off = (size_t)(row0 + ty * 4 + i) * N + col0 + tx * 4;
    float4 o;
    o.x = acc[i][0] + bias4.x;
    o.y = acc[i][1] + bias4.y;
    o.z = acc[i][2] + bias4.z;
    o.w = acc[i][3] + bias4.w;
    if (RELU) {
      o.x = fmaxf(o.x, 0.f); o.y = fmaxf(o.y, 0.f);
      o.z = fmaxf(o.z, 0.f); o.w = fmaxf(o.w, 0.f);
    }
    if (RES) {
      const float4 r4 = *reinterpret_cast<const float4*>(res + off);
      o.x += r4.x; o.y += r4.y; o.z += r4.z; o.w += r4.w;
    }
    *reinterpret_cast<float4*>(Cout + off) = o;
  }
}

// ---------------- Flash attention, fp32. Block = (b,h,64 queries), 256 thr ------
// Thread t: query row r = t>>2 of the tile, key-group kg = t&3 (16 keys),
// output slice d = kg*16 .. kg*16+15. Online softmax (m,l) shared in each quad.
__global__ __launch_bounds__(256) void attn_kernel(const float* __restrict__ q,
                                                   const float* __restrict__ k,
                                                   const float* __restrict__ v,
                                                   float* __restrict__ o) {
  __shared__ float Qs[64][68];
  __shared__ float Ks[64][68];
  __shared__ float Vs[64][68];
  const int t  = threadIdx.x;
  const int qt = blockIdx.x, h = blockIdx.y, b = blockIdx.z;
  const int r = t >> 2, kg = t & 3;
  const size_t headoff = (size_t)h * DHH;

  // load+scale Q tile (scale 1/sqrt(64) folded in)
#pragma unroll
  for (int i = 0; i < 4; ++i) {
    const int e = t + 256 * i;         // float4 slot id, 64 rows x 16 slots
    const int rr = e >> 4, c4 = e & 15;
    float4 qv = *reinterpret_cast<const float4*>(
        q + (size_t)(b * TT + qt * 64 + rr) * CC + headoff + c4 * 4);
    qv.x *= 0.125f; qv.y *= 0.125f; qv.z *= 0.125f; qv.w *= 0.125f;
    *reinterpret_cast<float4*>(&Qs[rr][c4 * 4]) = qv;
  }

  float m = -1e30f, l = 0.f;
  float o_[16] = {};

  for (int kt = 0; kt < TT / 64; ++kt) {
    __syncthreads();   // protect K/V from previous iteration's readers
#pragma unroll
    for (int i = 0; i < 4; ++i) {
      const int e = t + 256 * i;
      const int rr = e >> 4, c4 = e & 15;
      const size_t goff = (size_t)(b * TT + kt * 64 + rr) * CC + headoff + c4 * 4;
      *reinterpret_cast<float4*>(&Ks[rr][c4 * 4]) = *reinterpret_cast<const float4*>(k + goff);
      *reinterpret_cast<float4*>(&Vs[rr][c4 * 4]) = *reinterpret_cast<const float4*>(v + goff);
    }
    __syncthreads();

    // scores for 16 keys
    float p[16] = {};
#pragma unroll
    for (int d4 = 0; d4 < 16; ++d4) {
      const float4 qv = reinterpret_cast<const float4*>(&Qs[r][0])[d4];
#pragma unroll
      for (int jj = 0; jj < 16; ++jj) {
        const float4 kv = reinterpret_cast<const float4*>(&Ks[kg * 16 + jj][0])[d4];
        p[jj] += qv.x * kv.x + qv.y * kv.y + qv.z * kv.z + qv.w * kv.w;
      }
    }

    // online softmax across the quad
    float tmax = p[0];
#pragma unroll
    for (int jj = 1; jj < 16; ++jj) tmax = fmaxf(tmax, p[jj]);
    tmax = fmaxf(tmax, __shfl_xor(tmax, 1));
    tmax = fmaxf(tmax, __shfl_xor(tmax, 2));
    const float mnew  = fmaxf(m, tmax);
    const float alpha = __expf(m - mnew);
    float lsum = 0.f;
#pragma unroll
    for (int jj = 0; jj < 16; ++jj) {
      p[jj] = __expf(p[jj] - mnew);
      lsum += p[jj];
    }
    lsum += __shfl_xor(lsum, 1);
    lsum += __shfl_xor(lsum, 2);
    l = l * alpha + lsum;
    m = mnew;
#pragma unroll
    for (int i = 0; i < 16; ++i) o_[i] *= alpha;

    // PV: pull quad-mates' p via shuffle, accumulate 16 output dims
    const int lanebase = (t & 63) & ~3;
#pragma unroll
    for (int g = 0; g < 4; ++g) {
#pragma unroll
      for (int jj = 0; jj < 16; ++jj) {
        const float pj = __shfl(p[jj], lanebase + g);
        const float4* vrow = reinterpret_cast<const float4*>(&Vs[g * 16 + jj][0]) + kg * 4;
#pragma unroll
        for (int i = 0; i < 4; ++i) {
          const float4 vv = vrow[i];
          o_[i * 4 + 0] += pj * vv.x;
          o_[i * 4 + 1] += pj * vv.y;
          o_[i * 4 + 2] += pj * vv.z;
          o_[i * 4 + 3] += pj * vv.w;
        }
      }
    }
  }

  const float inv = 1.f / l;
#pragma unroll
  for (int i = 0; i < 4; ++i) {
    float4 ov = {o_[i * 4 + 0] * inv, o_[i * 4 + 1] * inv,
                 o_[i * 4 + 2] * inv, o_[i * 4 + 3] * inv};
    *reinterpret_cast<float4*>(o + (size_t)(b * TT + qt * 64 + r) * CC + headoff +
                               kg * 16 + i * 4) = ov;
  }
}

// --------------------------------- launcher -------------------------------------
extern "C" void kernel_launch(void* const* d_in, const int* in_sizes, int n_in,
                              void* d_out, int out_size, void* d_ws, size_t ws_size,
                              hipStream_t stream) {
  const float* x     = (const float*)d_in[0];
  const float* ln1_g = (const float*)d_in[1];
  const float* ln1_b = (const float*)d_in[2];
  const float* ln2_g = (const float*)d_in[3];
  const float* ln2_b = (const float*)d_in[4];
  const float* Wq = (const float*)d_in[5];
  const float* bq = (const float*)d_in[6];
  const float* Wk = (const float*)d_in[7];
  const float* bk = (const float*)d_in[8];
  const float* Wv = (const float*)d_in[9];
  const float* bv = (const float*)d_in[10];
  const float* Wo = (const float*)d_in[11];
  const float* bo = (const float*)d_in[12];
  const float* W1 = (const float*)d_in[13];
  const float* b1 = (const float*)d_in[14];
  const float* W2 = (const float*)d_in[15];
  const float* b2 = (const float*)d_in[16];
  float* out = (float*)d_out;
  float* ws  = (float*)d_ws;

  const size_t SZ = (size_t)M * CC;    // 4M floats
  float* xn   = ws;                    // LN1 out; later LN2 out
  float* qb   = ws + SZ;
  float* kb   = ws + 2 * SZ;
  float* vb   = ws + 3 * SZ;
  float* attn = ws + 4 * SZ;
  float* x1   = ws + 5 * SZ;           // live to the end
  float* hbuf = ws + SZ;               // MLP hidden (16M floats) reuses q/k/v/attn

  const dim3 blk(256);
  const dim3 gC(CC / 64, M / 64);      // N=1024 GEMMs
  const dim3 gH(HID / 64, M / 64);     // N=4096 GEMM

  ln_kernel<<<M, blk, 0, stream>>>(x, ln1_g, ln1_b, xn);
  gemm_kernel<false, false><<<gC, blk, 0, stream>>>(xn, Wq, bq, nullptr, qb, CC, CC);
  gemm_kernel<false, false><<<gC, blk, 0, stream>>>(xn, Wk, bk, nullptr, kb, CC, CC);
  gemm_kernel<false, false><<<gC, blk, 0, stream>>>(xn, Wv, bv, nullptr, vb, CC, CC);
  attn_kernel<<<dim3(TT / 64, HH, BB), blk, 0, stream>>>(qb, kb, vb, attn);
  gemm_kernel<false, true><<<gC, blk, 0, stream>>>(attn, Wo, bo, x, x1, CC, CC);
  ln_kernel<<<M, blk, 0, stream>>>(x1, ln2_g, ln2_b, xn);
  gemm_kernel<true, false><<<gH, blk, 0, stream>>>(xn, W1, b1, nullptr, hbuf, HID, CC);
  gemm_kernel<false, true><<<gC, blk, 0, stream>>>(hbuf, W2, b2, x1, out, CC, HID);
}

// Round 2
// 342.071 us; speedup vs baseline: 8.7601x; 8.7601x over previous
//
#include <hip/hip_runtime.h>

typedef float f32x4 __attribute__((ext_vector_type(4)));
typedef __bf16 bf16x8 __attribute__((ext_vector_type(8)));

constexpr int TT   = 2048;
constexpr int CC   = 1024;
constexpr int HIDN = 4096;
constexpr int MM   = 4096;   // B*T rows
constexpr int NQKV = 3072;

union U84 { uint32_t u[4]; bf16x8 v; };

__device__ inline uint32_t cvt_pk_bf16(float lo, float hi) {
  uint32_t r;
  asm("v_cvt_pk_bf16_f32 %0, %1, %2" : "=v"(r) : "v"(lo), "v"(hi));
  return r;
}
__device__ inline ushort f2bf(float f) { return (ushort)(cvt_pk_bf16(f, 0.f) & 0xffffu); }
__device__ inline float bfbits2f(uint32_t bits) {  // bits already shifted to f32 position
  union { uint32_t u; float f; } c; c.u = bits; return c.f;
}

#define AS1C(p) ((__attribute__((address_space(1))) void*)(p))
#define AS3(p)  ((__attribute__((address_space(3))) void*)(p))

// ---------------- LayerNorm fp32 -> bf16, one block per row ----------------
__global__ __launch_bounds__(256) void ln_kernel(const float* __restrict__ x,
                                                 const float* __restrict__ g,
                                                 const float* __restrict__ b,
                                                 ushort* __restrict__ y) {
  const int row = blockIdx.x;
  const float4* xr = reinterpret_cast<const float4*>(x + (size_t)row * CC);
  float4 v = xr[threadIdx.x];
  float s  = v.x + v.y + v.z + v.w;
  float ss = v.x * v.x + v.y * v.y + v.z * v.z + v.w * v.w;
#pragma unroll
  for (int off = 32; off; off >>= 1) {
    s  += __shfl_down(s, off);
    ss += __shfl_down(ss, off);
  }
  __shared__ float red[16];
  const int wid = threadIdx.x >> 6, lane = threadIdx.x & 63;
  if (lane == 0) { red[wid] = s; red[8 + wid] = ss; }
  __syncthreads();
  if (threadIdx.x == 0) {
    red[0] = red[0] + red[1] + red[2] + red[3];
    red[8] = red[8] + red[9] + red[10] + red[11];
  }
  __syncthreads();
  const float mu   = red[0] * (1.0f / CC);
  const float var  = red[8] * (1.0f / CC) - mu * mu;
  const float rstd = rsqrtf(var + 1e-5f);
  float4 gg = reinterpret_cast<const float4*>(g)[threadIdx.x];
  float4 bb = reinterpret_cast<const float4*>(b)[threadIdx.x];
  uint2 st;
  st.x = cvt_pk_bf16((v.x - mu) * rstd * gg.x + bb.x, (v.y - mu) * rstd * gg.y + bb.y);
  st.y = cvt_pk_bf16((v.z - mu) * rstd * gg.z + bb.z, (v.w - mu) * rstd * gg.w + bb.w);
  *reinterpret_cast<uint2*>(y + (size_t)row * CC + threadIdx.x * 4) = st;
}

// ---------------- weight transpose+convert: W[K][N] f32 -> out[N][K] bf16 ----------------
__global__ __launch_bounds__(256) void transpose_w(const float* __restrict__ W,
                                                   ushort* __restrict__ out,
                                                   int Kd, int Nd, int rowOff) {
  __shared__ float Ts[32][33];
  const int t = threadIdx.x;
  const int n0 = blockIdx.x * 32, k0 = blockIdx.y * 32;
  {
    const int r = t >> 3, cb = (t & 7) * 4;
    float4 v = *reinterpret_cast<const float4*>(W + (size_t)(k0 + r) * Nd + n0 + cb);
    Ts[r][cb + 0] = v.x; Ts[r][cb + 1] = v.y; Ts[r][cb + 2] = v.z; Ts[r][cb + 3] = v.w;
  }
  __syncthreads();
  {
    const int nl = t >> 3, kb = (t & 7) * 4;
    uint2 st;
    st.x = cvt_pk_bf16(Ts[kb + 0][nl], Ts[kb + 1][nl]);
    st.y = cvt_pk_bf16(Ts[kb + 2][nl], Ts[kb + 3][nl]);
    *reinterpret_cast<uint2*>(out + (size_t)(rowOff + n0 + nl) * Kd + k0 + kb) = st;
  }
}

// ---------------- concat bq|bk|bv -> bqkv[3072] ----------------
__global__ __launch_bounds__(256) void concat_bias(const float* __restrict__ bq,
                                                   const float* __restrict__ bk,
                                                   const float* __restrict__ bv,
                                                   float* __restrict__ out) {
  const int i = blockIdx.x * 256 + threadIdx.x;
  out[i] = (i < 1024) ? bq[i] : ((i < 2048) ? bk[i - 1024] : bv[i - 2048]);
}

// ---------------- V transpose: qkv cols [2048..3071] -> Vt[bh*64+d][T] ----------------
__global__ __launch_bounds__(256) void v_transpose(const ushort* __restrict__ qkv,
                                                   ushort* __restrict__ Vt) {
  __shared__ ushort Ts[64][72];
  const int t = threadIdx.x;
  const int tt = blockIdx.x, bh = blockIdx.y;
  const int b = bh >> 4, h = bh & 15;
#pragma unroll
  for (int c2 = 0; c2 < 2; ++c2) {
    const int e = t + 256 * c2;
    const int r = e >> 3, c = e & 7;
    uint4 raw = *reinterpret_cast<const uint4*>(
        qkv + (size_t)(b * TT + tt * 64 + r) * NQKV + 2048 + h * 64 + c * 8);
    *reinterpret_cast<uint4*>(&Ts[r][c * 8]) = raw;
  }
  __syncthreads();
  const int d = t >> 2, tkb = (t & 3) * 16;
  uint32_t wv[8];
#pragma unroll
  for (int j = 0; j < 8; ++j)
    wv[j] = (uint32_t)Ts[tkb + 2 * j][d] | ((uint32_t)Ts[tkb + 2 * j + 1][d] << 16);
  ushort* op = Vt + (size_t)(bh * 64 + d) * TT + tt * 64 + tkb;
  uint4 s0; s0.x = wv[0]; s0.y = wv[1]; s0.z = wv[2]; s0.w = wv[3];
  uint4 s1; s1.x = wv[4]; s1.y = wv[5]; s1.z = wv[6]; s1.w = wv[7];
  *reinterpret_cast<uint4*>(op) = s0;
  *reinterpret_cast<uint4*>(op + 8) = s1;
}

// ---------------- bf16 MFMA GEMM (m97 structure): C = A[M,K] @ Bt[N,K]^T ----------------
template <bool RELU, bool RES, bool OUTBF>
__global__ __launch_bounds__(256) void gemm_bf16(const ushort* __restrict__ A,
                                                 const ushort* __restrict__ Bt,
                                                 const float* __restrict__ bias,
                                                 const float* __restrict__ res,
                                                 void* __restrict__ outp,
                                                 int N, int K) {
  __shared__ ushort As[128 * 32];
  __shared__ ushort Bs[128 * 32];
  const int t = threadIdx.x;
  const int lane = t & 63, w = t >> 6;
  const int g = lane >> 4, i16 = lane & 15;
  const int wrow = w >> 1, wcol = w & 1;
  const int row0 = blockIdx.y * 128, col0 = blockIdx.x * 128;

  f32x4 acc[4][4] = {};

  const int srow = t >> 2, sc = (t & 3) * 8;   // chunk t: row, bf16-elem offset
  const ushort* aS1 = A + (size_t)(row0 + srow) * K + sc;
  const ushort* aS2 = A + (size_t)(row0 + 64 + srow) * K + sc;
  const ushort* bS1 = Bt + (size_t)(col0 + srow) * K + sc;
  const ushort* bS2 = Bt + (size_t)(col0 + 64 + srow) * K + sc;
  char* aL1 = (char*)As + w * 1024;
  char* aL2 = (char*)As + 4096 + w * 1024;
  char* bL1 = (char*)Bs + w * 1024;
  char* bL2 = (char*)Bs + 4096 + w * 1024;

  for (int k0 = 0; k0 < K; k0 += 32) {
    __syncthreads();
    __builtin_amdgcn_global_load_lds(AS1C(aS1 + k0), AS3(aL1), 16, 0, 0);
    __builtin_amdgcn_global_load_lds(AS1C(aS2 + k0), AS3(aL2), 16, 0, 0);
    __builtin_amdgcn_global_load_lds(AS1C(bS1 + k0), AS3(bL1), 16, 0, 0);
    __builtin_amdgcn_global_load_lds(AS1C(bS2 + k0), AS3(bL2), 16, 0, 0);
    __syncthreads();

    bf16x8 a4[4], b4[4];
#pragma unroll
    for (int mf = 0; mf < 4; ++mf) {
      const int r = wrow * 64 + mf * 16 + i16;
      a4[mf] = *reinterpret_cast<const bf16x8*>((const char*)As + r * 64 + g * 16);
    }
#pragma unroll
    for (int nf = 0; nf < 4; ++nf) {
      const int c = wcol * 64 + nf * 16 + i16;
      b4[nf] = *reinterpret_cast<const bf16x8*>((const char*)Bs + c * 64 + g * 16);
    }
#pragma unroll
    for (int mf = 0; mf < 4; ++mf)
#pragma unroll
      for (int nf = 0; nf < 4; ++nf)
        acc[mf][nf] = __builtin_amdgcn_mfma_f32_16x16x32_bf16(a4[mf], b4[nf], acc[mf][nf], 0, 0, 0);
  }

#pragma unroll
  for (int nf = 0; nf < 4; ++nf) {
    const int ncol = col0 + wcol * 64 + nf * 16 + i16;
    const float bb = bias[ncol];
#pragma unroll
    for (int mf = 0; mf < 4; ++mf) {
      const int mrow = row0 + wrow * 64 + mf * 16 + 4 * g;
#pragma unroll
      for (int r = 0; r < 4; ++r) {
        float v = acc[mf][nf][r] + bb;
        if (RELU) v = fmaxf(v, 0.f);
        const size_t off = (size_t)(mrow + r) * N + ncol;
        if (RES) v += res[off];
        if (OUTBF) ((ushort*)outp)[off] = f2bf(v);
        else       ((float*)outp)[off]  = v;
      }
    }
  }
}

// ---------------- MFMA flash attention (swapped QK^T), 4 waves x 16 queries ----------------
__global__ __launch_bounds__(256) void attn_kernel(const ushort* __restrict__ qkv,
                                                   const ushort* __restrict__ Vt,
                                                   ushort* __restrict__ attnb) {
  __shared__ ushort Ks[64 * 64];
  __shared__ ushort Vs[64 * 64];
  const int t = threadIdx.x, lane = t & 63, w = t >> 6;
  const int g = lane >> 4, iq = lane & 15;
  const int qt = blockIdx.x, bh = blockIdx.y;
  const int b = bh >> 4, h = bh & 15;

  // Q fragments in registers, pre-scaled by 1/sqrt(64)
  bf16x8 qfrag[2];
  {
    const ushort* qrow = qkv + (size_t)(b * TT + qt * 64 + w * 16 + iq) * NQKV + h * 64;
#pragma unroll
    for (int kk = 0; kk < 2; ++kk) {
      uint4 raw = *reinterpret_cast<const uint4*>(qrow + kk * 32 + g * 8);
      uint32_t rr[4] = {raw.x, raw.y, raw.z, raw.w};
      U84 tmp;
#pragma unroll
      for (int c = 0; c < 4; ++c) {
        float lo = bfbits2f(rr[c] << 16) * 0.125f;
        float hi = bfbits2f(rr[c] & 0xffff0000u) * 0.125f;
        tmp.u[c] = cvt_pk_bf16(lo, hi);
      }
      qfrag[kk] = tmp.v;
    }
  }

  // staging geometry (pre-swizzled global source, linear LDS dest)
  const int sr1 = t >> 3, sc1 = t & 7;
  const int csw = (sc1 ^ (sr1 & 7)) * 8;       // same for row+32 (row&7 unchanged)
  char* kL1 = (char*)Ks + w * 1024;
  char* kL2 = (char*)Ks + 4096 + w * 1024;
  char* vL1 = (char*)Vs + w * 1024;
  char* vL2 = (char*)Vs + 4096 + w * 1024;
  const ushort* kbase = qkv + 1024 + h * 64;
  const ushort* vbase = Vt + (size_t)(bh * 64) * TT;

  float mrun = -3e38f, lrun = 0.f;
  f32x4 ot[4] = {};

  for (int kt = 0; kt < TT / 64; ++kt) {
    __syncthreads();
    const size_t tok = (size_t)(b * TT + kt * 64);
    __builtin_amdgcn_global_load_lds(AS1C(kbase + (tok + sr1) * NQKV + csw), AS3(kL1), 16, 0, 0);
    __builtin_amdgcn_global_load_lds(AS1C(kbase + (tok + 32 + sr1) * NQKV + csw), AS3(kL2), 16, 0, 0);
    __builtin_amdgcn_global_load_lds(AS1C(vbase + (size_t)sr1 * TT + kt * 64 + csw), AS3(vL1), 16, 0, 0);
    __builtin_amdgcn_global_load_lds(AS1C(vbase + (size_t)(32 + sr1) * TT + kt * 64 + csw), AS3(vL2), 16, 0, 0);
    __syncthreads();

    // S^T = K @ Q^T : lane holds 16 scores for query iq, keys j = 16f+4g+r
    f32x4 sfr[4] = {};
#pragma unroll
    for (int kk = 0; kk < 2; ++kk)
#pragma unroll
      for (int jf = 0; jf < 4; ++jf) {
        const int row = iq + 16 * jf;
        const int off = row * 128 + ((kk * 64 + g * 16) ^ ((row & 7) << 4));
        bf16x8 a = *reinterpret_cast<const bf16x8*>((const char*)Ks + off);
        sfr[jf] = __builtin_amdgcn_mfma_f32_16x16x32_bf16(a, qfrag[kk], sfr[jf], 0, 0, 0);
      }

    // online softmax over keys (reduce across lanes iq, iq+16, iq+32, iq+48)
    float tmax = -3e38f;
#pragma unroll
    for (int f = 0; f < 4; ++f)
#pragma unroll
      for (int r = 0; r < 4; ++r) tmax = fmaxf(tmax, sfr[f][r]);
    tmax = fmaxf(tmax, __shfl_xor(tmax, 16, 64));
    tmax = fmaxf(tmax, __shfl_xor(tmax, 32, 64));
    const float mnew  = fmaxf(mrun, tmax);
    const float alpha = __expf(mrun - mnew);
    float lsum = 0.f;
    uint32_t u[4][2];
#pragma unroll
    for (int f = 0; f < 4; ++f) {
      float p0 = __expf(sfr[f][0] - mnew);
      float p1 = __expf(sfr[f][1] - mnew);
      float p2 = __expf(sfr[f][2] - mnew);
      float p3 = __expf(sfr[f][3] - mnew);
      lsum += (p0 + p1) + (p2 + p3);
      u[f][0] = cvt_pk_bf16(p0, p1);
      u[f][1] = cvt_pk_bf16(p2, p3);
    }
    lsum += __shfl_xor(lsum, 16, 64);
    lsum += __shfl_xor(lsum, 32, 64);
    lrun = lrun * alpha + lsum;
    mrun = mnew;
#pragma unroll
    for (int df = 0; df < 4; ++df)
#pragma unroll
      for (int r = 0; r < 4; ++r) ot[df][r] *= alpha;

    // PV: O^T = Vt @ P^T ; rebuild B-frag (P[iq][j] k-contiguous) via quad-group shuffles
#pragma unroll
    for (int kk = 0; kk < 2; ++kk) {
      U84 bfr;
#pragma unroll
      for (int q = 0; q < 4; ++q) {
        const int srcl = (2 * (g & 1) + (q >> 1)) * 16 + iq;
        const uint32_t v0 = (uint32_t)__shfl((int)u[2 * kk + 0][q & 1], srcl, 64);
        const uint32_t v1 = (uint32_t)__shfl((int)u[2 * kk + 1][q & 1], srcl, 64);
        bfr.u[q] = (g & 2) ? v1 : v0;
      }
#pragma unroll
      for (int df = 0; df < 4; ++df) {
        const int row = iq + 16 * df;
        const int off = row * 128 + ((kk * 64 + g * 16) ^ ((row & 7) << 4));
        bf16x8 a = *reinterpret_cast<const bf16x8*>((const char*)Vs + off);
        ot[df] = __builtin_amdgcn_mfma_f32_16x16x32_bf16(a, bfr.v, ot[df], 0, 0, 0);
      }
    }
  }

  const float inv = 1.f / lrun;
  ushort* orow = attnb + (size_t)(b * TT + qt * 64 + w * 16 + iq) * CC + h * 64;
#pragma unroll
  for (int df = 0; df < 4; ++df) {
    uint2 st;
    st.x = cvt_pk_bf16(ot[df][0] * inv, ot[df][1] * inv);
    st.y = cvt_pk_bf16(ot[df][2] * inv, ot[df][3] * inv);
    *reinterpret_cast<uint2*>(orow + df * 16 + g * 4) = st;
  }
}

// --------------------------------- launcher -------------------------------------
extern "C" void kernel_launch(void* const* d_in, const int* in_sizes, int n_in,
                              void* d_out, int out_size, void* d_ws, size_t ws_size,
                              hipStream_t stream) {
  const float* x     = (const float*)d_in[0];
  const float* ln1_g = (const float*)d_in[1];
  const float* ln1_b = (const float*)d_in[2];
  const float* ln2_g = (const float*)d_in[3];
  const float* ln2_b = (const float*)d_in[4];
  const float* Wq = (const float*)d_in[5];
  const float* bq = (const float*)d_in[6];
  const float* Wk = (const float*)d_in[7];
  const float* bk = (const float*)d_in[8];
  const float* Wv = (const float*)d_in[9];
  const float* bv = (const float*)d_in[10];
  const float* Wo = (const float*)d_in[11];
  const float* bo = (const float*)d_in[12];
  const float* W1 = (const float*)d_in[13];
  const float* b1 = (const float*)d_in[14];
  const float* W2 = (const float*)d_in[15];
  const float* b2 = (const float*)d_in[16];
  float* out = (float*)d_out;
  char* ws = (char*)d_ws;

  // byte offsets in workspace (total ~92.3 MB)
  ushort* WqkvT = (ushort*)(ws + 0);          // 3072x1024 bf16
  ushort* WoT   = (ushort*)(ws + 6291456);    // 1024x1024 bf16
  ushort* W1T   = (ushort*)(ws + 8388608);    // 4096x1024 bf16
  ushort* W2T   = (ushort*)(ws + 16777216);   // 1024x4096 bf16
  float*  Bqkv  = (float*) (ws + 25165824);   // 3072 f32
  ushort* Xn    = (ushort*)(ws + 25178112);   // 4096x1024 bf16
  float*  X1f   = (float*) (ws + 33566720);   // 4096x1024 f32
  ushort* Attn  = (ushort*)(ws + 50343936);   // 4096x1024 bf16
  ushort* Qkv   = (ushort*)(ws + 58732544);   // 4096x3072 bf16
  ushort* Vtb   = (ushort*)(ws + 83898368);   // 2*16*64 x 2048 bf16
  ushort* Hid   = (ushort*)(ws + 58732544);   // 4096x4096 bf16 (reuses Qkv+Vtb)

  const dim3 blk(256);

  transpose_w<<<dim3(32, 32), blk, 0, stream>>>(Wq, WqkvT, 1024, 1024, 0);
  transpose_w<<<dim3(32, 32), blk, 0, stream>>>(Wk, WqkvT, 1024, 1024, 1024);
  transpose_w<<<dim3(32, 32), blk, 0, stream>>>(Wv, WqkvT, 1024, 1024, 2048);
  transpose_w<<<dim3(32, 32), blk, 0, stream>>>(Wo, WoT, 1024, 1024, 0);
  transpose_w<<<dim3(128, 32), blk, 0, stream>>>(W1, W1T, 1024, 4096, 0);
  transpose_w<<<dim3(32, 128), blk, 0, stream>>>(W2, W2T, 4096, 1024, 0);
  concat_bias<<<dim3(12), blk, 0, stream>>>(bq, bk, bv, Bqkv);

  ln_kernel<<<dim3(MM), blk, 0, stream>>>(x, ln1_g, ln1_b, Xn);
  gemm_bf16<false, false, true><<<dim3(24, 32), blk, 0, stream>>>(Xn, WqkvT, Bqkv, nullptr, Qkv, NQKV, 1024);
  v_transpose<<<dim3(32, 32), blk, 0, stream>>>(Qkv, Vtb);
  attn_kernel<<<dim3(32, 32), blk, 0, stream>>>(Qkv, Vtb, Attn);
  gemm_bf16<false, true, false><<<dim3(8, 32), blk, 0, stream>>>(Attn, WoT, bo, x, X1f, 1024, 1024);
  ln_kernel<<<dim3(MM), blk, 0, stream>>>(X1f, ln2_g, ln2_b, Xn);
  gemm_bf16<true, false, true><<<dim3(32, 32), blk, 0, stream>>>(Xn, W1T, b1, nullptr, Hid, HIDN, 1024);
  gemm_bf16<false, true, false><<<dim3(8, 32), blk, 0, stream>>>(Hid, W2T, b2, X1f, out, 1024, HIDN);
}

// Round 3
// 319.289 us; speedup vs baseline: 9.3852x; 1.0714x over previous
//
#include <hip/hip_runtime.h>

typedef float f32x4 __attribute__((ext_vector_type(4)));
typedef __bf16 bf16x8 __attribute__((ext_vector_type(8)));

constexpr int TT   = 2048;
constexpr int CC   = 1024;
constexpr int HIDN = 4096;
constexpr int MM   = 4096;   // B*T rows
constexpr int NQKV = 3072;

union U84 { uint32_t u[4]; bf16x8 v; };

__device__ inline uint32_t cvt_pk_bf16(float lo, float hi) {
  uint32_t r;
  asm("v_cvt_pk_bf16_f32 %0, %1, %2" : "=v"(r) : "v"(lo), "v"(hi));
  return r;
}
__device__ inline ushort f2bf(float f) { return (ushort)(cvt_pk_bf16(f, 0.f) & 0xffffu); }
__device__ inline float bfbits2f(uint32_t bits) {
  union { uint32_t u; float f; } c; c.u = bits; return c.f;
}

#define AS1C(p) ((__attribute__((address_space(1))) void*)(p))
#define AS3(p)  ((__attribute__((address_space(3))) void*)(p))

// ---------------- LayerNorm fp32 -> bf16, one block per row ----------------
__global__ __launch_bounds__(256) void ln_kernel(const float* __restrict__ x,
                                                 const float* __restrict__ g,
                                                 const float* __restrict__ b,
                                                 ushort* __restrict__ y) {
  const int row = blockIdx.x;
  const float4* xr = reinterpret_cast<const float4*>(x + (size_t)row * CC);
  float4 v = xr[threadIdx.x];
  float s  = v.x + v.y + v.z + v.w;
  float ss = v.x * v.x + v.y * v.y + v.z * v.z + v.w * v.w;
#pragma unroll
  for (int off = 32; off; off >>= 1) {
    s  += __shfl_down(s, off);
    ss += __shfl_down(ss, off);
  }
  __shared__ float red[16];
  const int wid = threadIdx.x >> 6, lane = threadIdx.x & 63;
  if (lane == 0) { red[wid] = s; red[8 + wid] = ss; }
  __syncthreads();
  if (threadIdx.x == 0) {
    red[0] = red[0] + red[1] + red[2] + red[3];
    red[8] = red[8] + red[9] + red[10] + red[11];
  }
  __syncthreads();
  const float mu   = red[0] * (1.0f / CC);
  const float var  = red[8] * (1.0f / CC) - mu * mu;
  const float rstd = rsqrtf(var + 1e-5f);
  float4 gg = reinterpret_cast<const float4*>(g)[threadIdx.x];
  float4 bb = reinterpret_cast<const float4*>(b)[threadIdx.x];
  uint2 st;
  st.x = cvt_pk_bf16((v.x - mu) * rstd * gg.x + bb.x, (v.y - mu) * rstd * gg.y + bb.y);
  st.y = cvt_pk_bf16((v.z - mu) * rstd * gg.z + bb.z, (v.w - mu) * rstd * gg.w + bb.w);
  *reinterpret_cast<uint2*>(y + (size_t)row * CC + threadIdx.x * 4) = st;
}

// ---------------- weight transpose+convert: W[K][N] f32 -> out[N][K] bf16 ----------------
__global__ __launch_bounds__(256) void transpose_w(const float* __restrict__ W,
                                                   ushort* __restrict__ out,
                                                   int Kd, int Nd, int rowOff) {
  __shared__ float Ts[32][33];
  const int t = threadIdx.x;
  const int n0 = blockIdx.x * 32, k0 = blockIdx.y * 32;
  {
    const int r = t >> 3, cb = (t & 7) * 4;
    float4 v = *reinterpret_cast<const float4*>(W + (size_t)(k0 + r) * Nd + n0 + cb);
    Ts[r][cb + 0] = v.x; Ts[r][cb + 1] = v.y; Ts[r][cb + 2] = v.z; Ts[r][cb + 3] = v.w;
  }
  __syncthreads();
  {
    const int nl = t >> 3, kb = (t & 7) * 4;
    uint2 st;
    st.x = cvt_pk_bf16(Ts[kb + 0][nl], Ts[kb + 1][nl]);
    st.y = cvt_pk_bf16(Ts[kb + 2][nl], Ts[kb + 3][nl]);
    *reinterpret_cast<uint2*>(out + (size_t)(rowOff + n0 + nl) * Kd + k0 + kb) = st;
  }
}

// ---------------- concat bq|bk|bv -> bqkv[3072] ----------------
__global__ __launch_bounds__(256) void concat_bias(const float* __restrict__ bq,
                                                   const float* __restrict__ bk,
                                                   const float* __restrict__ bv,
                                                   float* __restrict__ out) {
  const int i = blockIdx.x * 256 + threadIdx.x;
  out[i] = (i < 1024) ? bq[i] : ((i < 2048) ? bk[i - 1024] : bv[i - 2048]);
}

// ---------------- V transpose: qkv cols [2048..3071] -> Vt[bh*64+d][T] ----------------
__global__ __launch_bounds__(256) void v_transpose(const ushort* __restrict__ qkv,
                                                   ushort* __restrict__ Vt) {
  __shared__ ushort Ts[64][72];
  const int t = threadIdx.x;
  const int tt = blockIdx.x, bh = blockIdx.y;
  const int b = bh >> 4, h = bh & 15;
#pragma unroll
  for (int c2 = 0; c2 < 2; ++c2) {
    const int e = t + 256 * c2;
    const int r = e >> 3, c = e & 7;
    uint4 raw = *reinterpret_cast<const uint4*>(
        qkv + (size_t)(b * TT + tt * 64 + r) * NQKV + 2048 + h * 64 + c * 8);
    *reinterpret_cast<uint4*>(&Ts[r][c * 8]) = raw;
  }
  __syncthreads();
  const int d = t >> 2, tkb = (t & 3) * 16;
  uint32_t wv[8];
#pragma unroll
  for (int j = 0; j < 8; ++j)
    wv[j] = (uint32_t)Ts[tkb + 2 * j][d] | ((uint32_t)Ts[tkb + 2 * j + 1][d] << 16);
  ushort* op = Vt + (size_t)(bh * 64 + d) * TT + tt * 64 + tkb;
  uint4 s0; s0.x = wv[0]; s0.y = wv[1]; s0.z = wv[2]; s0.w = wv[3];
  uint4 s1; s1.x = wv[4]; s1.y = wv[5]; s1.z = wv[6]; s1.w = wv[7];
  *reinterpret_cast<uint4*>(op) = s0;
  *reinterpret_cast<uint4*>(op + 8) = s1;
}

// ---------------- bf16 MFMA GEMM (m97 structure): C = A[M,K] @ Bt[N,K]^T ----------------
template <bool RELU, bool RES, bool OUTBF>
__global__ __launch_bounds__(256) void gemm_bf16(const ushort* __restrict__ A,
                                                 const ushort* __restrict__ Bt,
                                                 const float* __restrict__ bias,
                                                 const float* __restrict__ res,
                                                 void* __restrict__ outp,
                                                 int N, int K) {
  __shared__ ushort As[128 * 32];
  __shared__ ushort Bs[128 * 32];
  const int t = threadIdx.x;
  const int lane = t & 63, w = t >> 6;
  const int g = lane >> 4, i16 = lane & 15;
  const int wrow = w >> 1, wcol = w & 1;
  // bijective XCD swizzle (all grids have nwg % 8 == 0)
  const int nwg  = gridDim.x * gridDim.y;
  const int orig = blockIdx.y * gridDim.x + blockIdx.x;
  const int sw   = (orig & 7) * (nwg >> 3) + (orig >> 3);
  const int row0 = (sw / gridDim.x) * 128, col0 = (sw % gridDim.x) * 128;

  f32x4 acc[4][4] = {};

  const int srow = t >> 2, sc = (t & 3) * 8;
  const ushort* aS1 = A + (size_t)(row0 + srow) * K + sc;
  const ushort* aS2 = A + (size_t)(row0 + 64 + srow) * K + sc;
  const ushort* bS1 = Bt + (size_t)(col0 + srow) * K + sc;
  const ushort* bS2 = Bt + (size_t)(col0 + 64 + srow) * K + sc;
  char* aL1 = (char*)As + w * 1024;
  char* aL2 = (char*)As + 4096 + w * 1024;
  char* bL1 = (char*)Bs + w * 1024;
  char* bL2 = (char*)Bs + 4096 + w * 1024;

  for (int k0 = 0; k0 < K; k0 += 32) {
    __syncthreads();
    __builtin_amdgcn_global_load_lds(AS1C(aS1 + k0), AS3(aL1), 16, 0, 0);
    __builtin_amdgcn_global_load_lds(AS1C(aS2 + k0), AS3(aL2), 16, 0, 0);
    __builtin_amdgcn_global_load_lds(AS1C(bS1 + k0), AS3(bL1), 16, 0, 0);
    __builtin_amdgcn_global_load_lds(AS1C(bS2 + k0), AS3(bL2), 16, 0, 0);
    __syncthreads();

    bf16x8 a4[4], b4[4];
#pragma unroll
    for (int mf = 0; mf < 4; ++mf) {
      const int r = wrow * 64 + mf * 16 + i16;
      a4[mf] = *reinterpret_cast<const bf16x8*>((const char*)As + r * 64 + g * 16);
    }
#pragma unroll
    for (int nf = 0; nf < 4; ++nf) {
      const int c = wcol * 64 + nf * 16 + i16;
      b4[nf] = *reinterpret_cast<const bf16x8*>((const char*)Bs + c * 64 + g * 16);
    }
#pragma unroll
    for (int mf = 0; mf < 4; ++mf)
#pragma unroll
      for (int nf = 0; nf < 4; ++nf)
        acc[mf][nf] = __builtin_amdgcn_mfma_f32_16x16x32_bf16(a4[mf], b4[nf], acc[mf][nf], 0, 0, 0);
  }

#pragma unroll
  for (int nf = 0; nf < 4; ++nf) {
    const int ncol = col0 + wcol * 64 + nf * 16 + i16;
    const float bb = bias[ncol];
#pragma unroll
    for (int mf = 0; mf < 4; ++mf) {
      const int mrow = row0 + wrow * 64 + mf * 16 + 4 * g;
#pragma unroll
      for (int r = 0; r < 4; ++r) {
        float v = acc[mf][nf][r] + bb;
        if (RELU) v = fmaxf(v, 0.f);
        const size_t off = (size_t)(mrow + r) * N + ncol;
        if (RES) v += res[off];
        if (OUTBF) ((ushort*)outp)[off] = f2bf(v);
        else       ((float*)outp)[off]  = v;
      }
    }
  }
}

// ---------------- split-K (2-way) bf16 MFMA GEMM, raw f32 partials ----------------
__global__ __launch_bounds__(256) void gemm_splitk(const ushort* __restrict__ A,
                                                   const ushort* __restrict__ Bt,
                                                   float* __restrict__ P0,
                                                   float* __restrict__ P1,
                                                   int N, int K, int Kchunk) {
  __shared__ ushort As[128 * 32];
  __shared__ ushort Bs[128 * 32];
  const int t = threadIdx.x;
  const int lane = t & 63, w = t >> 6;
  const int g = lane >> 4, i16 = lane & 15;
  const int wrow = w >> 1, wcol = w & 1;
  const int nwg  = gridDim.x * gridDim.y;
  const int orig = blockIdx.y * gridDim.x + blockIdx.x;
  const int sw   = (orig & 7) * (nwg >> 3) + (orig >> 3);
  const int row0 = (sw / gridDim.x) * 128, col0 = (sw % gridDim.x) * 128;
  const int kstart = blockIdx.z * Kchunk;
  float* __restrict__ P = blockIdx.z ? P1 : P0;

  f32x4 acc[4][4] = {};

  const int srow = t >> 2, sc = (t & 3) * 8;
  const ushort* aS1 = A + (size_t)(row0 + srow) * K + sc;
  const ushort* aS2 = A + (size_t)(row0 + 64 + srow) * K + sc;
  const ushort* bS1 = Bt + (size_t)(col0 + srow) * K + sc;
  const ushort* bS2 = Bt + (size_t)(col0 + 64 + srow) * K + sc;
  char* aL1 = (char*)As + w * 1024;
  char* aL2 = (char*)As + 4096 + w * 1024;
  char* bL1 = (char*)Bs + w * 1024;
  char* bL2 = (char*)Bs + 4096 + w * 1024;

  for (int k0 = kstart; k0 < kstart + Kchunk; k0 += 32) {
    __syncthreads();
    __builtin_amdgcn_global_load_lds(AS1C(aS1 + k0), AS3(aL1), 16, 0, 0);
    __builtin_amdgcn_global_load_lds(AS1C(aS2 + k0), AS3(aL2), 16, 0, 0);
    __builtin_amdgcn_global_load_lds(AS1C(bS1 + k0), AS3(bL1), 16, 0, 0);
    __builtin_amdgcn_global_load_lds(AS1C(bS2 + k0), AS3(bL2), 16, 0, 0);
    __syncthreads();

    bf16x8 a4[4], b4[4];
#pragma unroll
    for (int mf = 0; mf < 4; ++mf) {
      const int r = wrow * 64 + mf * 16 + i16;
      a4[mf] = *reinterpret_cast<const bf16x8*>((const char*)As + r * 64 + g * 16);
    }
#pragma unroll
    for (int nf = 0; nf < 4; ++nf) {
      const int c = wcol * 64 + nf * 16 + i16;
      b4[nf] = *reinterpret_cast<const bf16x8*>((const char*)Bs + c * 64 + g * 16);
    }
#pragma unroll
    for (int mf = 0; mf < 4; ++mf)
#pragma unroll
      for (int nf = 0; nf < 4; ++nf)
        acc[mf][nf] = __builtin_amdgcn_mfma_f32_16x16x32_bf16(a4[mf], b4[nf], acc[mf][nf], 0, 0, 0);
  }

#pragma unroll
  for (int nf = 0; nf < 4; ++nf) {
    const int ncol = col0 + wcol * 64 + nf * 16 + i16;
#pragma unroll
    for (int mf = 0; mf < 4; ++mf) {
      const int mrow = row0 + wrow * 64 + mf * 16 + 4 * g;
#pragma unroll
      for (int r = 0; r < 4; ++r)
        P[(size_t)(mrow + r) * N + ncol] = acc[mf][nf][r];
    }
  }
}

// ---------------- Wo reduce + residual + LN2 fused: one block per row ----------------
__global__ __launch_bounds__(256) void reduce_wo_ln(const float* __restrict__ P0,
                                                    const float* __restrict__ P1,
                                                    const float* __restrict__ x,
                                                    const float* __restrict__ bo,
                                                    const float* __restrict__ g,
                                                    const float* __restrict__ b,
                                                    float* __restrict__ X1f,
                                                    ushort* __restrict__ Xn) {
  const int row = blockIdx.x, t = threadIdx.x;
  const size_t off = (size_t)row * CC + t * 4;
  float4 v  = *reinterpret_cast<const float4*>(x + off);
  float4 p0 = *reinterpret_cast<const float4*>(P0 + off);
  float4 p1 = *reinterpret_cast<const float4*>(P1 + off);
  float4 bb = reinterpret_cast<const float4*>(bo)[t];
  v.x += p0.x + p1.x + bb.x;
  v.y += p0.y + p1.y + bb.y;
  v.z += p0.z + p1.z + bb.z;
  v.w += p0.w + p1.w + bb.w;
  *reinterpret_cast<float4*>(X1f + off) = v;

  float s  = v.x + v.y + v.z + v.w;
  float ss = v.x * v.x + v.y * v.y + v.z * v.z + v.w * v.w;
#pragma unroll
  for (int o = 32; o; o >>= 1) {
    s  += __shfl_down(s, o);
    ss += __shfl_down(ss, o);
  }
  __shared__ float red[16];
  const int wid = t >> 6, lane = t & 63;
  if (lane == 0) { red[wid] = s; red[8 + wid] = ss; }
  __syncthreads();
  if (t == 0) {
    red[0] = red[0] + red[1] + red[2] + red[3];
    red[8] = red[8] + red[9] + red[10] + red[11];
  }
  __syncthreads();
  const float mu   = red[0] * (1.0f / CC);
  const float var  = red[8] * (1.0f / CC) - mu * mu;
  const float rstd = rsqrtf(var + 1e-5f);
  float4 gg = reinterpret_cast<const float4*>(g)[t];
  float4 lb = reinterpret_cast<const float4*>(b)[t];
  uint2 st;
  st.x = cvt_pk_bf16((v.x - mu) * rstd * gg.x + lb.x, (v.y - mu) * rstd * gg.y + lb.y);
  st.y = cvt_pk_bf16((v.z - mu) * rstd * gg.z + lb.z, (v.w - mu) * rstd * gg.w + lb.w);
  *reinterpret_cast<uint2*>(Xn + off) = st;
}

// ---------------- FC2 reduce + bias + residual -> final out ----------------
__global__ __launch_bounds__(256) void reduce_fc2(const float* __restrict__ P0,
                                                  const float* __restrict__ P1,
                                                  const float* __restrict__ X1,
                                                  const float* __restrict__ b2,
                                                  float* __restrict__ out) {
  const int row = blockIdx.x, t = threadIdx.x;
  const size_t off = (size_t)row * CC + t * 4;
  float4 v  = *reinterpret_cast<const float4*>(X1 + off);
  float4 p0 = *reinterpret_cast<const float4*>(P0 + off);
  float4 p1 = *reinterpret_cast<const float4*>(P1 + off);
  float4 bb = reinterpret_cast<const float4*>(b2)[t];
  v.x += p0.x + p1.x + bb.x;
  v.y += p0.y + p1.y + bb.y;
  v.z += p0.z + p1.z + bb.z;
  v.w += p0.w + p1.w + bb.w;
  *reinterpret_cast<float4*>(out + off) = v;
}

// ---------------- MFMA flash attention (swapped QK^T), 4 waves x 16 queries ----------------
__global__ __launch_bounds__(256) void attn_kernel(const ushort* __restrict__ qkv,
                                                   const ushort* __restrict__ Vt,
                                                   ushort* __restrict__ attnb) {
  __shared__ ushort Ks[64 * 64];
  __shared__ ushort Vs[64 * 64];
  const int t = threadIdx.x, lane = t & 63, w = t >> 6;
  const int g = lane >> 4, iq = lane & 15;
  const int qt = blockIdx.x, bh = blockIdx.y;
  const int b = bh >> 4, h = bh & 15;

  bf16x8 qfrag[2];
  {
    const ushort* qrow = qkv + (size_t)(b * TT + qt * 64 + w * 16 + iq) * NQKV + h * 64;
#pragma unroll
    for (int kk = 0; kk < 2; ++kk) {
      uint4 raw = *reinterpret_cast<const uint4*>(qrow + kk * 32 + g * 8);
      uint32_t rr[4] = {raw.x, raw.y, raw.z, raw.w};
      U84 tmp;
#pragma unroll
      for (int c = 0; c < 4; ++c) {
        float lo = bfbits2f(rr[c] << 16) * 0.125f;
        float hi = bfbits2f(rr[c] & 0xffff0000u) * 0.125f;
        tmp.u[c] = cvt_pk_bf16(lo, hi);
      }
      qfrag[kk] = tmp.v;
    }
  }

  const int sr1 = t >> 3, sc1 = t & 7;
  const int csw = (sc1 ^ (sr1 & 7)) * 8;
  char* kL1 = (char*)Ks + w * 1024;
  char* kL2 = (char*)Ks + 4096 + w * 1024;
  char* vL1 = (char*)Vs + w * 1024;
  char* vL2 = (char*)Vs + 4096 + w * 1024;
  const ushort* kbase = qkv + 1024 + h * 64;
  const ushort* vbase = Vt + (size_t)(bh * 64) * TT;

  float mrun = -3e38f, lrun = 0.f;
  f32x4 ot[4] = {};

  for (int kt = 0; kt < TT / 64; ++kt) {
    __syncthreads();
    const size_t tok = (size_t)(b * TT + kt * 64);
    __builtin_amdgcn_global_load_lds(AS1C(kbase + (tok + sr1) * NQKV + csw), AS3(kL1), 16, 0, 0);
    __builtin_amdgcn_global_load_lds(AS1C(kbase + (tok + 32 + sr1) * NQKV + csw), AS3(kL2), 16, 0, 0);
    __builtin_amdgcn_global_load_lds(AS1C(vbase + (size_t)sr1 * TT + kt * 64 + csw), AS3(vL1), 16, 0, 0);
    __builtin_amdgcn_global_load_lds(AS1C(vbase + (size_t)(32 + sr1) * TT + kt * 64 + csw), AS3(vL2), 16, 0, 0);
    __syncthreads();

    f32x4 sfr[4] = {};
#pragma unroll
    for (int kk = 0; kk < 2; ++kk)
#pragma unroll
      for (int jf = 0; jf < 4; ++jf) {
        const int row = iq + 16 * jf;
        const int off = row * 128 + ((kk * 64 + g * 16) ^ ((row & 7) << 4));
        bf16x8 a = *reinterpret_cast<const bf16x8*>((const char*)Ks + off);
        sfr[jf] = __builtin_amdgcn_mfma_f32_16x16x32_bf16(a, qfrag[kk], sfr[jf], 0, 0, 0);
      }

    float tmax = -3e38f;
#pragma unroll
    for (int f = 0; f < 4; ++f)
#pragma unroll
      for (int r = 0; r < 4; ++r) tmax = fmaxf(tmax, sfr[f][r]);
    tmax = fmaxf(tmax, __shfl_xor(tmax, 16, 64));
    tmax = fmaxf(tmax, __shfl_xor(tmax, 32, 64));
    const float mnew  = fmaxf(mrun, tmax);
    const float alpha = __expf(mrun - mnew);
    float lsum = 0.f;
    uint32_t u[4][2];
#pragma unroll
    for (int f = 0; f < 4; ++f) {
      float p0 = __expf(sfr[f][0] - mnew);
      float p1 = __expf(sfr[f][1] - mnew);
      float p2 = __expf(sfr[f][2] - mnew);
      float p3 = __expf(sfr[f][3] - mnew);
      lsum += (p0 + p1) + (p2 + p3);
      u[f][0] = cvt_pk_bf16(p0, p1);
      u[f][1] = cvt_pk_bf16(p2, p3);
    }
    lsum += __shfl_xor(lsum, 16, 64);
    lsum += __shfl_xor(lsum, 32, 64);
    lrun = lrun * alpha + lsum;
    mrun = mnew;
#pragma unroll
    for (int df = 0; df < 4; ++df)
#pragma unroll
      for (int r = 0; r < 4; ++r) ot[df][r] *= alpha;

#pragma unroll
    for (int kk = 0; kk < 2; ++kk) {
      U84 bfr;
#pragma unroll
      for (int q = 0; q < 4; ++q) {
        const int srcl = (2 * (g & 1) + (q >> 1)) * 16 + iq;
        const uint32_t v0 = (uint32_t)__shfl((int)u[2 * kk + 0][q & 1], srcl, 64);
        const uint32_t v1 = (uint32_t)__shfl((int)u[2 * kk + 1][q & 1], srcl, 64);
        bfr.u[q] = (g & 2) ? v1 : v0;
      }
#pragma unroll
      for (int df = 0; df < 4; ++df) {
        const int row = iq + 16 * df;
        const int off = row * 128 + ((kk * 64 + g * 16) ^ ((row & 7) << 4));
        bf16x8 a = *reinterpret_cast<const bf16x8*>((const char*)Vs + off);
        ot[df] = __builtin_amdgcn_mfma_f32_16x16x32_bf16(a, bfr.v, ot[df], 0, 0, 0);
      }
    }
  }

  const float inv = 1.f / lrun;
  ushort* orow = attnb + (size_t)(b * TT + qt * 64 + w * 16 + iq) * CC + h * 64;
#pragma unroll
  for (int df = 0; df < 4; ++df) {
    uint2 st;
    st.x = cvt_pk_bf16(ot[df][0] * inv, ot[df][1] * inv);
    st.y = cvt_pk_bf16(ot[df][2] * inv, ot[df][3] * inv);
    *reinterpret_cast<uint2*>(orow + df * 16 + g * 4) = st;
  }
}

// --------------------------------- launcher -------------------------------------
extern "C" void kernel_launch(void* const* d_in, const int* in_sizes, int n_in,
                              void* d_out, int out_size, void* d_ws, size_t ws_size,
                              hipStream_t stream) {
  const float* x     = (const float*)d_in[0];
  const float* ln1_g = (const float*)d_in[1];
  const float* ln1_b = (const float*)d_in[2];
  const float* ln2_g = (const float*)d_in[3];
  const float* ln2_b = (const float*)d_in[4];
  const float* Wq = (const float*)d_in[5];
  const float* bq = (const float*)d_in[6];
  const float* Wk = (const float*)d_in[7];
  const float* bk = (const float*)d_in[8];
  const float* Wv = (const float*)d_in[9];
  const float* bv = (const float*)d_in[10];
  const float* Wo = (const float*)d_in[11];
  const float* bo = (const float*)d_in[12];
  const float* W1 = (const float*)d_in[13];
  const float* b1 = (const float*)d_in[14];
  const float* W2 = (const float*)d_in[15];
  const float* b2 = (const float*)d_in[16];
  float* out = (float*)d_out;
  char* ws = (char*)d_ws;

  // workspace layout (92.3 MB total, same footprint as the passing round)
  ushort* WqkvT = (ushort*)(ws + 0);          // 3072x1024 bf16 (6 MB)
  ushort* WoT   = (ushort*)(ws + 6291456);    // 1024x1024 bf16 (2 MB)
  ushort* W1T   = (ushort*)(ws + 8388608);    // 4096x1024 bf16 (8 MB)
  ushort* W2T   = (ushort*)(ws + 16777216);   // 1024x4096 bf16 (8 MB)
  float*  Bqkv  = (float*) (ws + 25165824);   // 3072 f32
  ushort* Xn    = (ushort*)(ws + 25178112);   // 4096x1024 bf16 (8 MB)
  ushort* Attn  = (ushort*)(ws + 33566720);   // 4096x1024 bf16 (8 MB)
  float*  X1f   = (float*) (ws + 41955328);   // 4096x1024 f32 (16 MB)
  ushort* Qkv   = (ushort*)(ws + 58732544);   // 4096x3072 bf16 (24 MB)
  ushort* Vtb   = (ushort*)(ws + 83898368);   // 2048x2048 bf16 (8 MB)
  ushort* Hid   = (ushort*)(ws + 58732544);   // 4096x4096 bf16 (reuses Qkv+Vtb)
  // Wo split-K partials: reuse Qkv+Vtb region (dead after attn, before FC1/Hid)
  float* WoP0  = (float*)(ws + 58732544);     // 16 MB
  float* WoP1  = (float*)(ws + 75509760);     // 16 MB
  // FC2 split-K partials: reuse WqkvT+WoT+W1T (16 MB) and Xn+Attn (16 MB)
  float* F2P0  = (float*)(ws + 0);
  float* F2P1  = (float*)(ws + 25178112);

  const dim3 blk(256);

  transpose_w<<<dim3(32, 32), blk, 0, stream>>>(Wq, WqkvT, 1024, 1024, 0);
  transpose_w<<<dim3(32, 32), blk, 0, stream>>>(Wk, WqkvT, 1024, 1024, 1024);
  transpose_w<<<dim3(32, 32), blk, 0, stream>>>(Wv, WqkvT, 1024, 1024, 2048);
  transpose_w<<<dim3(32, 32), blk, 0, stream>>>(Wo, WoT, 1024, 1024, 0);
  transpose_w<<<dim3(128, 32), blk, 0, stream>>>(W1, W1T, 1024, 4096, 0);
  transpose_w<<<dim3(32, 128), blk, 0, stream>>>(W2, W2T, 4096, 1024, 0);
  concat_bias<<<dim3(12), blk, 0, stream>>>(bq, bk, bv, Bqkv);

  ln_kernel<<<dim3(MM), blk, 0, stream>>>(x, ln1_g, ln1_b, Xn);
  gemm_bf16<false, false, true><<<dim3(24, 32), blk, 0, stream>>>(Xn, WqkvT, Bqkv, nullptr, Qkv, NQKV, 1024);
  v_transpose<<<dim3(32, 32), blk, 0, stream>>>(Qkv, Vtb);
  attn_kernel<<<dim3(32, 32), blk, 0, stream>>>(Qkv, Vtb, Attn);
  // Wo projection: split-K2 -> partials -> fused reduce(+bias+residual)+LN2
  gemm_splitk<<<dim3(8, 32, 2), blk, 0, stream>>>(Attn, WoT, WoP0, WoP1, 1024, 1024, 512);
  reduce_wo_ln<<<dim3(MM), blk, 0, stream>>>(WoP0, WoP1, x, bo, ln2_g, ln2_b, X1f, Xn);
  gemm_bf16<true, false, true><<<dim3(32, 32), blk, 0, stream>>>(Xn, W1T, b1, nullptr, Hid, HIDN, 1024);
  // FC2: split-K2 -> partials -> fused reduce(+bias+residual) -> out
  gemm_splitk<<<dim3(8, 32, 2), blk, 0, stream>>>(Hid, W2T, F2P0, F2P1, 1024, 4096, 2048);
  reduce_fc2<<<dim3(MM), blk, 0, stream>>>(F2P0, F2P1, X1f, b2, out);
}

// Round 4
// 317.127 us; speedup vs baseline: 9.4491x; 1.0068x over previous
//
#include <hip/hip_runtime.h>

typedef float f32x4 __attribute__((ext_vector_type(4)));
typedef __bf16 bf16x8 __attribute__((ext_vector_type(8)));

constexpr int TT   = 2048;
constexpr int CC   = 1024;
constexpr int HIDN = 4096;
constexpr int MM   = 4096;   // B*T rows
constexpr int NQKV = 3072;

union U84 { uint32_t u[4]; bf16x8 v; };

__device__ inline uint32_t cvt_pk_bf16(float lo, float hi) {
  uint32_t r;
  asm("v_cvt_pk_bf16_f32 %0, %1, %2" : "=v"(r) : "v"(lo), "v"(hi));
  return r;
}
__device__ inline ushort f2bf(float f) { return (ushort)(cvt_pk_bf16(f, 0.f) & 0xffffu); }
__device__ inline float bfbits2f(uint32_t bits) {
  union { uint32_t u; float f; } c; c.u = bits; return c.f;
}
__device__ inline float exp2_fast(float x) {
  float r;
  asm("v_exp_f32 %0, %1" : "=v"(r) : "v"(x));
  return r;
}

#define AS1C(p) ((__attribute__((address_space(1))) void*)(p))
#define AS3(p)  ((__attribute__((address_space(3))) void*)(p))

// ---------------- LayerNorm fp32 -> bf16, one block per row ----------------
__global__ __launch_bounds__(256) void ln_kernel(const float* __restrict__ x,
                                                 const float* __restrict__ g,
                                                 const float* __restrict__ b,
                                                 ushort* __restrict__ y) {
  const int row = blockIdx.x;
  const float4* xr = reinterpret_cast<const float4*>(x + (size_t)row * CC);
  float4 v = xr[threadIdx.x];
  float s  = v.x + v.y + v.z + v.w;
  float ss = v.x * v.x + v.y * v.y + v.z * v.z + v.w * v.w;
#pragma unroll
  for (int off = 32; off; off >>= 1) {
    s  += __shfl_down(s, off);
    ss += __shfl_down(ss, off);
  }
  __shared__ float red[16];
  const int wid = threadIdx.x >> 6, lane = threadIdx.x & 63;
  if (lane == 0) { red[wid] = s; red[8 + wid] = ss; }
  __syncthreads();
  if (threadIdx.x == 0) {
    red[0] = red[0] + red[1] + red[2] + red[3];
    red[8] = red[8] + red[9] + red[10] + red[11];
  }
  __syncthreads();
  const float mu   = red[0] * (1.0f / CC);
  const float var  = red[8] * (1.0f / CC) - mu * mu;
  const float rstd = rsqrtf(var + 1e-5f);
  float4 gg = reinterpret_cast<const float4*>(g)[threadIdx.x];
  float4 bb = reinterpret_cast<const float4*>(b)[threadIdx.x];
  uint2 st;
  st.x = cvt_pk_bf16((v.x - mu) * rstd * gg.x + bb.x, (v.y - mu) * rstd * gg.y + bb.y);
  st.y = cvt_pk_bf16((v.z - mu) * rstd * gg.z + bb.z, (v.w - mu) * rstd * gg.w + bb.w);
  *reinterpret_cast<uint2*>(y + (size_t)row * CC + threadIdx.x * 4) = st;
}

// ---------------- weight transpose+convert: W[K][N] f32 -> out[N][K] bf16 ----------------
__global__ __launch_bounds__(256) void transpose_w(const float* __restrict__ W,
                                                   ushort* __restrict__ out,
                                                   int Kd, int Nd, int rowOff) {
  __shared__ float Ts[32][33];
  const int t = threadIdx.x;
  const int n0 = blockIdx.x * 32, k0 = blockIdx.y * 32;
  {
    const int r = t >> 3, cb = (t & 7) * 4;
    float4 v = *reinterpret_cast<const float4*>(W + (size_t)(k0 + r) * Nd + n0 + cb);
    Ts[r][cb + 0] = v.x; Ts[r][cb + 1] = v.y; Ts[r][cb + 2] = v.z; Ts[r][cb + 3] = v.w;
  }
  __syncthreads();
  {
    const int nl = t >> 3, kb = (t & 7) * 4;
    uint2 st;
    st.x = cvt_pk_bf16(Ts[kb + 0][nl], Ts[kb + 1][nl]);
    st.y = cvt_pk_bf16(Ts[kb + 2][nl], Ts[kb + 3][nl]);
    *reinterpret_cast<uint2*>(out + (size_t)(rowOff + n0 + nl) * Kd + k0 + kb) = st;
  }
}

// ---------------- concat bq|bk|bv -> bqkv[3072] ----------------
__global__ __launch_bounds__(256) void concat_bias(const float* __restrict__ bq,
                                                   const float* __restrict__ bk,
                                                   const float* __restrict__ bv,
                                                   float* __restrict__ out) {
  const int i = blockIdx.x * 256 + threadIdx.x;
  out[i] = (i < 1024) ? bq[i] : ((i < 2048) ? bk[i - 1024] : bv[i - 2048]);
}

// ---------------- V transpose: qkv cols [2048..3071] -> Vt[bh*64+d][T] ----------------
__global__ __launch_bounds__(256) void v_transpose(const ushort* __restrict__ qkv,
                                                   ushort* __restrict__ Vt) {
  __shared__ ushort Ts[64][72];
  const int t = threadIdx.x;
  const int tt = blockIdx.x, bh = blockIdx.y;
  const int b = bh >> 4, h = bh & 15;
#pragma unroll
  for (int c2 = 0; c2 < 2; ++c2) {
    const int e = t + 256 * c2;
    const int r = e >> 3, c = e & 7;
    uint4 raw = *reinterpret_cast<const uint4*>(
        qkv + (size_t)(b * TT + tt * 64 + r) * NQKV + 2048 + h * 64 + c * 8);
    *reinterpret_cast<uint4*>(&Ts[r][c * 8]) = raw;
  }
  __syncthreads();
  const int d = t >> 2, tkb = (t & 3) * 16;
  uint32_t wv[8];
#pragma unroll
  for (int j = 0; j < 8; ++j)
    wv[j] = (uint32_t)Ts[tkb + 2 * j][d] | ((uint32_t)Ts[tkb + 2 * j + 1][d] << 16);
  ushort* op = Vt + (size_t)(bh * 64 + d) * TT + tt * 64 + tkb;
  uint4 s0; s0.x = wv[0]; s0.y = wv[1]; s0.z = wv[2]; s0.w = wv[3];
  uint4 s1; s1.x = wv[4]; s1.y = wv[5]; s1.z = wv[6]; s1.w = wv[7];
  *reinterpret_cast<uint4*>(op) = s0;
  *reinterpret_cast<uint4*>(op + 8) = s1;
}

// ---------------- bf16 MFMA GEMM (m97 structure): C = A[M,K] @ Bt[N,K]^T ----------------
template <bool RELU, bool RES, bool OUTBF>
__global__ __launch_bounds__(256) void gemm_bf16(const ushort* __restrict__ A,
                                                 const ushort* __restrict__ Bt,
                                                 const float* __restrict__ bias,
                                                 const float* __restrict__ res,
                                                 void* __restrict__ outp,
                                                 int N, int K) {
  __shared__ ushort As[128 * 32];
  __shared__ ushort Bs[128 * 32];
  const int t = threadIdx.x;
  const int lane = t & 63, w = t >> 6;
  const int g = lane >> 4, i16 = lane & 15;
  const int wrow = w >> 1, wcol = w & 1;
  // bijective XCD swizzle (all grids have nwg % 8 == 0)
  const int nwg  = gridDim.x * gridDim.y;
  const int orig = blockIdx.y * gridDim.x + blockIdx.x;
  const int sw   = (orig & 7) * (nwg >> 3) + (orig >> 3);
  const int row0 = (sw / gridDim.x) * 128, col0 = (sw % gridDim.x) * 128;

  f32x4 acc[4][4] = {};

  const int srow = t >> 2, sc = (t & 3) * 8;
  const ushort* aS1 = A + (size_t)(row0 + srow) * K + sc;
  const ushort* aS2 = A + (size_t)(row0 + 64 + srow) * K + sc;
  const ushort* bS1 = Bt + (size_t)(col0 + srow) * K + sc;
  const ushort* bS2 = Bt + (size_t)(col0 + 64 + srow) * K + sc;
  char* aL1 = (char*)As + w * 1024;
  char* aL2 = (char*)As + 4096 + w * 1024;
  char* bL1 = (char*)Bs + w * 1024;
  char* bL2 = (char*)Bs + 4096 + w * 1024;

  for (int k0 = 0; k0 < K; k0 += 32) {
    __syncthreads();
    __builtin_amdgcn_global_load_lds(AS1C(aS1 + k0), AS3(aL1), 16, 0, 0);
    __builtin_amdgcn_global_load_lds(AS1C(aS2 + k0), AS3(aL2), 16, 0, 0);
    __builtin_amdgcn_global_load_lds(AS1C(bS1 + k0), AS3(bL1), 16, 0, 0);
    __builtin_amdgcn_global_load_lds(AS1C(bS2 + k0), AS3(bL2), 16, 0, 0);
    __syncthreads();

    bf16x8 a4[4], b4[4];
#pragma unroll
    for (int mf = 0; mf < 4; ++mf) {
      const int r = wrow * 64 + mf * 16 + i16;
      a4[mf] = *reinterpret_cast<const bf16x8*>((const char*)As + r * 64 + g * 16);
    }
#pragma unroll
    for (int nf = 0; nf < 4; ++nf) {
      const int c = wcol * 64 + nf * 16 + i16;
      b4[nf] = *reinterpret_cast<const bf16x8*>((const char*)Bs + c * 64 + g * 16);
    }
#pragma unroll
    for (int mf = 0; mf < 4; ++mf)
#pragma unroll
      for (int nf = 0; nf < 4; ++nf)
        acc[mf][nf] = __builtin_amdgcn_mfma_f32_16x16x32_bf16(a4[mf], b4[nf], acc[mf][nf], 0, 0, 0);
  }

#pragma unroll
  for (int nf = 0; nf < 4; ++nf) {
    const int ncol = col0 + wcol * 64 + nf * 16 + i16;
    const float bb = bias[ncol];
#pragma unroll
    for (int mf = 0; mf < 4; ++mf) {
      const int mrow = row0 + wrow * 64 + mf * 16 + 4 * g;
#pragma unroll
      for (int r = 0; r < 4; ++r) {
        float v = acc[mf][nf][r] + bb;
        if (RELU) v = fmaxf(v, 0.f);
        const size_t off = (size_t)(mrow + r) * N + ncol;
        if (RES) v += res[off];
        if (OUTBF) ((ushort*)outp)[off] = f2bf(v);
        else       ((float*)outp)[off]  = v;
      }
    }
  }
}

// ---------------- split-K (2-way) bf16 MFMA GEMM, raw f32 partials ----------------
__global__ __launch_bounds__(256) void gemm_splitk(const ushort* __restrict__ A,
                                                   const ushort* __restrict__ Bt,
                                                   float* __restrict__ P0,
                                                   float* __restrict__ P1,
                                                   int N, int K, int Kchunk) {
  __shared__ ushort As[128 * 32];
  __shared__ ushort Bs[128 * 32];
  const int t = threadIdx.x;
  const int lane = t & 63, w = t >> 6;
  const int g = lane >> 4, i16 = lane & 15;
  const int wrow = w >> 1, wcol = w & 1;
  const int nwg  = gridDim.x * gridDim.y;
  const int orig = blockIdx.y * gridDim.x + blockIdx.x;
  const int sw   = (orig & 7) * (nwg >> 3) + (orig >> 3);
  const int row0 = (sw / gridDim.x) * 128, col0 = (sw % gridDim.x) * 128;
  const int kstart = blockIdx.z * Kchunk;
  float* __restrict__ P = blockIdx.z ? P1 : P0;

  f32x4 acc[4][4] = {};

  const int srow = t >> 2, sc = (t & 3) * 8;
  const ushort* aS1 = A + (size_t)(row0 + srow) * K + sc;
  const ushort* aS2 = A + (size_t)(row0 + 64 + srow) * K + sc;
  const ushort* bS1 = Bt + (size_t)(col0 + srow) * K + sc;
  const ushort* bS2 = Bt + (size_t)(col0 + 64 + srow) * K + sc;
  char* aL1 = (char*)As + w * 1024;
  char* aL2 = (char*)As + 4096 + w * 1024;
  char* bL1 = (char*)Bs + w * 1024;
  char* bL2 = (char*)Bs + 4096 + w * 1024;

  for (int k0 = kstart; k0 < kstart + Kchunk; k0 += 32) {
    __syncthreads();
    __builtin_amdgcn_global_load_lds(AS1C(aS1 + k0), AS3(aL1), 16, 0, 0);
    __builtin_amdgcn_global_load_lds(AS1C(aS2 + k0), AS3(aL2), 16, 0, 0);
    __builtin_amdgcn_global_load_lds(AS1C(bS1 + k0), AS3(bL1), 16, 0, 0);
    __builtin_amdgcn_global_load_lds(AS1C(bS2 + k0), AS3(bL2), 16, 0, 0);
    __syncthreads();

    bf16x8 a4[4], b4[4];
#pragma unroll
    for (int mf = 0; mf < 4; ++mf) {
      const int r = wrow * 64 + mf * 16 + i16;
      a4[mf] = *reinterpret_cast<const bf16x8*>((const char*)As + r * 64 + g * 16);
    }
#pragma unroll
    for (int nf = 0; nf < 4; ++nf) {
      const int c = wcol * 64 + nf * 16 + i16;
      b4[nf] = *reinterpret_cast<const bf16x8*>((const char*)Bs + c * 64 + g * 16);
    }
#pragma unroll
    for (int mf = 0; mf < 4; ++mf)
#pragma unroll
      for (int nf = 0; nf < 4; ++nf)
        acc[mf][nf] = __builtin_amdgcn_mfma_f32_16x16x32_bf16(a4[mf], b4[nf], acc[mf][nf], 0, 0, 0);
  }

#pragma unroll
  for (int nf = 0; nf < 4; ++nf) {
    const int ncol = col0 + wcol * 64 + nf * 16 + i16;
#pragma unroll
    for (int mf = 0; mf < 4; ++mf) {
      const int mrow = row0 + wrow * 64 + mf * 16 + 4 * g;
#pragma unroll
      for (int r = 0; r < 4; ++r)
        P[(size_t)(mrow + r) * N + ncol] = acc[mf][nf][r];
    }
  }
}

// ---------------- Wo reduce + residual + LN2 fused: one block per row ----------------
__global__ __launch_bounds__(256) void reduce_wo_ln(const float* __restrict__ P0,
                                                    const float* __restrict__ P1,
                                                    const float* __restrict__ x,
                                                    const float* __restrict__ bo,
                                                    const float* __restrict__ g,
                                                    const float* __restrict__ b,
                                                    float* __restrict__ X1f,
                                                    ushort* __restrict__ Xn) {
  const int row = blockIdx.x, t = threadIdx.x;
  const size_t off = (size_t)row * CC + t * 4;
  float4 v  = *reinterpret_cast<const float4*>(x + off);
  float4 p0 = *reinterpret_cast<const float4*>(P0 + off);
  float4 p1 = *reinterpret_cast<const float4*>(P1 + off);
  float4 bb = reinterpret_cast<const float4*>(bo)[t];
  v.x += p0.x + p1.x + bb.x;
  v.y += p0.y + p1.y + bb.y;
  v.z += p0.z + p1.z + bb.z;
  v.w += p0.w + p1.w + bb.w;
  *reinterpret_cast<float4*>(X1f + off) = v;

  float s  = v.x + v.y + v.z + v.w;
  float ss = v.x * v.x + v.y * v.y + v.z * v.z + v.w * v.w;
#pragma unroll
  for (int o = 32; o; o >>= 1) {
    s  += __shfl_down(s, o);
    ss += __shfl_down(ss, o);
  }
  __shared__ float red[16];
  const int wid = t >> 6, lane = t & 63;
  if (lane == 0) { red[wid] = s; red[8 + wid] = ss; }
  __syncthreads();
  if (t == 0) {
    red[0] = red[0] + red[1] + red[2] + red[3];
    red[8] = red[8] + red[9] + red[10] + red[11];
  }
  __syncthreads();
  const float mu   = red[0] * (1.0f / CC);
  const float var  = red[8] * (1.0f / CC) - mu * mu;
  const float rstd = rsqrtf(var + 1e-5f);
  float4 gg = reinterpret_cast<const float4*>(g)[t];
  float4 lb = reinterpret_cast<const float4*>(b)[t];
  uint2 st;
  st.x = cvt_pk_bf16((v.x - mu) * rstd * gg.x + lb.x, (v.y - mu) * rstd * gg.y + lb.y);
  st.y = cvt_pk_bf16((v.z - mu) * rstd * gg.z + lb.z, (v.w - mu) * rstd * gg.w + lb.w);
  *reinterpret_cast<uint2*>(Xn + off) = st;
}

// ---------------- FC2 reduce + bias + residual -> final out ----------------
__global__ __launch_bounds__(256) void reduce_fc2(const float* __restrict__ P0,
                                                  const float* __restrict__ P1,
                                                  const float* __restrict__ X1,
                                                  const float* __restrict__ b2,
                                                  float* __restrict__ out) {
  const int row = blockIdx.x, t = threadIdx.x;
  const size_t off = (size_t)row * CC + t * 4;
  float4 v  = *reinterpret_cast<const float4*>(X1 + off);
  float4 p0 = *reinterpret_cast<const float4*>(P0 + off);
  float4 p1 = *reinterpret_cast<const float4*>(P1 + off);
  float4 bb = reinterpret_cast<const float4*>(b2)[t];
  v.x += p0.x + p1.x + bb.x;
  v.y += p0.y + p1.y + bb.y;
  v.z += p0.z + p1.z + bb.z;
  v.w += p0.w + p1.w + bb.w;
  *reinterpret_cast<float4*>(out + off) = v;
}

// ---------------- MFMA flash attention, double-buffered K/V, exp2 + defer-max ----------------
__global__ __launch_bounds__(256) void attn_kernel(const ushort* __restrict__ qkv,
                                                   const ushort* __restrict__ Vt,
                                                   ushort* __restrict__ attnb) {
  __shared__ ushort Ks[2][64 * 64];
  __shared__ ushort Vs[2][64 * 64];
  const int t = threadIdx.x, lane = t & 63, w = t >> 6;
  const int g = lane >> 4, iq = lane & 15;
  const int qt = blockIdx.x, bh = blockIdx.y;
  const int b = bh >> 4, h = bh & 15;

  // Q fragments in registers; scale = 1/sqrt(64) * log2(e) so softmax runs in exp2 domain
  bf16x8 qfrag[2];
  {
    const ushort* qrow = qkv + (size_t)(b * TT + qt * 64 + w * 16 + iq) * NQKV + h * 64;
    const float qs = 0.125f * 1.44269504f;
#pragma unroll
    for (int kk = 0; kk < 2; ++kk) {
      uint4 raw = *reinterpret_cast<const uint4*>(qrow + kk * 32 + g * 8);
      uint32_t rr[4] = {raw.x, raw.y, raw.z, raw.w};
      U84 tmp;
#pragma unroll
      for (int c = 0; c < 4; ++c) {
        float lo = bfbits2f(rr[c] << 16) * qs;
        float hi = bfbits2f(rr[c] & 0xffff0000u) * qs;
        tmp.u[c] = cvt_pk_bf16(lo, hi);
      }
      qfrag[kk] = tmp.v;
    }
  }

  const int sr1 = t >> 3, sc1 = t & 7;
  const int csw = (sc1 ^ (sr1 & 7)) * 8;   // pre-swizzled global col (linear LDS dest)
  const ushort* kbase = qkv + 1024 + h * 64;
  const ushort* vbase = Vt + (size_t)(bh * 64) * TT;

  auto STAGE = [&](int bi, int kt) {
    char* kL1 = (char*)(&Ks[bi][0]) + w * 1024;
    char* kL2 = (char*)(&Ks[bi][0]) + 4096 + w * 1024;
    char* vL1 = (char*)(&Vs[bi][0]) + w * 1024;
    char* vL2 = (char*)(&Vs[bi][0]) + 4096 + w * 1024;
    const size_t tok = (size_t)(b * TT + kt * 64);
    __builtin_amdgcn_global_load_lds(AS1C(kbase + (tok + sr1) * NQKV + csw), AS3(kL1), 16, 0, 0);
    __builtin_amdgcn_global_load_lds(AS1C(kbase + (tok + 32 + sr1) * NQKV + csw), AS3(kL2), 16, 0, 0);
    __builtin_amdgcn_global_load_lds(AS1C(vbase + (size_t)sr1 * TT + kt * 64 + csw), AS3(vL1), 16, 0, 0);
    __builtin_amdgcn_global_load_lds(AS1C(vbase + (size_t)(32 + sr1) * TT + kt * 64 + csw), AS3(vL2), 16, 0, 0);
  };

  STAGE(0, 0);
  __syncthreads();   // drains vmcnt(0) before first compute

  float mrun = -3e38f, lrun = 0.f;
  f32x4 ot[4] = {};

  for (int kt = 0; kt < TT / 64; ++kt) {
    const int cur = kt & 1;
    if (kt + 1 < TT / 64) STAGE(cur ^ 1, kt + 1);   // prefetch next tile under compute
    const char* Kc = (const char*)(&Ks[cur][0]);
    const char* Vc = (const char*)(&Vs[cur][0]);

    // S^T = K @ Q^T : lane holds 16 scores for query iq, keys j = 16jf+4g+r
    f32x4 sfr[4] = {};
    __builtin_amdgcn_s_setprio(1);
#pragma unroll
    for (int kk = 0; kk < 2; ++kk)
#pragma unroll
      for (int jf = 0; jf < 4; ++jf) {
        const int row = iq + 16 * jf;
        const int off = row * 128 + ((kk * 64 + g * 16) ^ ((row & 7) << 4));
        bf16x8 a = *reinterpret_cast<const bf16x8*>(Kc + off);
        sfr[jf] = __builtin_amdgcn_mfma_f32_16x16x32_bf16(a, qfrag[kk], sfr[jf], 0, 0, 0);
      }
    __builtin_amdgcn_s_setprio(0);

    // online softmax (exp2 domain), defer-max with THR=8
    float tm0 = fmaxf(fmaxf(sfr[0][0], sfr[0][1]), fmaxf(sfr[0][2], sfr[0][3]));
    float tm1 = fmaxf(fmaxf(sfr[1][0], sfr[1][1]), fmaxf(sfr[1][2], sfr[1][3]));
    float tm2 = fmaxf(fmaxf(sfr[2][0], sfr[2][1]), fmaxf(sfr[2][2], sfr[2][3]));
    float tm3 = fmaxf(fmaxf(sfr[3][0], sfr[3][1]), fmaxf(sfr[3][2], sfr[3][3]));
    float tmax = fmaxf(fmaxf(tm0, tm1), fmaxf(tm2, tm3));
    tmax = fmaxf(tmax, __shfl_xor(tmax, 16, 64));
    tmax = fmaxf(tmax, __shfl_xor(tmax, 32, 64));

    if (!__all(tmax <= mrun + 8.f)) {
      const float mnew  = fmaxf(mrun, tmax);
      const float alpha = exp2_fast(mrun - mnew);
      lrun *= alpha;
#pragma unroll
      for (int df = 0; df < 4; ++df)
#pragma unroll
        for (int r = 0; r < 4; ++r) ot[df][r] *= alpha;
      mrun = mnew;
    }

    float lsum = 0.f;
    uint32_t u[4][2];
#pragma unroll
    for (int f = 0; f < 4; ++f) {
      float p0 = exp2_fast(sfr[f][0] - mrun);
      float p1 = exp2_fast(sfr[f][1] - mrun);
      float p2 = exp2_fast(sfr[f][2] - mrun);
      float p3 = exp2_fast(sfr[f][3] - mrun);
      lsum += (p0 + p1) + (p2 + p3);
      u[f][0] = cvt_pk_bf16(p0, p1);
      u[f][1] = cvt_pk_bf16(p2, p3);
    }
    lsum += __shfl_xor(lsum, 16, 64);
    lsum += __shfl_xor(lsum, 32, 64);
    lrun += lsum;

    // PV: O^T = Vt @ P^T ; rebuild B-frag via quad-group shuffles
#pragma unroll
    for (int kk = 0; kk < 2; ++kk) {
      U84 bfr;
#pragma unroll
      for (int q = 0; q < 4; ++q) {
        const int srcl = (2 * (g & 1) + (q >> 1)) * 16 + iq;
        const uint32_t v0 = (uint32_t)__shfl((int)u[2 * kk + 0][q & 1], srcl, 64);
        const uint32_t v1 = (uint32_t)__shfl((int)u[2 * kk + 1][q & 1], srcl, 64);
        bfr.u[q] = (g & 2) ? v1 : v0;
      }
      __builtin_amdgcn_s_setprio(1);
#pragma unroll
      for (int df = 0; df < 4; ++df) {
        const int row = iq + 16 * df;
        const int off = row * 128 + ((kk * 64 + g * 16) ^ ((row & 7) << 4));
        bf16x8 a = *reinterpret_cast<const bf16x8*>(Vc + off);
        ot[df] = __builtin_amdgcn_mfma_f32_16x16x32_bf16(a, bfr.v, ot[df], 0, 0, 0);
      }
      __builtin_amdgcn_s_setprio(0);
    }

    __syncthreads();   // implicit vmcnt(0)+lgkmcnt(0) drain: next tile staged & safe to flip
  }

  const float inv = 1.f / lrun;
  ushort* orow = attnb + (size_t)(b * TT + qt * 64 + w * 16 + iq) * CC + h * 64;
#pragma unroll
  for (int df = 0; df < 4; ++df) {
    uint2 st;
    st.x = cvt_pk_bf16(ot[df][0] * inv, ot[df][1] * inv);
    st.y = cvt_pk_bf16(ot[df][2] * inv, ot[df][3] * inv);
    *reinterpret_cast<uint2*>(orow + df * 16 + g * 4) = st;
  }
}

// --------------------------------- launcher -------------------------------------
extern "C" void kernel_launch(void* const* d_in, const int* in_sizes, int n_in,
                              void* d_out, int out_size, void* d_ws, size_t ws_size,
                              hipStream_t stream) {
  const float* x     = (const float*)d_in[0];
  const float* ln1_g = (const float*)d_in[1];
  const float* ln1_b = (const float*)d_in[2];
  const float* ln2_g = (const float*)d_in[3];
  const float* ln2_b = (const float*)d_in[4];
  const float* Wq = (const float*)d_in[5];
  const float* bq = (const float*)d_in[6];
  const float* Wk = (const float*)d_in[7];
  const float* bk = (const float*)d_in[8];
  const float* Wv = (const float*)d_in[9];
  const float* bv = (const float*)d_in[10];
  const float* Wo = (const float*)d_in[11];
  const float* bo = (const float*)d_in[12];
  const float* W1 = (const float*)d_in[13];
  const float* b1 = (const float*)d_in[14];
  const float* W2 = (const float*)d_in[15];
  const float* b2 = (const float*)d_in[16];
  float* out = (float*)d_out;
  char* ws = (char*)d_ws;

  // workspace layout (92.3 MB total)
  ushort* WqkvT = (ushort*)(ws + 0);          // 3072x1024 bf16 (6 MB)
  ushort* WoT   = (ushort*)(ws + 6291456);    // 1024x1024 bf16 (2 MB)
  ushort* W1T   = (ushort*)(ws + 8388608);    // 4096x1024 bf16 (8 MB)
  ushort* W2T   = (ushort*)(ws + 16777216);   // 1024x4096 bf16 (8 MB)
  float*  Bqkv  = (float*) (ws + 25165824);   // 3072 f32
  ushort* Xn    = (ushort*)(ws + 25178112);   // 4096x1024 bf16 (8 MB)
  ushort* Attn  = (ushort*)(ws + 33566720);   // 4096x1024 bf16 (8 MB)
  float*  X1f   = (float*) (ws + 41955328);   // 4096x1024 f32 (16 MB)
  ushort* Qkv   = (ushort*)(ws + 58732544);   // 4096x3072 bf16 (24 MB)
  ushort* Vtb   = (ushort*)(ws + 83898368);   // 2048x2048 bf16 (8 MB)
  ushort* Hid   = (ushort*)(ws + 58732544);   // 4096x4096 bf16 (reuses Qkv+Vtb)
  float* WoP0  = (float*)(ws + 58732544);     // Wo split-K partials (dead Qkv region)
  float* WoP1  = (float*)(ws + 75509760);
  float* F2P0  = (float*)(ws + 0);            // FC2 partials (dead weight regions)
  float* F2P1  = (float*)(ws + 25178112);

  const dim3 blk(256);

  transpose_w<<<dim3(32, 32), blk, 0, stream>>>(Wq, WqkvT, 1024, 1024, 0);
  transpose_w<<<dim3(32, 32), blk, 0, stream>>>(Wk, WqkvT, 1024, 1024, 1024);
  transpose_w<<<dim3(32, 32), blk, 0, stream>>>(Wv, WqkvT, 1024, 1024, 2048);
  transpose_w<<<dim3(32, 32), blk, 0, stream>>>(Wo, WoT, 1024, 1024, 0);
  transpose_w<<<dim3(128, 32), blk, 0, stream>>>(W1, W1T, 1024, 4096, 0);
  transpose_w<<<dim3(32, 128), blk, 0, stream>>>(W2, W2T, 4096, 1024, 0);
  concat_bias<<<dim3(12), blk, 0, stream>>>(bq, bk, bv, Bqkv);

  ln_kernel<<<dim3(MM), blk, 0, stream>>>(x, ln1_g, ln1_b, Xn);
  gemm_bf16<false, false, true><<<dim3(24, 32), blk, 0, stream>>>(Xn, WqkvT, Bqkv, nullptr, Qkv, NQKV, 1024);
  v_transpose<<<dim3(32, 32), blk, 0, stream>>>(Qkv, Vtb);
  attn_kernel<<<dim3(32, 32), blk, 0, stream>>>(Qkv, Vtb, Attn);
  gemm_splitk<<<dim3(8, 32, 2), blk, 0, stream>>>(Attn, WoT, WoP0, WoP1, 1024, 1024, 512);
  reduce_wo_ln<<<dim3(MM), blk, 0, stream>>>(WoP0, WoP1, x, bo, ln2_g, ln2_b, X1f, Xn);
  gemm_bf16<true, false, true><<<dim3(32, 32), blk, 0, stream>>>(Xn, W1T, b1, nullptr, Hid, HIDN, 1024);
  gemm_splitk<<<dim3(8, 32, 2), blk, 0, stream>>>(Hid, W2T, F2P0, F2P1, 1024, 4096, 2048);
  reduce_fc2<<<dim3(MM), blk, 0, stream>>>(F2P0, F2P1, X1f, b2, out);
}

// Round 5
// 312.914 us; speedup vs baseline: 9.5764x; 1.0135x over previous
//
#include <hip/hip_runtime.h>

typedef float f32x4 __attribute__((ext_vector_type(4)));
typedef __bf16 bf16x8 __attribute__((ext_vector_type(8)));

constexpr int TT   = 2048;
constexpr int CC   = 1024;
constexpr int HIDN = 4096;
constexpr int MM   = 4096;   // B*T rows
constexpr int NQKV = 3072;

union U84 { uint32_t u[4]; bf16x8 v; };

__device__ inline uint32_t cvt_pk_bf16(float lo, float hi) {
  uint32_t r;
  asm("v_cvt_pk_bf16_f32 %0, %1, %2" : "=v"(r) : "v"(lo), "v"(hi));
  return r;
}
__device__ inline ushort f2bf(float f) { return (ushort)(cvt_pk_bf16(f, 0.f) & 0xffffu); }
__device__ inline float bfbits2f(uint32_t bits) {
  union { uint32_t u; float f; } c; c.u = bits; return c.f;
}
__device__ inline float exp2_fast(float x) {
  float r;
  asm("v_exp_f32 %0, %1" : "=v"(r) : "v"(x));
  return r;
}

#define AS1C(p) ((__attribute__((address_space(1))) void*)(p))
#define AS3(p)  ((__attribute__((address_space(3))) void*)(p))

// ---------------- LayerNorm fp32 -> bf16, one block per row ----------------
__global__ __launch_bounds__(256) void ln_kernel(const float* __restrict__ x,
                                                 const float* __restrict__ g,
                                                 const float* __restrict__ b,
                                                 ushort* __restrict__ y) {
  const int row = blockIdx.x;
  const float4* xr = reinterpret_cast<const float4*>(x + (size_t)row * CC);
  float4 v = xr[threadIdx.x];
  float s  = v.x + v.y + v.z + v.w;
  float ss = v.x * v.x + v.y * v.y + v.z * v.z + v.w * v.w;
#pragma unroll
  for (int off = 32; off; off >>= 1) {
    s  += __shfl_down(s, off);
    ss += __shfl_down(ss, off);
  }
  __shared__ float red[16];
  const int wid = threadIdx.x >> 6, lane = threadIdx.x & 63;
  if (lane == 0) { red[wid] = s; red[8 + wid] = ss; }
  __syncthreads();
  if (threadIdx.x == 0) {
    red[0] = red[0] + red[1] + red[2] + red[3];
    red[8] = red[8] + red[9] + red[10] + red[11];
  }
  __syncthreads();
  const float mu   = red[0] * (1.0f / CC);
  const float var  = red[8] * (1.0f / CC) - mu * mu;
  const float rstd = rsqrtf(var + 1e-5f);
  float4 gg = reinterpret_cast<const float4*>(g)[threadIdx.x];
  float4 bb = reinterpret_cast<const float4*>(b)[threadIdx.x];
  uint2 st;
  st.x = cvt_pk_bf16((v.x - mu) * rstd * gg.x + bb.x, (v.y - mu) * rstd * gg.y + bb.y);
  st.y = cvt_pk_bf16((v.z - mu) * rstd * gg.z + bb.z, (v.w - mu) * rstd * gg.w + bb.w);
  *reinterpret_cast<uint2*>(y + (size_t)row * CC + threadIdx.x * 4) = st;
}

// ---------------- weight transpose+convert: W[K][N] f32 -> out[N][K] bf16 ----------------
__global__ __launch_bounds__(256) void transpose_w(const float* __restrict__ W,
                                                   ushort* __restrict__ out,
                                                   int Kd, int Nd, int rowOff) {
  __shared__ float Ts[32][33];
  const int t = threadIdx.x;
  const int n0 = blockIdx.x * 32, k0 = blockIdx.y * 32;
  {
    const int r = t >> 3, cb = (t & 7) * 4;
    float4 v = *reinterpret_cast<const float4*>(W + (size_t)(k0 + r) * Nd + n0 + cb);
    Ts[r][cb + 0] = v.x; Ts[r][cb + 1] = v.y; Ts[r][cb + 2] = v.z; Ts[r][cb + 3] = v.w;
  }
  __syncthreads();
  {
    const int nl = t >> 3, kb = (t & 7) * 4;
    uint2 st;
    st.x = cvt_pk_bf16(Ts[kb + 0][nl], Ts[kb + 1][nl]);
    st.y = cvt_pk_bf16(Ts[kb + 2][nl], Ts[kb + 3][nl]);
    *reinterpret_cast<uint2*>(out + (size_t)(rowOff + n0 + nl) * Kd + k0 + kb) = st;
  }
}

// ---------------- concat bq|bk|bv -> bqkv[3072] ----------------
__global__ __launch_bounds__(256) void concat_bias(const float* __restrict__ bq,
                                                   const float* __restrict__ bk,
                                                   const float* __restrict__ bv,
                                                   float* __restrict__ out) {
  const int i = blockIdx.x * 256 + threadIdx.x;
  out[i] = (i < 1024) ? bq[i] : ((i < 2048) ? bk[i - 1024] : bv[i - 2048]);
}

// ---------------- V transpose: qkv cols [2048..3071] -> Vt[bh*64+d][T] ----------------
__global__ __launch_bounds__(256) void v_transpose(const ushort* __restrict__ qkv,
                                                   ushort* __restrict__ Vt) {
  __shared__ ushort Ts[64][72];
  const int t = threadIdx.x;
  const int tt = blockIdx.x, bh = blockIdx.y;
  const int b = bh >> 4, h = bh & 15;
#pragma unroll
  for (int c2 = 0; c2 < 2; ++c2) {
    const int e = t + 256 * c2;
    const int r = e >> 3, c = e & 7;
    uint4 raw = *reinterpret_cast<const uint4*>(
        qkv + (size_t)(b * TT + tt * 64 + r) * NQKV + 2048 + h * 64 + c * 8);
    *reinterpret_cast<uint4*>(&Ts[r][c * 8]) = raw;
  }
  __syncthreads();
  const int d = t >> 2, tkb = (t & 3) * 16;
  uint32_t wv[8];
#pragma unroll
  for (int j = 0; j < 8; ++j)
    wv[j] = (uint32_t)Ts[tkb + 2 * j][d] | ((uint32_t)Ts[tkb + 2 * j + 1][d] << 16);
  ushort* op = Vt + (size_t)(bh * 64 + d) * TT + tt * 64 + tkb;
  uint4 s0; s0.x = wv[0]; s0.y = wv[1]; s0.z = wv[2]; s0.w = wv[3];
  uint4 s1; s1.x = wv[4]; s1.y = wv[5]; s1.z = wv[6]; s1.w = wv[7];
  *reinterpret_cast<uint4*>(op) = s0;
  *reinterpret_cast<uint4*>(op + 8) = s1;
}

// ---------------- bf16 MFMA GEMM (m97 structure): C = A[M,K] @ Bt[N,K]^T ----------------
template <bool RELU, bool RES, bool OUTBF>
__global__ __launch_bounds__(256) void gemm_bf16(const ushort* __restrict__ A,
                                                 const ushort* __restrict__ Bt,
                                                 const float* __restrict__ bias,
                                                 const float* __restrict__ res,
                                                 void* __restrict__ outp,
                                                 int N, int K) {
  __shared__ ushort As[128 * 32];
  __shared__ ushort Bs[128 * 32];
  const int t = threadIdx.x;
  const int lane = t & 63, w = t >> 6;
  const int g = lane >> 4, i16 = lane & 15;
  const int wrow = w >> 1, wcol = w & 1;
  const int nwg  = gridDim.x * gridDim.y;
  const int orig = blockIdx.y * gridDim.x + blockIdx.x;
  const int sw   = (orig & 7) * (nwg >> 3) + (orig >> 3);
  const int row0 = (sw / gridDim.x) * 128, col0 = (sw % gridDim.x) * 128;

  f32x4 acc[4][4] = {};

  const int srow = t >> 2, sc = (t & 3) * 8;
  const ushort* aS1 = A + (size_t)(row0 + srow) * K + sc;
  const ushort* aS2 = A + (size_t)(row0 + 64 + srow) * K + sc;
  const ushort* bS1 = Bt + (size_t)(col0 + srow) * K + sc;
  const ushort* bS2 = Bt + (size_t)(col0 + 64 + srow) * K + sc;
  char* aL1 = (char*)As + w * 1024;
  char* aL2 = (char*)As + 4096 + w * 1024;
  char* bL1 = (char*)Bs + w * 1024;
  char* bL2 = (char*)Bs + 4096 + w * 1024;

  for (int k0 = 0; k0 < K; k0 += 32) {
    __syncthreads();
    __builtin_amdgcn_global_load_lds(AS1C(aS1 + k0), AS3(aL1), 16, 0, 0);
    __builtin_amdgcn_global_load_lds(AS1C(aS2 + k0), AS3(aL2), 16, 0, 0);
    __builtin_amdgcn_global_load_lds(AS1C(bS1 + k0), AS3(bL1), 16, 0, 0);
    __builtin_amdgcn_global_load_lds(AS1C(bS2 + k0), AS3(bL2), 16, 0, 0);
    __syncthreads();

    bf16x8 a4[4], b4[4];
#pragma unroll
    for (int mf = 0; mf < 4; ++mf) {
      const int r = wrow * 64 + mf * 16 + i16;
      a4[mf] = *reinterpret_cast<const bf16x8*>((const char*)As + r * 64 + g * 16);
    }
#pragma unroll
    for (int nf = 0; nf < 4; ++nf) {
      const int c = wcol * 64 + nf * 16 + i16;
      b4[nf] = *reinterpret_cast<const bf16x8*>((const char*)Bs + c * 64 + g * 16);
    }
#pragma unroll
    for (int mf = 0; mf < 4; ++mf)
#pragma unroll
      for (int nf = 0; nf < 4; ++nf)
        acc[mf][nf] = __builtin_amdgcn_mfma_f32_16x16x32_bf16(a4[mf], b4[nf], acc[mf][nf], 0, 0, 0);
  }

#pragma unroll
  for (int nf = 0; nf < 4; ++nf) {
    const int ncol = col0 + wcol * 64 + nf * 16 + i16;
    const float bb = bias[ncol];
#pragma unroll
    for (int mf = 0; mf < 4; ++mf) {
      const int mrow = row0 + wrow * 64 + mf * 16 + 4 * g;
#pragma unroll
      for (int r = 0; r < 4; ++r) {
        float v = acc[mf][nf][r] + bb;
        if (RELU) v = fmaxf(v, 0.f);
        const size_t off = (size_t)(mrow + r) * N + ncol;
        if (RES) v += res[off];
        if (OUTBF) ((ushort*)outp)[off] = f2bf(v);
        else       ((float*)outp)[off]  = v;
      }
    }
  }
}

// ---------------- split-K (2-way) bf16 MFMA GEMM, bf16 partials ----------------
__global__ __launch_bounds__(256) void gemm_splitk(const ushort* __restrict__ A,
                                                   const ushort* __restrict__ Bt,
                                                   ushort* __restrict__ P0,
                                                   ushort* __restrict__ P1,
                                                   int N, int K, int Kchunk) {
  __shared__ ushort As[128 * 32];
  __shared__ ushort Bs[128 * 32];
  const int t = threadIdx.x;
  const int lane = t & 63, w = t >> 6;
  const int g = lane >> 4, i16 = lane & 15;
  const int wrow = w >> 1, wcol = w & 1;
  const int nwg  = gridDim.x * gridDim.y;
  const int orig = blockIdx.y * gridDim.x + blockIdx.x;
  const int sw   = (orig & 7) * (nwg >> 3) + (orig >> 3);
  const int row0 = (sw / gridDim.x) * 128, col0 = (sw % gridDim.x) * 128;
  const int kstart = blockIdx.z * Kchunk;
  ushort* __restrict__ P = blockIdx.z ? P1 : P0;

  f32x4 acc[4][4] = {};

  const int srow = t >> 2, sc = (t & 3) * 8;
  const ushort* aS1 = A + (size_t)(row0 + srow) * K + sc;
  const ushort* aS2 = A + (size_t)(row0 + 64 + srow) * K + sc;
  const ushort* bS1 = Bt + (size_t)(col0 + srow) * K + sc;
  const ushort* bS2 = Bt + (size_t)(col0 + 64 + srow) * K + sc;
  char* aL1 = (char*)As + w * 1024;
  char* aL2 = (char*)As + 4096 + w * 1024;
  char* bL1 = (char*)Bs + w * 1024;
  char* bL2 = (char*)Bs + 4096 + w * 1024;

  for (int k0 = kstart; k0 < kstart + Kchunk; k0 += 32) {
    __syncthreads();
    __builtin_amdgcn_global_load_lds(AS1C(aS1 + k0), AS3(aL1), 16, 0, 0);
    __builtin_amdgcn_global_load_lds(AS1C(aS2 + k0), AS3(aL2), 16, 0, 0);
    __builtin_amdgcn_global_load_lds(AS1C(bS1 + k0), AS3(bL1), 16, 0, 0);
    __builtin_amdgcn_global_load_lds(AS1C(bS2 + k0), AS3(bL2), 16, 0, 0);
    __syncthreads();

    bf16x8 a4[4], b4[4];
#pragma unroll
    for (int mf = 0; mf < 4; ++mf) {
      const int r = wrow * 64 + mf * 16 + i16;
      a4[mf] = *reinterpret_cast<const bf16x8*>((const char*)As + r * 64 + g * 16);
    }
#pragma unroll
    for (int nf = 0; nf < 4; ++nf) {
      const int c = wcol * 64 + nf * 16 + i16;
      b4[nf] = *reinterpret_cast<const bf16x8*>((const char*)Bs + c * 64 + g * 16);
    }
#pragma unroll
    for (int mf = 0; mf < 4; ++mf)
#pragma unroll
      for (int nf = 0; nf < 4; ++nf)
        acc[mf][nf] = __builtin_amdgcn_mfma_f32_16x16x32_bf16(a4[mf], b4[nf], acc[mf][nf], 0, 0, 0);
  }

#pragma unroll
  for (int nf = 0; nf < 4; ++nf) {
    const int ncol = col0 + wcol * 64 + nf * 16 + i16;
#pragma unroll
    for (int mf = 0; mf < 4; ++mf) {
      const int mrow = row0 + wrow * 64 + mf * 16 + 4 * g;
#pragma unroll
      for (int r = 0; r < 4; ++r)
        P[(size_t)(mrow + r) * N + ncol] = f2bf(acc[mf][nf][r]);
    }
  }
}

// ---------------- Wo reduce + residual + LN2 fused: one block per row ----------------
__global__ __launch_bounds__(256) void reduce_wo_ln(const ushort* __restrict__ P0,
                                                    const ushort* __restrict__ P1,
                                                    const float* __restrict__ x,
                                                    const float* __restrict__ bo,
                                                    const float* __restrict__ g,
                                                    const float* __restrict__ b,
                                                    float* __restrict__ X1f,
                                                    ushort* __restrict__ Xn) {
  const int row = blockIdx.x, t = threadIdx.x;
  const size_t off = (size_t)row * CC + t * 4;
  float4 v  = *reinterpret_cast<const float4*>(x + off);
  const uint2 q0 = *reinterpret_cast<const uint2*>(P0 + off);
  const uint2 q1 = *reinterpret_cast<const uint2*>(P1 + off);
  float4 bb = reinterpret_cast<const float4*>(bo)[t];
  v.x += bfbits2f(q0.x << 16)          + bfbits2f(q1.x << 16)          + bb.x;
  v.y += bfbits2f(q0.x & 0xffff0000u)  + bfbits2f(q1.x & 0xffff0000u)  + bb.y;
  v.z += bfbits2f(q0.y << 16)          + bfbits2f(q1.y << 16)          + bb.z;
  v.w += bfbits2f(q0.y & 0xffff0000u)  + bfbits2f(q1.y & 0xffff0000u)  + bb.w;
  *reinterpret_cast<float4*>(X1f + off) = v;

  float s  = v.x + v.y + v.z + v.w;
  float ss = v.x * v.x + v.y * v.y + v.z * v.z + v.w * v.w;
#pragma unroll
  for (int o = 32; o; o >>= 1) {
    s  += __shfl_down(s, o);
    ss += __shfl_down(ss, o);
  }
  __shared__ float red[16];
  const int wid = t >> 6, lane = t & 63;
  if (lane == 0) { red[wid] = s; red[8 + wid] = ss; }
  __syncthreads();
  if (t == 0) {
    red[0] = red[0] + red[1] + red[2] + red[3];
    red[8] = red[8] + red[9] + red[10] + red[11];
  }
  __syncthreads();
  const float mu   = red[0] * (1.0f / CC);
  const float var  = red[8] * (1.0f / CC) - mu * mu;
  const float rstd = rsqrtf(var + 1e-5f);
  float4 gg = reinterpret_cast<const float4*>(g)[t];
  float4 lb = reinterpret_cast<const float4*>(b)[t];
  uint2 st;
  st.x = cvt_pk_bf16((v.x - mu) * rstd * gg.x + lb.x, (v.y - mu) * rstd * gg.y + lb.y);
  st.y = cvt_pk_bf16((v.z - mu) * rstd * gg.z + lb.z, (v.w - mu) * rstd * gg.w + lb.w);
  *reinterpret_cast<uint2*>(Xn + off) = st;
}

// ---------------- FC2 reduce + bias + residual -> final out ----------------
__global__ __launch_bounds__(256) void reduce_fc2(const ushort* __restrict__ P0,
                                                  const ushort* __restrict__ P1,
                                                  const float* __restrict__ X1,
                                                  const float* __restrict__ b2,
                                                  float* __restrict__ out) {
  const int row = blockIdx.x, t = threadIdx.x;
  const size_t off = (size_t)row * CC + t * 4;
  float4 v  = *reinterpret_cast<const float4*>(X1 + off);
  const uint2 q0 = *reinterpret_cast<const uint2*>(P0 + off);
  const uint2 q1 = *reinterpret_cast<const uint2*>(P1 + off);
  float4 bb = reinterpret_cast<const float4*>(b2)[t];
  v.x += bfbits2f(q0.x << 16)          + bfbits2f(q1.x << 16)          + bb.x;
  v.y += bfbits2f(q0.x & 0xffff0000u)  + bfbits2f(q1.x & 0xffff0000u)  + bb.y;
  v.z += bfbits2f(q0.y << 16)          + bfbits2f(q1.y << 16)          + bb.z;
  v.w += bfbits2f(q0.y & 0xffff0000u)  + bfbits2f(q1.y & 0xffff0000u)  + bb.w;
  *reinterpret_cast<float4*>(out + off) = v;
}

// ---------------- MFMA flash attention, KV-split x2, 100%-occupancy single-buffer ----------------
// Grid 2048 blocks; XCD-aware remap puts 4 consecutive bh groups on each XCD (K/V L2-resident).
__global__ __launch_bounds__(256) void attn_partial(const ushort* __restrict__ qkv,
                                                    const ushort* __restrict__ Vt,
                                                    ushort* __restrict__ O0,
                                                    ushort* __restrict__ O1,
                                                    float2* __restrict__ ml) {
  __shared__ ushort Ks[64 * 64];
  __shared__ ushort Vs[64 * 64];
  const int t = threadIdx.x, lane = t & 63, w = t >> 6;
  const int g = lane >> 4, iq = lane & 15;
  // remap: work = (flat%8)*256 + flat/8; bh = work/64, z = (work%64)/32, qt = work%32
  const int flat = blockIdx.x;
  const int work = (flat & 7) * 256 + (flat >> 3);
  const int bh = work >> 6;
  const int rem = work & 63;
  const int z = rem >> 5;
  const int qt = rem & 31;
  const int b = bh >> 4, h = bh & 15;
  ushort* __restrict__ Obuf = z ? O1 : O0;

  // Q fragments in registers; scale = 1/sqrt(64) * log2(e) (exp2-domain softmax)
  bf16x8 qfrag[2];
  {
    const ushort* qrow = qkv + (size_t)(b * TT + qt * 64 + w * 16 + iq) * NQKV + h * 64;
    const float qs = 0.125f * 1.44269504f;
#pragma unroll
    for (int kk = 0; kk < 2; ++kk) {
      uint4 raw = *reinterpret_cast<const uint4*>(qrow + kk * 32 + g * 8);
      uint32_t rr[4] = {raw.x, raw.y, raw.z, raw.w};
      U84 tmp;
#pragma unroll
      for (int c = 0; c < 4; ++c) {
        float lo = bfbits2f(rr[c] << 16) * qs;
        float hi = bfbits2f(rr[c] & 0xffff0000u) * qs;
        tmp.u[c] = cvt_pk_bf16(lo, hi);
      }
      qfrag[kk] = tmp.v;
    }
  }

  const int sr1 = t >> 3, sc1 = t & 7;
  const int csw = (sc1 ^ (sr1 & 7)) * 8;   // pre-swizzled global col (linear LDS dest)
  const ushort* kbase = qkv + 1024 + h * 64;
  const ushort* vbase = Vt + (size_t)(bh * 64) * TT;
  char* kL1 = (char*)Ks + w * 1024;
  char* kL2 = (char*)Ks + 4096 + w * 1024;
  char* vL1 = (char*)Vs + w * 1024;
  char* vL2 = (char*)Vs + 4096 + w * 1024;

  float mrun = -3e38f, lrun = 0.f;
  f32x4 ot[4] = {};

  const int kt0 = z * 16;
  for (int kt = kt0; kt < kt0 + 16; ++kt) {
    __syncthreads();   // previous tile's readers done
    {
      const size_t tok = (size_t)(b * TT + kt * 64);
      __builtin_amdgcn_global_load_lds(AS1C(kbase + (tok + sr1) * NQKV + csw), AS3(kL1), 16, 0, 0);
      __builtin_amdgcn_global_load_lds(AS1C(kbase + (tok + 32 + sr1) * NQKV + csw), AS3(kL2), 16, 0, 0);
      __builtin_amdgcn_global_load_lds(AS1C(vbase + (size_t)sr1 * TT + kt * 64 + csw), AS3(vL1), 16, 0, 0);
      __builtin_amdgcn_global_load_lds(AS1C(vbase + (size_t)(32 + sr1) * TT + kt * 64 + csw), AS3(vL2), 16, 0, 0);
    }
    __syncthreads();   // loads landed

    // S^T = K @ Q^T : lane holds 16 scores for query iq, keys j = 16jf+4g+r
    f32x4 sfr[4] = {};
    __builtin_amdgcn_s_setprio(1);
#pragma unroll
    for (int kk = 0; kk < 2; ++kk)
#pragma unroll
      for (int jf = 0; jf < 4; ++jf) {
        const int row = iq + 16 * jf;
        const int off = row * 128 + ((kk * 64 + g * 16) ^ ((row & 7) << 4));
        bf16x8 a = *reinterpret_cast<const bf16x8*>((const char*)Ks + off);
        sfr[jf] = __builtin_amdgcn_mfma_f32_16x16x32_bf16(a, qfrag[kk], sfr[jf], 0, 0, 0);
      }
    __builtin_amdgcn_s_setprio(0);

    // online softmax (exp2 domain), defer-max THR=8
    float tm0 = fmaxf(fmaxf(sfr[0][0], sfr[0][1]), fmaxf(sfr[0][2], sfr[0][3]));
    float tm1 = fmaxf(fmaxf(sfr[1][0], sfr[1][1]), fmaxf(sfr[1][2], sfr[1][3]));
    float tm2 = fmaxf(fmaxf(sfr[2][0], sfr[2][1]), fmaxf(sfr[2][2], sfr[2][3]));
    float tm3 = fmaxf(fmaxf(sfr[3][0], sfr[3][1]), fmaxf(sfr[3][2], sfr[3][3]));
    float tmax = fmaxf(fmaxf(tm0, tm1), fmaxf(tm2, tm3));
    tmax = fmaxf(tmax, __shfl_xor(tmax, 16, 64));
    tmax = fmaxf(tmax, __shfl_xor(tmax, 32, 64));

    if (!__all(tmax <= mrun + 8.f)) {
      const float mnew  = fmaxf(mrun, tmax);
      const float alpha = exp2_fast(mrun - mnew);
      lrun *= alpha;
#pragma unroll
      for (int df = 0; df < 4; ++df)
#pragma unroll
        for (int r = 0; r < 4; ++r) ot[df][r] *= alpha;
      mrun = mnew;
    }

    float lsum = 0.f;
    uint32_t u[4][2];
#pragma unroll
    for (int f = 0; f < 4; ++f) {
      float p0 = exp2_fast(sfr[f][0] - mrun);
      float p1 = exp2_fast(sfr[f][1] - mrun);
      float p2 = exp2_fast(sfr[f][2] - mrun);
      float p3 = exp2_fast(sfr[f][3] - mrun);
      lsum += (p0 + p1) + (p2 + p3);
      u[f][0] = cvt_pk_bf16(p0, p1);
      u[f][1] = cvt_pk_bf16(p2, p3);
    }
    lsum += __shfl_xor(lsum, 16, 64);
    lsum += __shfl_xor(lsum, 32, 64);
    lrun += lsum;

    // PV: O^T = Vt @ P^T ; rebuild B-frag via quad-group shuffles
#pragma unroll
    for (int kk = 0; kk < 2; ++kk) {
      U84 bfr;
#pragma unroll
      for (int q = 0; q < 4; ++q) {
        const int srcl = (2 * (g & 1) + (q >> 1)) * 16 + iq;
        const uint32_t v0 = (uint32_t)__shfl((int)u[2 * kk + 0][q & 1], srcl, 64);
        const uint32_t v1 = (uint32_t)__shfl((int)u[2 * kk + 1][q & 1], srcl, 64);
        bfr.u[q] = (g & 2) ? v1 : v0;
      }
      __builtin_amdgcn_s_setprio(1);
#pragma unroll
      for (int df = 0; df < 4; ++df) {
        const int row = iq + 16 * df;
        const int off = row * 128 + ((kk * 64 + g * 16) ^ ((row & 7) << 4));
        bf16x8 a = *reinterpret_cast<const bf16x8*>((const char*)Vs + off);
        ot[df] = __builtin_amdgcn_mfma_f32_16x16x32_bf16(a, bfr.v, ot[df], 0, 0, 0);
      }
      __builtin_amdgcn_s_setprio(0);
    }
  }

  // epilogue: per-split normalized O (bf16) + (m, l)
  const int grow = b * TT + qt * 64 + w * 16 + iq;
  const float inv = 1.f / lrun;
  ushort* orow = Obuf + (size_t)grow * CC + h * 64;
#pragma unroll
  for (int df = 0; df < 4; ++df) {
    uint2 st;
    st.x = cvt_pk_bf16(ot[df][0] * inv, ot[df][1] * inv);
    st.y = cvt_pk_bf16(ot[df][2] * inv, ot[df][3] * inv);
    *reinterpret_cast<uint2*>(orow + df * 16 + g * 4) = st;
  }
  if (g == 0) ml[(size_t)z * (MM * 16) + grow * 16 + h] = make_float2(mrun, lrun);
}

// ---------------- combine the two KV-split partials -> Attn (bf16) ----------------
__global__ __launch_bounds__(256) void attn_combine(const ushort* __restrict__ O0,
                                                    const ushort* __restrict__ O1,
                                                    const float2* __restrict__ ml,
                                                    ushort* __restrict__ attnb) {
  const int row = blockIdx.x, t = threadIdx.x;
  const int h = t >> 4;
  const float2 a = ml[(size_t)row * 16 + h];
  const float2 c = ml[(size_t)MM * 16 + (size_t)row * 16 + h];
  const float m  = fmaxf(a.x, c.x);
  const float w0 = exp2_fast(a.x - m) * a.y;
  const float w1 = exp2_fast(c.x - m) * c.y;
  const float inv = 1.f / (w0 + w1);
  const float s0 = w0 * inv, s1 = w1 * inv;
  const size_t off = (size_t)row * CC + t * 4;
  const uint2 r0 = *reinterpret_cast<const uint2*>(O0 + off);
  const uint2 r1 = *reinterpret_cast<const uint2*>(O1 + off);
  const float o0 = bfbits2f(r0.x << 16)         * s0 + bfbits2f(r1.x << 16)         * s1;
  const float o1 = bfbits2f(r0.x & 0xffff0000u) * s0 + bfbits2f(r1.x & 0xffff0000u) * s1;
  const float o2 = bfbits2f(r0.y << 16)         * s0 + bfbits2f(r1.y << 16)         * s1;
  const float o3 = bfbits2f(r0.y & 0xffff0000u) * s0 + bfbits2f(r1.y & 0xffff0000u) * s1;
  uint2 st;
  st.x = cvt_pk_bf16(o0, o1);
  st.y = cvt_pk_bf16(o2, o3);
  *reinterpret_cast<uint2*>(attnb + off) = st;
}

// --------------------------------- launcher -------------------------------------
extern "C" void kernel_launch(void* const* d_in, const int* in_sizes, int n_in,
                              void* d_out, int out_size, void* d_ws, size_t ws_size,
                              hipStream_t stream) {
  const float* x     = (const float*)d_in[0];
  const float* ln1_g = (const float*)d_in[1];
  const float* ln1_b = (const float*)d_in[2];
  const float* ln2_g = (const float*)d_in[3];
  const float* ln2_b = (const float*)d_in[4];
  const float* Wq = (const float*)d_in[5];
  const float* bq = (const float*)d_in[6];
  const float* Wk = (const float*)d_in[7];
  const float* bk = (const float*)d_in[8];
  const float* Wv = (const float*)d_in[9];
  const float* bv = (const float*)d_in[10];
  const float* Wo = (const float*)d_in[11];
  const float* bo = (const float*)d_in[12];
  const float* W1 = (const float*)d_in[13];
  const float* b1 = (const float*)d_in[14];
  const float* W2 = (const float*)d_in[15];
  const float* b2 = (const float*)d_in[16];
  float* out = (float*)d_out;
  char* ws = (char*)d_ws;

  // workspace layout (92.3 MB total, unchanged footprint)
  ushort* WqkvT = (ushort*)(ws + 0);          // 3072x1024 bf16 (6 MB)
  ushort* WoT   = (ushort*)(ws + 6291456);    // 1024x1024 bf16 (2 MB)
  ushort* W1T   = (ushort*)(ws + 8388608);    // 4096x1024 bf16 (8 MB)
  ushort* W2T   = (ushort*)(ws + 16777216);   // 1024x4096 bf16 (8 MB)
  float*  Bqkv  = (float*) (ws + 25165824);   // 3072 f32
  ushort* Xn    = (ushort*)(ws + 25178112);   // 4096x1024 bf16 (8 MB)
  ushort* Attn  = (ushort*)(ws + 33566720);   // 4096x1024 bf16 (8 MB)
  float*  X1f   = (float*) (ws + 41955328);   // 4096x1024 f32 (16 MB)
  ushort* Qkv   = (ushort*)(ws + 58732544);   // 4096x3072 bf16 (24 MB)
  ushort* Vtb   = (ushort*)(ws + 83898368);   // 2048x2048 bf16 (8 MB)
  ushort* Hid   = (ushort*)(ws + 58732544);   // 4096x4096 bf16 (reuses Qkv+Vtb)
  // attention split partials: O0/O1 bf16 in X1f region (dead until reduce_wo_ln)
  ushort* OP0   = (ushort*)(ws + 41955328);   // 8 MB
  ushort* OP1   = (ushort*)(ws + 50343936);   // 8 MB
  float2* mlbuf = (float2*)(ws + 0);          // 1 MB (WqkvT dead after QKV gemm)
  // Wo split-K bf16 partials (dead Qkv region)
  ushort* WoP0  = (ushort*)(ws + 58732544);
  ushort* WoP1  = (ushort*)(ws + 67121152);
  // FC2 split-K bf16 partials (dead weight/Xn regions)
  ushort* F2P0  = (ushort*)(ws + 0);
  ushort* F2P1  = (ushort*)(ws + 25178112);

  const dim3 blk(256);

  transpose_w<<<dim3(32, 32), blk, 0, stream>>>(Wq, WqkvT, 1024, 1024, 0);
  transpose_w<<<dim3(32, 32), blk, 0, stream>>>(Wk, WqkvT, 1024, 1024, 1024);
  transpose_w<<<dim3(32, 32), blk, 0, stream>>>(Wv, WqkvT, 1024, 1024, 2048);
  transpose_w<<<dim3(32, 32), blk, 0, stream>>>(Wo, WoT, 1024, 1024, 0);
  transpose_w<<<dim3(128, 32), blk, 0, stream>>>(W1, W1T, 1024, 4096, 0);
  transpose_w<<<dim3(32, 128), blk, 0, stream>>>(W2, W2T, 4096, 1024, 0);
  concat_bias<<<dim3(12), blk, 0, stream>>>(bq, bk, bv, Bqkv);

  ln_kernel<<<dim3(MM), blk, 0, stream>>>(x, ln1_g, ln1_b, Xn);
  gemm_bf16<false, false, true><<<dim3(24, 32), blk, 0, stream>>>(Xn, WqkvT, Bqkv, nullptr, Qkv, NQKV, 1024);
  v_transpose<<<dim3(32, 32), blk, 0, stream>>>(Qkv, Vtb);
  attn_partial<<<dim3(2048), blk, 0, stream>>>(Qkv, Vtb, OP0, OP1, mlbuf);
  attn_combine<<<dim3(MM), blk, 0, stream>>>(OP0, OP1, mlbuf, Attn);
  gemm_splitk<<<dim3(8, 32, 2), blk, 0, stream>>>(Attn, WoT, WoP0, WoP1, 1024, 1024, 512);
  reduce_wo_ln<<<dim3(MM), blk, 0, stream>>>(WoP0, WoP1, x, bo, ln2_g, ln2_b, X1f, Xn);
  gemm_bf16<true, false, true><<<dim3(32, 32), blk, 0, stream>>>(Xn, W1T, b1, nullptr, Hid, HIDN, 1024);
  gemm_splitk<<<dim3(8, 32, 2), blk, 0, stream>>>(Hid, W2T, F2P0, F2P1, 1024, 4096, 2048);
  reduce_fc2<<<dim3(MM), blk, 0, stream>>>(F2P0, F2P1, X1f, b2, out);
}

// Round 6
// 297.716 us; speedup vs baseline: 10.0652x; 1.0511x over previous
//
#include <hip/hip_runtime.h>

typedef float f32x4 __attribute__((ext_vector_type(4)));
typedef __bf16 bf16x8 __attribute__((ext_vector_type(8)));

constexpr int TT   = 2048;
constexpr int CC   = 1024;
constexpr int HIDN = 4096;
constexpr int MM   = 4096;   // B*T rows
constexpr int NQKV = 3072;

union U84 { uint32_t u[4]; bf16x8 v; };

__device__ inline uint32_t cvt_pk_bf16(float lo, float hi) {
  uint32_t r;
  asm("v_cvt_pk_bf16_f32 %0, %1, %2" : "=v"(r) : "v"(lo), "v"(hi));
  return r;
}
__device__ inline ushort f2bf(float f) { return (ushort)(cvt_pk_bf16(f, 0.f) & 0xffffu); }
__device__ inline float bfbits2f(uint32_t bits) {
  union { uint32_t u; float f; } c; c.u = bits; return c.f;
}
__device__ inline float exp2_fast(float x) {
  float r;
  asm("v_exp_f32 %0, %1" : "=v"(r) : "v"(x));
  return r;
}

#define AS1C(p) ((__attribute__((address_space(1))) void*)(p))
#define AS3(p)  ((__attribute__((address_space(3))) void*)(p))

// ---------------- LayerNorm fp32 -> bf16, one block per row ----------------
__global__ __launch_bounds__(256) void ln_kernel(const float* __restrict__ x,
                                                 const float* __restrict__ g,
                                                 const float* __restrict__ b,
                                                 ushort* __restrict__ y) {
  const int row = blockIdx.x;
  const float4* xr = reinterpret_cast<const float4*>(x + (size_t)row * CC);
  float4 v = xr[threadIdx.x];
  float s  = v.x + v.y + v.z + v.w;
  float ss = v.x * v.x + v.y * v.y + v.z * v.z + v.w * v.w;
#pragma unroll
  for (int off = 32; off; off >>= 1) {
    s  += __shfl_down(s, off);
    ss += __shfl_down(ss, off);
  }
  __shared__ float red[16];
  const int wid = threadIdx.x >> 6, lane = threadIdx.x & 63;
  if (lane == 0) { red[wid] = s; red[8 + wid] = ss; }
  __syncthreads();
  if (threadIdx.x == 0) {
    red[0] = red[0] + red[1] + red[2] + red[3];
    red[8] = red[8] + red[9] + red[10] + red[11];
  }
  __syncthreads();
  const float mu   = red[0] * (1.0f / CC);
  const float var  = red[8] * (1.0f / CC) - mu * mu;
  const float rstd = rsqrtf(var + 1e-5f);
  float4 gg = reinterpret_cast<const float4*>(g)[threadIdx.x];
  float4 bb = reinterpret_cast<const float4*>(b)[threadIdx.x];
  uint2 st;
  st.x = cvt_pk_bf16((v.x - mu) * rstd * gg.x + bb.x, (v.y - mu) * rstd * gg.y + bb.y);
  st.y = cvt_pk_bf16((v.z - mu) * rstd * gg.z + bb.z, (v.w - mu) * rstd * gg.w + bb.w);
  *reinterpret_cast<uint2*>(y + (size_t)row * CC + threadIdx.x * 4) = st;
}

// ---------------- fused weight prep: all transposes + bias concat in one launch ----------------
__global__ __launch_bounds__(256) void prep_weights(const float* __restrict__ Wq,
                                                    const float* __restrict__ Wk,
                                                    const float* __restrict__ Wv,
                                                    const float* __restrict__ Wo,
                                                    const float* __restrict__ W1,
                                                    const float* __restrict__ W2,
                                                    const float* __restrict__ bq,
                                                    const float* __restrict__ bk,
                                                    const float* __restrict__ bv,
                                                    ushort* __restrict__ WqkvT,
                                                    ushort* __restrict__ WoT,
                                                    ushort* __restrict__ W1T,
                                                    ushort* __restrict__ W2T,
                                                    float* __restrict__ Bqkv) {
  const int id = blockIdx.x;
  const int t = threadIdx.x;
  if (id >= 12288) {   // bias concat: 12 blocks
    const int i = (id - 12288) * 256 + t;
    Bqkv[i] = (i < 1024) ? bq[i] : ((i < 2048) ? bk[i - 1024] : bv[i - 2048]);
    return;
  }
  const float* W; ushort* out; int Kd, Nd, bx, by, rowOff = 0;
  if (id < 4096) {
    const int which = id >> 10, sub = id & 1023;
    bx = sub & 31; by = sub >> 5; Kd = 1024; Nd = 1024;
    if (which == 0)      { W = Wq; out = WqkvT; rowOff = 0; }
    else if (which == 1) { W = Wk; out = WqkvT; rowOff = 1024; }
    else if (which == 2) { W = Wv; out = WqkvT; rowOff = 2048; }
    else                 { W = Wo; out = WoT; }
  } else if (id < 8192) {
    const int sub = id - 4096; bx = sub & 127; by = sub >> 7;
    W = W1; out = W1T; Kd = 1024; Nd = 4096;
  } else {
    const int sub = id - 8192; bx = sub & 31; by = sub >> 5;
    W = W2; out = W2T; Kd = 4096; Nd = 1024;
  }
  const int n0 = bx * 32, k0 = by * 32;
  __shared__ float Ts[32][33];
  {
    const int r = t >> 3, cb = (t & 7) * 4;
    float4 v = *reinterpret_cast<const float4*>(W + (size_t)(k0 + r) * Nd + n0 + cb);
    Ts[r][cb + 0] = v.x; Ts[r][cb + 1] = v.y; Ts[r][cb + 2] = v.z; Ts[r][cb + 3] = v.w;
  }
  __syncthreads();
  {
    const int nl = t >> 3, kb = (t & 7) * 4;
    uint2 st;
    st.x = cvt_pk_bf16(Ts[kb + 0][nl], Ts[kb + 1][nl]);
    st.y = cvt_pk_bf16(Ts[kb + 2][nl], Ts[kb + 3][nl]);
    *reinterpret_cast<uint2*>(out + (size_t)(rowOff + n0 + nl) * Kd + k0 + kb) = st;
  }
}

// ---------------- V transpose: qkv cols [2048..3071] -> Vt[bh*64+d][T] ----------------
__global__ __launch_bounds__(256) void v_transpose(const ushort* __restrict__ qkv,
                                                   ushort* __restrict__ Vt) {
  __shared__ ushort Ts[64][72];
  const int t = threadIdx.x;
  const int tt = blockIdx.x, bh = blockIdx.y;
  const int b = bh >> 4, h = bh & 15;
#pragma unroll
  for (int c2 = 0; c2 < 2; ++c2) {
    const int e = t + 256 * c2;
    const int r = e >> 3, c = e & 7;
    uint4 raw = *reinterpret_cast<const uint4*>(
        qkv + (size_t)(b * TT + tt * 64 + r) * NQKV + 2048 + h * 64 + c * 8);
    *reinterpret_cast<uint4*>(&Ts[r][c * 8]) = raw;
  }
  __syncthreads();
  const int d = t >> 2, tkb = (t & 3) * 16;
  uint32_t wv[8];
#pragma unroll
  for (int j = 0; j < 8; ++j)
    wv[j] = (uint32_t)Ts[tkb + 2 * j][d] | ((uint32_t)Ts[tkb + 2 * j + 1][d] << 16);
  ushort* op = Vt + (size_t)(bh * 64 + d) * TT + tt * 64 + tkb;
  uint4 s0; s0.x = wv[0]; s0.y = wv[1]; s0.z = wv[2]; s0.w = wv[3];
  uint4 s1; s1.x = wv[4]; s1.y = wv[5]; s1.z = wv[6]; s1.w = wv[7];
  *reinterpret_cast<uint4*>(op) = s0;
  *reinterpret_cast<uint4*>(op + 8) = s1;
}

// ---------------- bf16 MFMA GEMM (m97 structure): C = A[M,K] @ Bt[N,K]^T ----------------
template <bool RELU, bool RES, bool OUTBF>
__global__ __launch_bounds__(256) void gemm_bf16(const ushort* __restrict__ A,
                                                 const ushort* __restrict__ Bt,
                                                 const float* __restrict__ bias,
                                                 const float* __restrict__ res,
                                                 void* __restrict__ outp,
                                                 int N, int K) {
  __shared__ ushort As[128 * 32];
  __shared__ ushort Bs[128 * 32];
  const int t = threadIdx.x;
  const int lane = t & 63, w = t >> 6;
  const int g = lane >> 4, i16 = lane & 15;
  const int wrow = w >> 1, wcol = w & 1;
  const int nwg  = gridDim.x * gridDim.y;
  const int orig = blockIdx.y * gridDim.x + blockIdx.x;
  const int sw   = (orig & 7) * (nwg >> 3) + (orig >> 3);
  const int row0 = (sw / gridDim.x) * 128, col0 = (sw % gridDim.x) * 128;

  f32x4 acc[4][4] = {};

  const int srow = t >> 2, sc = (t & 3) * 8;
  const ushort* aS1 = A + (size_t)(row0 + srow) * K + sc;
  const ushort* aS2 = A + (size_t)(row0 + 64 + srow) * K + sc;
  const ushort* bS1 = Bt + (size_t)(col0 + srow) * K + sc;
  const ushort* bS2 = Bt + (size_t)(col0 + 64 + srow) * K + sc;
  char* aL1 = (char*)As + w * 1024;
  char* aL2 = (char*)As + 4096 + w * 1024;
  char* bL1 = (char*)Bs + w * 1024;
  char* bL2 = (char*)Bs + 4096 + w * 1024;

  for (int k0 = 0; k0 < K; k0 += 32) {
    __syncthreads();
    __builtin_amdgcn_global_load_lds(AS1C(aS1 + k0), AS3(aL1), 16, 0, 0);
    __builtin_amdgcn_global_load_lds(AS1C(aS2 + k0), AS3(aL2), 16, 0, 0);
    __builtin_amdgcn_global_load_lds(AS1C(bS1 + k0), AS3(bL1), 16, 0, 0);
    __builtin_amdgcn_global_load_lds(AS1C(bS2 + k0), AS3(bL2), 16, 0, 0);
    __syncthreads();

    bf16x8 a4[4], b4[4];
#pragma unroll
    for (int mf = 0; mf < 4; ++mf) {
      const int r = wrow * 64 + mf * 16 + i16;
      a4[mf] = *reinterpret_cast<const bf16x8*>((const char*)As + r * 64 + g * 16);
    }
#pragma unroll
    for (int nf = 0; nf < 4; ++nf) {
      const int c = wcol * 64 + nf * 16 + i16;
      b4[nf] = *reinterpret_cast<const bf16x8*>((const char*)Bs + c * 64 + g * 16);
    }
#pragma unroll
    for (int mf = 0; mf < 4; ++mf)
#pragma unroll
      for (int nf = 0; nf < 4; ++nf)
        acc[mf][nf] = __builtin_amdgcn_mfma_f32_16x16x32_bf16(a4[mf], b4[nf], acc[mf][nf], 0, 0, 0);
  }

#pragma unroll
  for (int nf = 0; nf < 4; ++nf) {
    const int ncol = col0 + wcol * 64 + nf * 16 + i16;
    const float bb = bias[ncol];
#pragma unroll
    for (int mf = 0; mf < 4; ++mf) {
      const int mrow = row0 + wrow * 64 + mf * 16 + 4 * g;
#pragma unroll
      for (int r = 0; r < 4; ++r) {
        float v = acc[mf][nf][r] + bb;
        if (RELU) v = fmaxf(v, 0.f);
        const size_t off = (size_t)(mrow + r) * N + ncol;
        if (RES) v += res[off];
        if (OUTBF) ((ushort*)outp)[off] = f2bf(v);
        else       ((float*)outp)[off]  = v;
      }
    }
  }
}

// ---------------- split-K (4-way) bf16 MFMA GEMM, bf16 partials ----------------
__global__ __launch_bounds__(256) void gemm_splitk(const ushort* __restrict__ A,
                                                   const ushort* __restrict__ Bt,
                                                   ushort* __restrict__ P0,
                                                   ushort* __restrict__ P1,
                                                   ushort* __restrict__ P2,
                                                   ushort* __restrict__ P3,
                                                   int N, int K, int Kchunk) {
  __shared__ ushort As[128 * 32];
  __shared__ ushort Bs[128 * 32];
  const int t = threadIdx.x;
  const int lane = t & 63, w = t >> 6;
  const int g = lane >> 4, i16 = lane & 15;
  const int wrow = w >> 1, wcol = w & 1;
  const int nwg  = gridDim.x * gridDim.y;
  const int orig = blockIdx.y * gridDim.x + blockIdx.x;
  const int sw   = (orig & 7) * (nwg >> 3) + (orig >> 3);
  const int row0 = (sw / gridDim.x) * 128, col0 = (sw % gridDim.x) * 128;
  const int kstart = blockIdx.z * Kchunk;
  ushort* __restrict__ P = (blockIdx.z == 0) ? P0 : (blockIdx.z == 1) ? P1
                          : (blockIdx.z == 2) ? P2 : P3;

  f32x4 acc[4][4] = {};

  const int srow = t >> 2, sc = (t & 3) * 8;
  const ushort* aS1 = A + (size_t)(row0 + srow) * K + sc;
  const ushort* aS2 = A + (size_t)(row0 + 64 + srow) * K + sc;
  const ushort* bS1 = Bt + (size_t)(col0 + srow) * K + sc;
  const ushort* bS2 = Bt + (size_t)(col0 + 64 + srow) * K + sc;
  char* aL1 = (char*)As + w * 1024;
  char* aL2 = (char*)As + 4096 + w * 1024;
  char* bL1 = (char*)Bs + w * 1024;
  char* bL2 = (char*)Bs + 4096 + w * 1024;

  for (int k0 = kstart; k0 < kstart + Kchunk; k0 += 32) {
    __syncthreads();
    __builtin_amdgcn_global_load_lds(AS1C(aS1 + k0), AS3(aL1), 16, 0, 0);
    __builtin_amdgcn_global_load_lds(AS1C(aS2 + k0), AS3(aL2), 16, 0, 0);
    __builtin_amdgcn_global_load_lds(AS1C(bS1 + k0), AS3(bL1), 16, 0, 0);
    __builtin_amdgcn_global_load_lds(AS1C(bS2 + k0), AS3(bL2), 16, 0, 0);
    __syncthreads();

    bf16x8 a4[4], b4[4];
#pragma unroll
    for (int mf = 0; mf < 4; ++mf) {
      const int r = wrow * 64 + mf * 16 + i16;
      a4[mf] = *reinterpret_cast<const bf16x8*>((const char*)As + r * 64 + g * 16);
    }
#pragma unroll
    for (int nf = 0; nf < 4; ++nf) {
      const int c = wcol * 64 + nf * 16 + i16;
      b4[nf] = *reinterpret_cast<const bf16x8*>((const char*)Bs + c * 64 + g * 16);
    }
#pragma unroll
    for (int mf = 0; mf < 4; ++mf)
#pragma unroll
      for (int nf = 0; nf < 4; ++nf)
        acc[mf][nf] = __builtin_amdgcn_mfma_f32_16x16x32_bf16(a4[mf], b4[nf], acc[mf][nf], 0, 0, 0);
  }

#pragma unroll
  for (int nf = 0; nf < 4; ++nf) {
    const int ncol = col0 + wcol * 64 + nf * 16 + i16;
#pragma unroll
    for (int mf = 0; mf < 4; ++mf) {
      const int mrow = row0 + wrow * 64 + mf * 16 + 4 * g;
#pragma unroll
      for (int r = 0; r < 4; ++r)
        P[(size_t)(mrow + r) * N + ncol] = f2bf(acc[mf][nf][r]);
    }
  }
}

__device__ inline float bfsum4(uint32_t a, uint32_t b, uint32_t c, uint32_t d, bool hi) {
  if (hi) return bfbits2f(a & 0xffff0000u) + bfbits2f(b & 0xffff0000u) +
                 bfbits2f(c & 0xffff0000u) + bfbits2f(d & 0xffff0000u);
  return bfbits2f(a << 16) + bfbits2f(b << 16) + bfbits2f(c << 16) + bfbits2f(d << 16);
}

// ---------------- Wo reduce (4 partials) + residual + LN2 fused ----------------
__global__ __launch_bounds__(256) void reduce_wo_ln(const ushort* __restrict__ P0,
                                                    const ushort* __restrict__ P1,
                                                    const ushort* __restrict__ P2,
                                                    const ushort* __restrict__ P3,
                                                    const float* __restrict__ x,
                                                    const float* __restrict__ bo,
                                                    const float* __restrict__ g,
                                                    const float* __restrict__ b,
                                                    float* __restrict__ X1f,
                                                    ushort* __restrict__ Xn) {
  const int row = blockIdx.x, t = threadIdx.x;
  const size_t off = (size_t)row * CC + t * 4;
  float4 v  = *reinterpret_cast<const float4*>(x + off);
  const uint2 q0 = *reinterpret_cast<const uint2*>(P0 + off);
  const uint2 q1 = *reinterpret_cast<const uint2*>(P1 + off);
  const uint2 q2 = *reinterpret_cast<const uint2*>(P2 + off);
  const uint2 q3 = *reinterpret_cast<const uint2*>(P3 + off);
  float4 bb = reinterpret_cast<const float4*>(bo)[t];
  v.x += bfsum4(q0.x, q1.x, q2.x, q3.x, false) + bb.x;
  v.y += bfsum4(q0.x, q1.x, q2.x, q3.x, true)  + bb.y;
  v.z += bfsum4(q0.y, q1.y, q2.y, q3.y, false) + bb.z;
  v.w += bfsum4(q0.y, q1.y, q2.y, q3.y, true)  + bb.w;
  *reinterpret_cast<float4*>(X1f + off) = v;

  float s  = v.x + v.y + v.z + v.w;
  float ss = v.x * v.x + v.y * v.y + v.z * v.z + v.w * v.w;
#pragma unroll
  for (int o = 32; o; o >>= 1) {
    s  += __shfl_down(s, o);
    ss += __shfl_down(ss, o);
  }
  __shared__ float red[16];
  const int wid = t >> 6, lane = t & 63;
  if (lane == 0) { red[wid] = s; red[8 + wid] = ss; }
  __syncthreads();
  if (t == 0) {
    red[0] = red[0] + red[1] + red[2] + red[3];
    red[8] = red[8] + red[9] + red[10] + red[11];
  }
  __syncthreads();
  const float mu   = red[0] * (1.0f / CC);
  const float var  = red[8] * (1.0f / CC) - mu * mu;
  const float rstd = rsqrtf(var + 1e-5f);
  float4 gg = reinterpret_cast<const float4*>(g)[t];
  float4 lb = reinterpret_cast<const float4*>(b)[t];
  uint2 st;
  st.x = cvt_pk_bf16((v.x - mu) * rstd * gg.x + lb.x, (v.y - mu) * rstd * gg.y + lb.y);
  st.y = cvt_pk_bf16((v.z - mu) * rstd * gg.z + lb.z, (v.w - mu) * rstd * gg.w + lb.w);
  *reinterpret_cast<uint2*>(Xn + off) = st;
}

// ---------------- FC2 reduce (4 partials) + bias + residual -> final out ----------------
__global__ __launch_bounds__(256) void reduce_fc2(const ushort* __restrict__ P0,
                                                  const ushort* __restrict__ P1,
                                                  const ushort* __restrict__ P2,
                                                  const ushort* __restrict__ P3,
                                                  const float* __restrict__ X1,
                                                  const float* __restrict__ b2,
                                                  float* __restrict__ out) {
  const int row = blockIdx.x, t = threadIdx.x;
  const size_t off = (size_t)row * CC + t * 4;
  float4 v  = *reinterpret_cast<const float4*>(X1 + off);
  const uint2 q0 = *reinterpret_cast<const uint2*>(P0 + off);
  const uint2 q1 = *reinterpret_cast<const uint2*>(P1 + off);
  const uint2 q2 = *reinterpret_cast<const uint2*>(P2 + off);
  const uint2 q3 = *reinterpret_cast<const uint2*>(P3 + off);
  float4 bb = reinterpret_cast<const float4*>(b2)[t];
  v.x += bfsum4(q0.x, q1.x, q2.x, q3.x, false) + bb.x;
  v.y += bfsum4(q0.x, q1.x, q2.x, q3.x, true)  + bb.y;
  v.z += bfsum4(q0.y, q1.y, q2.y, q3.y, false) + bb.z;
  v.w += bfsum4(q0.y, q1.y, q2.y, q3.y, true)  + bb.w;
  *reinterpret_cast<float4*>(out + off) = v;
}

// ---------------- MFMA flash attention, KV-split x2, P-through-LDS (no bpermute) ----------------
__global__ __launch_bounds__(256) void attn_partial(const ushort* __restrict__ qkv,
                                                    const ushort* __restrict__ Vt,
                                                    ushort* __restrict__ O0,
                                                    ushort* __restrict__ O1,
                                                    float2* __restrict__ ml) {
  __shared__ ushort Ks[64 * 64];
  __shared__ ushort Vs[64 * 64];
  __shared__ uint32_t Ps[4][16][36];   // per-wave P strip, [query][packed key-pair], pad 36
  const int t = threadIdx.x, lane = t & 63, w = t >> 6;
  const int g = lane >> 4, iq = lane & 15;
  const int flat = blockIdx.x;
  const int work = (flat & 7) * 256 + (flat >> 3);
  const int bh = work >> 6;
  const int rem = work & 63;
  const int z = rem >> 5;
  const int qt = rem & 31;
  const int b = bh >> 4, h = bh & 15;
  ushort* __restrict__ Obuf = z ? O1 : O0;

  // Q fragments in registers; scale = 1/sqrt(64) * log2(e) (exp2-domain softmax)
  bf16x8 qfrag[2];
  {
    const ushort* qrow = qkv + (size_t)(b * TT + qt * 64 + w * 16 + iq) * NQKV + h * 64;
    const float qs = 0.125f * 1.44269504f;
#pragma unroll
    for (int kk = 0; kk < 2; ++kk) {
      uint4 raw = *reinterpret_cast<const uint4*>(qrow + kk * 32 + g * 8);
      uint32_t rr[4] = {raw.x, raw.y, raw.z, raw.w};
      U84 tmp;
#pragma unroll
      for (int c = 0; c < 4; ++c) {
        float lo = bfbits2f(rr[c] << 16) * qs;
        float hi = bfbits2f(rr[c] & 0xffff0000u) * qs;
        tmp.u[c] = cvt_pk_bf16(lo, hi);
      }
      qfrag[kk] = tmp.v;
    }
  }

  const int sr1 = t >> 3, sc1 = t & 7;
  const int csw = (sc1 ^ (sr1 & 7)) * 8;   // pre-swizzled global col (linear LDS dest)
  const ushort* kbase = qkv + 1024 + h * 64;
  const ushort* vbase = Vt + (size_t)(bh * 64) * TT;
  char* kL1 = (char*)Ks + w * 1024;
  char* kL2 = (char*)Ks + 4096 + w * 1024;
  char* vL1 = (char*)Vs + w * 1024;
  char* vL2 = (char*)Vs + 4096 + w * 1024;

  // P-strip addressing: u32 col XOR 16 for iq>=8 -> 2-way (free) write banks
  uint32_t (*pw)[36] = Ps[w];
  const int wsw = (iq & 8) << 1;           // 0 or 16 (u32 cols)
  const int xsb = wsw << 2;                // 0 or 64 (bytes)
  const char* prow = (const char*)&pw[iq][0];

  float mrun = -3e38f, lrun = 0.f;
  f32x4 ot[4] = {};

  const int kt0 = z * 16;
  for (int kt = kt0; kt < kt0 + 16; ++kt) {
    __syncthreads();   // previous tile's readers done
    {
      const size_t tok = (size_t)(b * TT + kt * 64);
      __builtin_amdgcn_global_load_lds(AS1C(kbase + (tok + sr1) * NQKV + csw), AS3(kL1), 16, 0, 0);
      __builtin_amdgcn_global_load_lds(AS1C(kbase + (tok + 32 + sr1) * NQKV + csw), AS3(kL2), 16, 0, 0);
      __builtin_amdgcn_global_load_lds(AS1C(vbase + (size_t)sr1 * TT + kt * 64 + csw), AS3(vL1), 16, 0, 0);
      __builtin_amdgcn_global_load_lds(AS1C(vbase + (size_t)(32 + sr1) * TT + kt * 64 + csw), AS3(vL2), 16, 0, 0);
    }
    __syncthreads();   // loads landed

    // S^T = K @ Q^T : lane holds 16 scores for query iq, keys j = 16jf+4g+r
    f32x4 sfr[4] = {};
    __builtin_amdgcn_s_setprio(1);
#pragma unroll
    for (int kk = 0; kk < 2; ++kk)
#pragma unroll
      for (int jf = 0; jf < 4; ++jf) {
        const int row = iq + 16 * jf;
        const int off = row * 128 + ((kk * 64 + g * 16) ^ ((row & 7) << 4));
        bf16x8 a = *reinterpret_cast<const bf16x8*>((const char*)Ks + off);
        sfr[jf] = __builtin_amdgcn_mfma_f32_16x16x32_bf16(a, qfrag[kk], sfr[jf], 0, 0, 0);
      }
    __builtin_amdgcn_s_setprio(0);

    // online softmax (exp2 domain), defer-max THR=8; lsum stays lane-partial
    float tm0 = fmaxf(fmaxf(sfr[0][0], sfr[0][1]), fmaxf(sfr[0][2], sfr[0][3]));
    float tm1 = fmaxf(fmaxf(sfr[1][0], sfr[1][1]), fmaxf(sfr[1][2], sfr[1][3]));
    float tm2 = fmaxf(fmaxf(sfr[2][0], sfr[2][1]), fmaxf(sfr[2][2], sfr[2][3]));
    float tm3 = fmaxf(fmaxf(sfr[3][0], sfr[3][1]), fmaxf(sfr[3][2], sfr[3][3]));
    float tmax = fmaxf(fmaxf(tm0, tm1), fmaxf(tm2, tm3));
    tmax = fmaxf(tmax, __shfl_xor(tmax, 16, 64));
    tmax = fmaxf(tmax, __shfl_xor(tmax, 32, 64));

    if (!__all(tmax <= mrun + 8.f)) {
      const float mnew  = fmaxf(mrun, tmax);
      const float alpha = exp2_fast(mrun - mnew);
      lrun *= alpha;
#pragma unroll
      for (int df = 0; df < 4; ++df)
#pragma unroll
        for (int r = 0; r < 4; ++r) ot[df][r] *= alpha;
      mrun = mnew;
    }

#pragma unroll
    for (int f = 0; f < 4; ++f) {
      float p0 = exp2_fast(sfr[f][0] - mrun);
      float p1 = exp2_fast(sfr[f][1] - mrun);
      float p2 = exp2_fast(sfr[f][2] - mrun);
      float p3 = exp2_fast(sfr[f][3] - mrun);
      lrun += (p0 + p1) + (p2 + p3);
      pw[iq][(8 * f + 2 * g + 0) ^ wsw] = cvt_pk_bf16(p0, p1);
      pw[iq][(8 * f + 2 * g + 1) ^ wsw] = cvt_pk_bf16(p2, p3);
    }
    asm volatile("s_waitcnt lgkmcnt(0)" ::: "memory");   // wave-local: P strip visible

    // PV: O^T = Vt @ P^T ; B-frag read straight from the P strip
    __builtin_amdgcn_s_setprio(1);
#pragma unroll
    for (int kk = 0; kk < 2; ++kk) {
      bf16x8 pb = *reinterpret_cast<const bf16x8*>(prow + ((kk * 64 + g * 16) ^ xsb));
#pragma unroll
      for (int df = 0; df < 4; ++df) {
        const int row = iq + 16 * df;
        const int off = row * 128 + ((kk * 64 + g * 16) ^ ((row & 7) << 4));
        bf16x8 a = *reinterpret_cast<const bf16x8*>((const char*)Vs + off);
        ot[df] = __builtin_amdgcn_mfma_f32_16x16x32_bf16(a, pb, ot[df], 0, 0, 0);
      }
    }
    __builtin_amdgcn_s_setprio(0);
  }

  // epilogue: finish deferred lsum reduce across the 4 g-groups, then write partials
  lrun += __shfl_xor(lrun, 16, 64);
  lrun += __shfl_xor(lrun, 32, 64);
  const int grow = b * TT + qt * 64 + w * 16 + iq;
  const float inv = 1.f / lrun;
  ushort* orow = Obuf + (size_t)grow * CC + h * 64;
#pragma unroll
  for (int df = 0; df < 4; ++df) {
    uint2 st;
    st.x = cvt_pk_bf16(ot[df][0] * inv, ot[df][1] * inv);
    st.y = cvt_pk_bf16(ot[df][2] * inv, ot[df][3] * inv);
    *reinterpret_cast<uint2*>(orow + df * 16 + g * 4) = st;
  }
  if (g == 0) ml[(size_t)z * (MM * 16) + grow * 16 + h] = make_float2(mrun, lrun);
}

// ---------------- combine the two KV-split partials -> Attn (bf16) ----------------
__global__ __launch_bounds__(256) void attn_combine(const ushort* __restrict__ O0,
                                                    const ushort* __restrict__ O1,
                                                    const float2* __restrict__ ml,
                                                    ushort* __restrict__ attnb) {
  const int row = blockIdx.x, t = threadIdx.x;
  const int h = t >> 4;
  const float2 a = ml[(size_t)row * 16 + h];
  const float2 c = ml[(size_t)MM * 16 + (size_t)row * 16 + h];
  const float m  = fmaxf(a.x, c.x);
  const float w0 = exp2_fast(a.x - m) * a.y;
  const float w1 = exp2_fast(c.x - m) * c.y;
  const float inv = 1.f / (w0 + w1);
  const float s0 = w0 * inv, s1 = w1 * inv;
  const size_t off = (size_t)row * CC + t * 4;
  const uint2 r0 = *reinterpret_cast<const uint2*>(O0 + off);
  const uint2 r1 = *reinterpret_cast<const uint2*>(O1 + off);
  const float o0 = bfbits2f(r0.x << 16)         * s0 + bfbits2f(r1.x << 16)         * s1;
  const float o1 = bfbits2f(r0.x & 0xffff0000u) * s0 + bfbits2f(r1.x & 0xffff0000u) * s1;
  const float o2 = bfbits2f(r0.y << 16)         * s0 + bfbits2f(r1.y << 16)         * s1;
  const float o3 = bfbits2f(r0.y & 0xffff0000u) * s0 + bfbits2f(r1.y & 0xffff0000u) * s1;
  uint2 st;
  st.x = cvt_pk_bf16(o0, o1);
  st.y = cvt_pk_bf16(o2, o3);
  *reinterpret_cast<uint2*>(attnb + off) = st;
}

// --------------------------------- launcher -------------------------------------
extern "C" void kernel_launch(void* const* d_in, const int* in_sizes, int n_in,
                              void* d_out, int out_size, void* d_ws, size_t ws_size,
                              hipStream_t stream) {
  const float* x     = (const float*)d_in[0];
  const float* ln1_g = (const float*)d_in[1];
  const float* ln1_b = (const float*)d_in[2];
  const float* ln2_g = (const float*)d_in[3];
  const float* ln2_b = (const float*)d_in[4];
  const float* Wq = (const float*)d_in[5];
  const float* bq = (const float*)d_in[6];
  const float* Wk = (const float*)d_in[7];
  const float* bk = (const float*)d_in[8];
  const float* Wv = (const float*)d_in[9];
  const float* bv = (const float*)d_in[10];
  const float* Wo = (const float*)d_in[11];
  const float* bo = (const float*)d_in[12];
  const float* W1 = (const float*)d_in[13];
  const float* b1 = (const float*)d_in[14];
  const float* W2 = (const float*)d_in[15];
  const float* b2 = (const float*)d_in[16];
  float* out = (float*)d_out;
  char* ws = (char*)d_ws;

  // workspace layout (92.3 MB total, unchanged footprint)
  ushort* WqkvT = (ushort*)(ws + 0);          // 3072x1024 bf16 (6 MB)
  ushort* WoT   = (ushort*)(ws + 6291456);    // 1024x1024 bf16 (2 MB)
  ushort* W1T   = (ushort*)(ws + 8388608);    // 4096x1024 bf16 (8 MB)
  ushort* W2T   = (ushort*)(ws + 16777216);   // 1024x4096 bf16 (8 MB)
  float*  Bqkv  = (float*) (ws + 25165824);   // 3072 f32
  ushort* Xn    = (ushort*)(ws + 25178112);   // 4096x1024 bf16 (8 MB)
  ushort* Attn  = (ushort*)(ws + 33566720);   // 4096x1024 bf16 (8 MB)
  float*  X1f   = (float*) (ws + 41955328);   // 4096x1024 f32 (16 MB)
  ushort* Qkv   = (ushort*)(ws + 58732544);   // 4096x3072 bf16 (24 MB)
  ushort* Vtb   = (ushort*)(ws + 83898368);   // 2048x2048 bf16 (8 MB)
  ushort* Hid   = (ushort*)(ws + 58732544);   // 4096x4096 bf16 (reuses Qkv+Vtb)
  // attention split partials: O0/O1 bf16 in X1f region (dead until reduce_wo_ln)
  ushort* OP0   = (ushort*)(ws + 41955328);   // 8 MB
  ushort* OP1   = (ushort*)(ws + 50343936);   // 8 MB
  float2* mlbuf = (float2*)(ws + 0);          // 1 MB (WqkvT dead after QKV gemm)
  // Wo split-K4 bf16 partials: dead Qkv+Vtb region, exactly 4 x 8 MB
  ushort* WoP0  = (ushort*)(ws + 58732544);
  ushort* WoP1  = (ushort*)(ws + 67121152);
  ushort* WoP2  = (ushort*)(ws + 75509760);
  ushort* WoP3  = (ushort*)(ws + 83898368);
  // FC2 split-K4 bf16 partials: dead {WqkvT+WoT}, {W1T}, {Xn}, {Attn} regions
  ushort* F2P0  = (ushort*)(ws + 0);
  ushort* F2P1  = (ushort*)(ws + 8388608);
  ushort* F2P2  = (ushort*)(ws + 25178112);
  ushort* F2P3  = (ushort*)(ws + 33566720);

  const dim3 blk(256);

  prep_weights<<<dim3(12300), blk, 0, stream>>>(Wq, Wk, Wv, Wo, W1, W2, bq, bk, bv,
                                                WqkvT, WoT, W1T, W2T, Bqkv);
  ln_kernel<<<dim3(MM), blk, 0, stream>>>(x, ln1_g, ln1_b, Xn);
  gemm_bf16<false, false, true><<<dim3(24, 32), blk, 0, stream>>>(Xn, WqkvT, Bqkv, nullptr, Qkv, NQKV, 1024);
  v_transpose<<<dim3(32, 32), blk, 0, stream>>>(Qkv, Vtb);
  attn_partial<<<dim3(2048), blk, 0, stream>>>(Qkv, Vtb, OP0, OP1, mlbuf);
  attn_combine<<<dim3(MM), blk, 0, stream>>>(OP0, OP1, mlbuf, Attn);
  gemm_splitk<<<dim3(8, 32, 4), blk, 0, stream>>>(Attn, WoT, WoP0, WoP1, WoP2, WoP3, 1024, 1024, 256);
  reduce_wo_ln<<<dim3(MM), blk, 0, stream>>>(WoP0, WoP1, WoP2, WoP3, x, bo, ln2_g, ln2_b, X1f, Xn);
  gemm_bf16<true, false, true><<<dim3(32, 32), blk, 0, stream>>>(Xn, W1T, b1, nullptr, Hid, HIDN, 1024);
  gemm_splitk<<<dim3(8, 32, 4), blk, 0, stream>>>(Hid, W2T, F2P0, F2P1, F2P2, F2P3, 1024, 4096, 1024);
  reduce_fc2<<<dim3(MM), blk, 0, stream>>>(F2P0, F2P1, F2P2, F2P3, X1f, b2, out);
}

// Round 7
// 282.937 us; speedup vs baseline: 10.5910x; 1.0522x over previous
//
#include <hip/hip_runtime.h>

typedef float f32x4 __attribute__((ext_vector_type(4)));
typedef __bf16 bf16x8 __attribute__((ext_vector_type(8)));

constexpr int TT   = 2048;
constexpr int CC   = 1024;
constexpr int HIDN = 4096;
constexpr int MM   = 4096;   // B*T rows
constexpr int NQKV = 3072;

union U84 { uint32_t u[4]; bf16x8 v; };

__device__ inline uint32_t cvt_pk_bf16(float lo, float hi) {
  uint32_t r;
  asm("v_cvt_pk_bf16_f32 %0, %1, %2" : "=v"(r) : "v"(lo), "v"(hi));
  return r;
}
__device__ inline ushort f2bf(float f) { return (ushort)(cvt_pk_bf16(f, 0.f) & 0xffffu); }
__device__ inline float bfbits2f(uint32_t bits) {
  union { uint32_t u; float f; } c; c.u = bits; return c.f;
}
__device__ inline float exp2_fast(float x) {
  float r;
  asm("v_exp_f32 %0, %1" : "=v"(r) : "v"(x));
  return r;
}

#define AS1C(p) ((__attribute__((address_space(1))) void*)(p))
#define AS3(p)  ((__attribute__((address_space(3))) void*)(p))

// ---------------- LayerNorm fp32 -> bf16, one block per row ----------------
__global__ __launch_bounds__(256) void ln_kernel(const float* __restrict__ x,
                                                 const float* __restrict__ g,
                                                 const float* __restrict__ b,
                                                 ushort* __restrict__ y) {
  const int row = blockIdx.x;
  const float4* xr = reinterpret_cast<const float4*>(x + (size_t)row * CC);
  float4 v = xr[threadIdx.x];
  float s  = v.x + v.y + v.z + v.w;
  float ss = v.x * v.x + v.y * v.y + v.z * v.z + v.w * v.w;
#pragma unroll
  for (int off = 32; off; off >>= 1) {
    s  += __shfl_down(s, off);
    ss += __shfl_down(ss, off);
  }
  __shared__ float red[16];
  const int wid = threadIdx.x >> 6, lane = threadIdx.x & 63;
  if (lane == 0) { red[wid] = s; red[8 + wid] = ss; }
  __syncthreads();
  if (threadIdx.x == 0) {
    red[0] = red[0] + red[1] + red[2] + red[3];
    red[8] = red[8] + red[9] + red[10] + red[11];
  }
  __syncthreads();
  const float mu   = red[0] * (1.0f / CC);
  const float var  = red[8] * (1.0f / CC) - mu * mu;
  const float rstd = rsqrtf(var + 1e-5f);
  float4 gg = reinterpret_cast<const float4*>(g)[threadIdx.x];
  float4 bb = reinterpret_cast<const float4*>(b)[threadIdx.x];
  uint2 st;
  st.x = cvt_pk_bf16((v.x - mu) * rstd * gg.x + bb.x, (v.y - mu) * rstd * gg.y + bb.y);
  st.y = cvt_pk_bf16((v.z - mu) * rstd * gg.z + bb.z, (v.w - mu) * rstd * gg.w + bb.w);
  *reinterpret_cast<uint2*>(y + (size_t)row * CC + threadIdx.x * 4) = st;
}

// ---------------- fused weight prep: all transposes + bias concat in one launch ----------------
__global__ __launch_bounds__(256) void prep_weights(const float* __restrict__ Wq,
                                                    const float* __restrict__ Wk,
                                                    const float* __restrict__ Wv,
                                                    const float* __restrict__ Wo,
                                                    const float* __restrict__ W1,
                                                    const float* __restrict__ W2,
                                                    const float* __restrict__ bq,
                                                    const float* __restrict__ bk,
                                                    const float* __restrict__ bv,
                                                    ushort* __restrict__ WqkvT,
                                                    ushort* __restrict__ WoT,
                                                    ushort* __restrict__ W1T,
                                                    ushort* __restrict__ W2T,
                                                    float* __restrict__ Bqkv) {
  const int id = blockIdx.x;
  const int t = threadIdx.x;
  if (id >= 12288) {   // bias concat: 12 blocks
    const int i = (id - 12288) * 256 + t;
    Bqkv[i] = (i < 1024) ? bq[i] : ((i < 2048) ? bk[i - 1024] : bv[i - 2048]);
    return;
  }
  const float* W; ushort* out; int Kd, Nd, bx, by, rowOff = 0;
  if (id < 4096) {
    const int which = id >> 10, sub = id & 1023;
    bx = sub & 31; by = sub >> 5; Kd = 1024; Nd = 1024;
    if (which == 0)      { W = Wq; out = WqkvT; rowOff = 0; }
    else if (which == 1) { W = Wk; out = WqkvT; rowOff = 1024; }
    else if (which == 2) { W = Wv; out = WqkvT; rowOff = 2048; }
    else                 { W = Wo; out = WoT; }
  } else if (id < 8192) {
    const int sub = id - 4096; bx = sub & 127; by = sub >> 7;
    W = W1; out = W1T; Kd = 1024; Nd = 4096;
  } else {
    const int sub = id - 8192; bx = sub & 31; by = sub >> 5;
    W = W2; out = W2T; Kd = 4096; Nd = 1024;
  }
  const int n0 = bx * 32, k0 = by * 32;
  __shared__ float Ts[32][33];
  {
    const int r = t >> 3, cb = (t & 7) * 4;
    float4 v = *reinterpret_cast<const float4*>(W + (size_t)(k0 + r) * Nd + n0 + cb);
    Ts[r][cb + 0] = v.x; Ts[r][cb + 1] = v.y; Ts[r][cb + 2] = v.z; Ts[r][cb + 3] = v.w;
  }
  __syncthreads();
  {
    const int nl = t >> 3, kb = (t & 7) * 4;
    uint2 st;
    st.x = cvt_pk_bf16(Ts[kb + 0][nl], Ts[kb + 1][nl]);
    st.y = cvt_pk_bf16(Ts[kb + 2][nl], Ts[kb + 3][nl]);
    *reinterpret_cast<uint2*>(out + (size_t)(rowOff + n0 + nl) * Kd + k0 + kb) = st;
  }
}

// ---------------- bf16 MFMA GEMM (m97 structure): C = A[M,K] @ Bt[N,K]^T ----------------
// VOUT: columns >= 2048 are the V projection -> written transposed to Vt[bh*64+d][token]
template <bool RELU, bool RES, bool OUTBF, bool VOUT>
__global__ __launch_bounds__(256) void gemm_bf16(const ushort* __restrict__ A,
                                                 const ushort* __restrict__ Bt,
                                                 const float* __restrict__ bias,
                                                 const float* __restrict__ res,
                                                 void* __restrict__ outp,
                                                 ushort* __restrict__ Vt,
                                                 int N, int K) {
  __shared__ ushort As[128 * 32];
  __shared__ ushort Bs[128 * 32];
  const int t = threadIdx.x;
  const int lane = t & 63, w = t >> 6;
  const int g = lane >> 4, i16 = lane & 15;
  const int wrow = w >> 1, wcol = w & 1;
  const int nwg  = gridDim.x * gridDim.y;
  const int orig = blockIdx.y * gridDim.x + blockIdx.x;
  const int sw   = (orig & 7) * (nwg >> 3) + (orig >> 3);
  const int row0 = (sw / gridDim.x) * 128, col0 = (sw % gridDim.x) * 128;

  f32x4 acc[4][4] = {};

  const int srow = t >> 2, sc = (t & 3) * 8;
  const ushort* aS1 = A + (size_t)(row0 + srow) * K + sc;
  const ushort* aS2 = A + (size_t)(row0 + 64 + srow) * K + sc;
  const ushort* bS1 = Bt + (size_t)(col0 + srow) * K + sc;
  const ushort* bS2 = Bt + (size_t)(col0 + 64 + srow) * K + sc;
  char* aL1 = (char*)As + w * 1024;
  char* aL2 = (char*)As + 4096 + w * 1024;
  char* bL1 = (char*)Bs + w * 1024;
  char* bL2 = (char*)Bs + 4096 + w * 1024;

  for (int k0 = 0; k0 < K; k0 += 32) {
    __syncthreads();
    __builtin_amdgcn_global_load_lds(AS1C(aS1 + k0), AS3(aL1), 16, 0, 0);
    __builtin_amdgcn_global_load_lds(AS1C(aS2 + k0), AS3(aL2), 16, 0, 0);
    __builtin_amdgcn_global_load_lds(AS1C(bS1 + k0), AS3(bL1), 16, 0, 0);
    __builtin_amdgcn_global_load_lds(AS1C(bS2 + k0), AS3(bL2), 16, 0, 0);
    __syncthreads();

    bf16x8 a4[4], b4[4];
#pragma unroll
    for (int mf = 0; mf < 4; ++mf) {
      const int r = wrow * 64 + mf * 16 + i16;
      a4[mf] = *reinterpret_cast<const bf16x8*>((const char*)As + r * 64 + g * 16);
    }
#pragma unroll
    for (int nf = 0; nf < 4; ++nf) {
      const int c = wcol * 64 + nf * 16 + i16;
      b4[nf] = *reinterpret_cast<const bf16x8*>((const char*)Bs + c * 64 + g * 16);
    }
#pragma unroll
    for (int mf = 0; mf < 4; ++mf)
#pragma unroll
      for (int nf = 0; nf < 4; ++nf)
        acc[mf][nf] = __builtin_amdgcn_mfma_f32_16x16x32_bf16(a4[mf], b4[nf], acc[mf][nf], 0, 0, 0);
  }

#pragma unroll
  for (int nf = 0; nf < 4; ++nf) {
    const int ncol = col0 + wcol * 64 + nf * 16 + i16;
    const float bb = bias[ncol];
#pragma unroll
    for (int mf = 0; mf < 4; ++mf) {
      const int mrow = row0 + wrow * 64 + mf * 16 + 4 * g;
      if (VOUT && ncol >= 2048) {
        // V projection: write transposed, packed pairs along token dim
        const int d = ncol - 2048;
        const int hh = d >> 6, dd = d & 63;
        const int bb_ = mrow >> 11;        // TT = 2048
        const int tok = mrow & 2047;
        uint2 st;
        st.x = cvt_pk_bf16(acc[mf][nf][0] + bb, acc[mf][nf][1] + bb);
        st.y = cvt_pk_bf16(acc[mf][nf][2] + bb, acc[mf][nf][3] + bb);
        *reinterpret_cast<uint2*>(Vt + (size_t)((bb_ * 16 + hh) * 64 + dd) * TT + tok) = st;
      } else {
#pragma unroll
        for (int r = 0; r < 4; ++r) {
          float v = acc[mf][nf][r] + bb;
          if (RELU) v = fmaxf(v, 0.f);
          const size_t off = (size_t)(mrow + r) * N + ncol;
          if (RES) v += res[off];
          if (OUTBF) ((ushort*)outp)[off] = f2bf(v);
          else       ((float*)outp)[off]  = v;
        }
      }
    }
  }
}

// ---------------- split-K (4-way) bf16 MFMA GEMM, bf16 partials ----------------
__global__ __launch_bounds__(256) void gemm_splitk(const ushort* __restrict__ A,
                                                   const ushort* __restrict__ Bt,
                                                   ushort* __restrict__ P0,
                                                   ushort* __restrict__ P1,
                                                   ushort* __restrict__ P2,
                                                   ushort* __restrict__ P3,
                                                   int N, int K, int Kchunk) {
  __shared__ ushort As[128 * 32];
  __shared__ ushort Bs[128 * 32];
  const int t = threadIdx.x;
  const int lane = t & 63, w = t >> 6;
  const int g = lane >> 4, i16 = lane & 15;
  const int wrow = w >> 1, wcol = w & 1;
  const int nwg  = gridDim.x * gridDim.y;
  const int orig = blockIdx.y * gridDim.x + blockIdx.x;
  const int sw   = (orig & 7) * (nwg >> 3) + (orig >> 3);
  const int row0 = (sw / gridDim.x) * 128, col0 = (sw % gridDim.x) * 128;
  const int kstart = blockIdx.z * Kchunk;
  ushort* __restrict__ P = (blockIdx.z == 0) ? P0 : (blockIdx.z == 1) ? P1
                          : (blockIdx.z == 2) ? P2 : P3;

  f32x4 acc[4][4] = {};

  const int srow = t >> 2, sc = (t & 3) * 8;
  const ushort* aS1 = A + (size_t)(row0 + srow) * K + sc;
  const ushort* aS2 = A + (size_t)(row0 + 64 + srow) * K + sc;
  const ushort* bS1 = Bt + (size_t)(col0 + srow) * K + sc;
  const ushort* bS2 = Bt + (size_t)(col0 + 64 + srow) * K + sc;
  char* aL1 = (char*)As + w * 1024;
  char* aL2 = (char*)As + 4096 + w * 1024;
  char* bL1 = (char*)Bs + w * 1024;
  char* bL2 = (char*)Bs + 4096 + w * 1024;

  for (int k0 = kstart; k0 < kstart + Kchunk; k0 += 32) {
    __syncthreads();
    __builtin_amdgcn_global_load_lds(AS1C(aS1 + k0), AS3(aL1), 16, 0, 0);
    __builtin_amdgcn_global_load_lds(AS1C(aS2 + k0), AS3(aL2), 16, 0, 0);
    __builtin_amdgcn_global_load_lds(AS1C(bS1 + k0), AS3(bL1), 16, 0, 0);
    __builtin_amdgcn_global_load_lds(AS1C(bS2 + k0), AS3(bL2), 16, 0, 0);
    __syncthreads();

    bf16x8 a4[4], b4[4];
#pragma unroll
    for (int mf = 0; mf < 4; ++mf) {
      const int r = wrow * 64 + mf * 16 + i16;
      a4[mf] = *reinterpret_cast<const bf16x8*>((const char*)As + r * 64 + g * 16);
    }
#pragma unroll
    for (int nf = 0; nf < 4; ++nf) {
      const int c = wcol * 64 + nf * 16 + i16;
      b4[nf] = *reinterpret_cast<const bf16x8*>((const char*)Bs + c * 64 + g * 16);
    }
#pragma unroll
    for (int mf = 0; mf < 4; ++mf)
#pragma unroll
      for (int nf = 0; nf < 4; ++nf)
        acc[mf][nf] = __builtin_amdgcn_mfma_f32_16x16x32_bf16(a4[mf], b4[nf], acc[mf][nf], 0, 0, 0);
  }

#pragma unroll
  for (int nf = 0; nf < 4; ++nf) {
    const int ncol = col0 + wcol * 64 + nf * 16 + i16;
#pragma unroll
    for (int mf = 0; mf < 4; ++mf) {
      const int mrow = row0 + wrow * 64 + mf * 16 + 4 * g;
#pragma unroll
      for (int r = 0; r < 4; ++r)
        P[(size_t)(mrow + r) * N + ncol] = f2bf(acc[mf][nf][r]);
    }
  }
}

__device__ inline float bfsum4(uint32_t a, uint32_t b, uint32_t c, uint32_t d, bool hi) {
  if (hi) return bfbits2f(a & 0xffff0000u) + bfbits2f(b & 0xffff0000u) +
                 bfbits2f(c & 0xffff0000u) + bfbits2f(d & 0xffff0000u);
  return bfbits2f(a << 16) + bfbits2f(b << 16) + bfbits2f(c << 16) + bfbits2f(d << 16);
}

// ---------------- Wo reduce (4 partials) + residual + LN2 fused ----------------
__global__ __launch_bounds__(256) void reduce_wo_ln(const ushort* __restrict__ P0,
                                                    const ushort* __restrict__ P1,
                                                    const ushort* __restrict__ P2,
                                                    const ushort* __restrict__ P3,
                                                    const float* __restrict__ x,
                                                    const float* __restrict__ bo,
                                                    const float* __restrict__ g,
                                                    const float* __restrict__ b,
                                                    float* __restrict__ X1f,
                                                    ushort* __restrict__ Xn) {
  const int row = blockIdx.x, t = threadIdx.x;
  const size_t off = (size_t)row * CC + t * 4;
  float4 v  = *reinterpret_cast<const float4*>(x + off);
  const uint2 q0 = *reinterpret_cast<const uint2*>(P0 + off);
  const uint2 q1 = *reinterpret_cast<const uint2*>(P1 + off);
  const uint2 q2 = *reinterpret_cast<const uint2*>(P2 + off);
  const uint2 q3 = *reinterpret_cast<const uint2*>(P3 + off);
  float4 bb = reinterpret_cast<const float4*>(bo)[t];
  v.x += bfsum4(q0.x, q1.x, q2.x, q3.x, false) + bb.x;
  v.y += bfsum4(q0.x, q1.x, q2.x, q3.x, true)  + bb.y;
  v.z += bfsum4(q0.y, q1.y, q2.y, q3.y, false) + bb.z;
  v.w += bfsum4(q0.y, q1.y, q2.y, q3.y, true)  + bb.w;
  *reinterpret_cast<float4*>(X1f + off) = v;

  float s  = v.x + v.y + v.z + v.w;
  float ss = v.x * v.x + v.y * v.y + v.z * v.z + v.w * v.w;
#pragma unroll
  for (int o = 32; o; o >>= 1) {
    s  += __shfl_down(s, o);
    ss += __shfl_down(ss, o);
  }
  __shared__ float red[16];
  const int wid = t >> 6, lane = t & 63;
  if (lane == 0) { red[wid] = s; red[8 + wid] = ss; }
  __syncthreads();
  if (t == 0) {
    red[0] = red[0] + red[1] + red[2] + red[3];
    red[8] = red[8] + red[9] + red[10] + red[11];
  }
  __syncthreads();
  const float mu   = red[0] * (1.0f / CC);
  const float var  = red[8] * (1.0f / CC) - mu * mu;
  const float rstd = rsqrtf(var + 1e-5f);
  float4 gg = reinterpret_cast<const float4*>(g)[t];
  float4 lb = reinterpret_cast<const float4*>(b)[t];
  uint2 st;
  st.x = cvt_pk_bf16((v.x - mu) * rstd * gg.x + lb.x, (v.y - mu) * rstd * gg.y + lb.y);
  st.y = cvt_pk_bf16((v.z - mu) * rstd * gg.z + lb.z, (v.w - mu) * rstd * gg.w + lb.w);
  *reinterpret_cast<uint2*>(Xn + off) = st;
}

// ---------------- FC2 reduce (4 partials) + bias + residual -> final out ----------------
__global__ __launch_bounds__(256) void reduce_fc2(const ushort* __restrict__ P0,
                                                  const ushort* __restrict__ P1,
                                                  const ushort* __restrict__ P2,
                                                  const ushort* __restrict__ P3,
                                                  const float* __restrict__ X1,
                                                  const float* __restrict__ b2,
                                                  float* __restrict__ out) {
  const int row = blockIdx.x, t = threadIdx.x;
  const size_t off = (size_t)row * CC + t * 4;
  float4 v  = *reinterpret_cast<const float4*>(X1 + off);
  const uint2 q0 = *reinterpret_cast<const uint2*>(P0 + off);
  const uint2 q1 = *reinterpret_cast<const uint2*>(P1 + off);
  const uint2 q2 = *reinterpret_cast<const uint2*>(P2 + off);
  const uint2 q3 = *reinterpret_cast<const uint2*>(P3 + off);
  float4 bb = reinterpret_cast<const float4*>(b2)[t];
  v.x += bfsum4(q0.x, q1.x, q2.x, q3.x, false) + bb.x;
  v.y += bfsum4(q0.x, q1.x, q2.x, q3.x, true)  + bb.y;
  v.z += bfsum4(q0.y, q1.y, q2.y, q3.y, false) + bb.z;
  v.w += bfsum4(q0.y, q1.y, q2.y, q3.y, true)  + bb.w;
  *reinterpret_cast<float4*>(out + off) = v;
}

// ---------------- MFMA flash attention: QBLK=128, 8 waves, KV-split x2 ----------------
// One K/V staging feeds 8 waves (128 queries); 4 blocks/CU = 32 waves/CU (100% occupancy).
__global__ __launch_bounds__(512) void attn_partial(const ushort* __restrict__ qkv,
                                                    const ushort* __restrict__ Vt,
                                                    ushort* __restrict__ O0,
                                                    ushort* __restrict__ O1,
                                                    float2* __restrict__ ml) {
  __shared__ ushort Ks[64 * 64];
  __shared__ ushort Vs[64 * 64];
  __shared__ uint32_t Ps[8][16][36];   // per-wave P strip
  const int t = threadIdx.x, lane = t & 63, w = t >> 6;   // w in 0..7
  const int g = lane >> 4, iq = lane & 15;
  // remap: 1024 blocks -> consecutive bh chunks per XCD
  const int flat = blockIdx.x;
  const int work = (flat & 7) * 128 + (flat >> 3);
  const int bh = work >> 5;
  const int rem = work & 31;
  const int z = rem >> 4;
  const int qt = rem & 15;
  const int b = bh >> 4, h = bh & 15;
  ushort* __restrict__ Obuf = z ? O1 : O0;

  // Q fragments in registers; scale = 1/sqrt(64) * log2(e) (exp2-domain softmax)
  bf16x8 qfrag[2];
  {
    const ushort* qrow = qkv + (size_t)(b * TT + qt * 128 + w * 16 + iq) * NQKV + h * 64;
    const float qs = 0.125f * 1.44269504f;
#pragma unroll
    for (int kk = 0; kk < 2; ++kk) {
      uint4 raw = *reinterpret_cast<const uint4*>(qrow + kk * 32 + g * 8);
      uint32_t rr[4] = {raw.x, raw.y, raw.z, raw.w};
      U84 tmp;
#pragma unroll
      for (int c = 0; c < 4; ++c) {
        float lo = bfbits2f(rr[c] << 16) * qs;
        float hi = bfbits2f(rr[c] & 0xffff0000u) * qs;
        tmp.u[c] = cvt_pk_bf16(lo, hi);
      }
      qfrag[kk] = tmp.v;
    }
  }

  // staging: 512 threads x 16B = one full 64x64 bf16 tile per call
  const int sr1 = t >> 3, sc1 = t & 7;           // sr1 = 8w + (lane>>3)
  const int csw = (sc1 ^ (sr1 & 7)) * 8;         // pre-swizzled global col
  const ushort* kbase = qkv + 1024 + h * 64;
  const ushort* vbase = Vt + (size_t)(bh * 64) * TT;
  char* kL = (char*)Ks + w * 1024;               // wave w covers rows 8w..8w+7
  char* vL = (char*)Vs + w * 1024;

  // P-strip addressing
  uint32_t (*pw)[36] = Ps[w];
  const int wsw = (iq & 8) << 1;                 // 0 or 16 (u32 cols)
  const int xsb = wsw << 2;                      // 0 or 64 (bytes)
  const char* prow = (const char*)&pw[iq][0];

  float mrun = -3e38f, lrun = 0.f;
  f32x4 ot[4] = {};

  const int kt0 = z * 16;
  for (int kt = kt0; kt < kt0 + 16; ++kt) {
    __syncthreads();   // previous tile's readers done
    {
      const size_t tok = (size_t)(b * TT + kt * 64);
      __builtin_amdgcn_global_load_lds(AS1C(kbase + (tok + sr1) * NQKV + csw), AS3(kL), 16, 0, 0);
      __builtin_amdgcn_global_load_lds(AS1C(vbase + (size_t)sr1 * TT + kt * 64 + csw), AS3(vL), 16, 0, 0);
    }
    __syncthreads();   // loads landed

    // S^T = K @ Q^T : lane holds 16 scores for query iq, keys j = 16jf+4g+r
    f32x4 sfr[4] = {};
    __builtin_amdgcn_s_setprio(1);
#pragma unroll
    for (int kk = 0; kk < 2; ++kk)
#pragma unroll
      for (int jf = 0; jf < 4; ++jf) {
        const int row = iq + 16 * jf;
        const int off = row * 128 + ((kk * 64 + g * 16) ^ ((row & 7) << 4));
        bf16x8 a = *reinterpret_cast<const bf16x8*>((const char*)Ks + off);
        sfr[jf] = __builtin_amdgcn_mfma_f32_16x16x32_bf16(a, qfrag[kk], sfr[jf], 0, 0, 0);
      }
    __builtin_amdgcn_s_setprio(0);

    // online softmax (exp2 domain), defer-max THR=8; lsum stays lane-partial
    float tm0 = fmaxf(fmaxf(sfr[0][0], sfr[0][1]), fmaxf(sfr[0][2], sfr[0][3]));
    float tm1 = fmaxf(fmaxf(sfr[1][0], sfr[1][1]), fmaxf(sfr[1][2], sfr[1][3]));
    float tm2 = fmaxf(fmaxf(sfr[2][0], sfr[2][1]), fmaxf(sfr[2][2], sfr[2][3]));
    float tm3 = fmaxf(fmaxf(sfr[3][0], sfr[3][1]), fmaxf(sfr[3][2], sfr[3][3]));
    float tmax = fmaxf(fmaxf(tm0, tm1), fmaxf(tm2, tm3));
    tmax = fmaxf(tmax, __shfl_xor(tmax, 16, 64));
    tmax = fmaxf(tmax, __shfl_xor(tmax, 32, 64));

    if (!__all(tmax <= mrun + 8.f)) {
      const float mnew  = fmaxf(mrun, tmax);
      const float alpha = exp2_fast(mrun - mnew);
      lrun *= alpha;
#pragma unroll
      for (int df = 0; df < 4; ++df)
#pragma unroll
        for (int r = 0; r < 4; ++r) ot[df][r] *= alpha;
      mrun = mnew;
    }

#pragma unroll
    for (int f = 0; f < 4; ++f) {
      float p0 = exp2_fast(sfr[f][0] - mrun);
      float p1 = exp2_fast(sfr[f][1] - mrun);
      float p2 = exp2_fast(sfr[f][2] - mrun);
      float p3 = exp2_fast(sfr[f][3] - mrun);
      lrun += (p0 + p1) + (p2 + p3);
      pw[iq][(8 * f + 2 * g + 0) ^ wsw] = cvt_pk_bf16(p0, p1);
      pw[iq][(8 * f + 2 * g + 1) ^ wsw] = cvt_pk_bf16(p2, p3);
    }
    asm volatile("s_waitcnt lgkmcnt(0)" ::: "memory");   // wave-local: P strip visible

    // PV: O^T = Vt @ P^T ; B-frag read straight from the P strip
    __builtin_amdgcn_s_setprio(1);
#pragma unroll
    for (int kk = 0; kk < 2; ++kk) {
      bf16x8 pb = *reinterpret_cast<const bf16x8*>(prow + ((kk * 64 + g * 16) ^ xsb));
#pragma unroll
      for (int df = 0; df < 4; ++df) {
        const int row = iq + 16 * df;
        const int off = row * 128 + ((kk * 64 + g * 16) ^ ((row & 7) << 4));
        bf16x8 a = *reinterpret_cast<const bf16x8*>((const char*)Vs + off);
        ot[df] = __builtin_amdgcn_mfma_f32_16x16x32_bf16(a, pb, ot[df], 0, 0, 0);
      }
    }
    __builtin_amdgcn_s_setprio(0);
  }

  // epilogue: finish deferred lsum reduce across the 4 g-groups, then write partials
  lrun += __shfl_xor(lrun, 16, 64);
  lrun += __shfl_xor(lrun, 32, 64);
  const int grow = b * TT + qt * 128 + w * 16 + iq;
  const float inv = 1.f / lrun;
  ushort* orow = Obuf + (size_t)grow * CC + h * 64;
#pragma unroll
  for (int df = 0; df < 4; ++df) {
    uint2 st;
    st.x = cvt_pk_bf16(ot[df][0] * inv, ot[df][1] * inv);
    st.y = cvt_pk_bf16(ot[df][2] * inv, ot[df][3] * inv);
    *reinterpret_cast<uint2*>(orow + df * 16 + g * 4) = st;
  }
  if (g == 0) ml[(size_t)z * (MM * 16) + grow * 16 + h] = make_float2(mrun, lrun);
}

// ---------------- combine the two KV-split partials -> Attn (bf16) ----------------
__global__ __launch_bounds__(256) void attn_combine(const ushort* __restrict__ O0,
                                                    const ushort* __restrict__ O1,
                                                    const float2* __restrict__ ml,
                                                    ushort* __restrict__ attnb) {
  const int row = blockIdx.x, t = threadIdx.x;
  const int h = t >> 4;
  const float2 a = ml[(size_t)row * 16 + h];
  const float2 c = ml[(size_t)MM * 16 + (size_t)row * 16 + h];
  const float m  = fmaxf(a.x, c.x);
  const float w0 = exp2_fast(a.x - m) * a.y;
  const float w1 = exp2_fast(c.x - m) * c.y;
  const float inv = 1.f / (w0 + w1);
  const float s0 = w0 * inv, s1 = w1 * inv;
  const size_t off = (size_t)row * CC + t * 4;
  const uint2 r0 = *reinterpret_cast<const uint2*>(O0 + off);
  const uint2 r1 = *reinterpret_cast<const uint2*>(O1 + off);
  const float o0 = bfbits2f(r0.x << 16)         * s0 + bfbits2f(r1.x << 16)         * s1;
  const float o1 = bfbits2f(r0.x & 0xffff0000u) * s0 + bfbits2f(r1.x & 0xffff0000u) * s1;
  const float o2 = bfbits2f(r0.y << 16)         * s0 + bfbits2f(r1.y << 16)         * s1;
  const float o3 = bfbits2f(r0.y & 0xffff0000u) * s0 + bfbits2f(r1.y & 0xffff0000u) * s1;
  uint2 st;
  st.x = cvt_pk_bf16(o0, o1);
  st.y = cvt_pk_bf16(o2, o3);
  *reinterpret_cast<uint2*>(attnb + off) = st;
}

// --------------------------------- launcher -------------------------------------
extern "C" void kernel_launch(void* const* d_in, const int* in_sizes, int n_in,
                              void* d_out, int out_size, void* d_ws, size_t ws_size,
                              hipStream_t stream) {
  const float* x     = (const float*)d_in[0];
  const float* ln1_g = (const float*)d_in[1];
  const float* ln1_b = (const float*)d_in[2];
  const float* ln2_g = (const float*)d_in[3];
  const float* ln2_b = (const float*)d_in[4];
  const float* Wq = (const float*)d_in[5];
  const float* bq = (const float*)d_in[6];
  const float* Wk = (const float*)d_in[7];
  const float* bk = (const float*)d_in[8];
  const float* Wv = (const float*)d_in[9];
  const float* bv = (const float*)d_in[10];
  const float* Wo = (const float*)d_in[11];
  const float* bo = (const float*)d_in[12];
  const float* W1 = (const float*)d_in[13];
  const float* b1 = (const float*)d_in[14];
  const float* W2 = (const float*)d_in[15];
  const float* b2 = (const float*)d_in[16];
  float* out = (float*)d_out;
  char* ws = (char*)d_ws;

  // workspace layout (92.3 MB total, unchanged footprint)
  ushort* WqkvT = (ushort*)(ws + 0);          // 3072x1024 bf16 (6 MB)
  ushort* WoT   = (ushort*)(ws + 6291456);    // 1024x1024 bf16 (2 MB)
  ushort* W1T   = (ushort*)(ws + 8388608);    // 4096x1024 bf16 (8 MB)
  ushort* W2T   = (ushort*)(ws + 16777216);   // 1024x4096 bf16 (8 MB)
  float*  Bqkv  = (float*) (ws + 25165824);   // 3072 f32
  ushort* Xn    = (ushort*)(ws + 25178112);   // 4096x1024 bf16 (8 MB)
  ushort* Attn  = (ushort*)(ws + 33566720);   // 4096x1024 bf16 (8 MB)
  float*  X1f   = (float*) (ws + 41955328);   // 4096x1024 f32 (16 MB)
  ushort* Qkv   = (ushort*)(ws + 58732544);   // 4096x3072 bf16 (24 MB)
  ushort* Vtb   = (ushort*)(ws + 83898368);   // 2048x2048 bf16 (8 MB)
  ushort* Hid   = (ushort*)(ws + 58732544);   // 4096x4096 bf16 (reuses Qkv+Vtb)
  // attention split partials: O0/O1 bf16 in X1f region (dead until reduce_wo_ln)
  ushort* OP0   = (ushort*)(ws + 41955328);   // 8 MB
  ushort* OP1   = (ushort*)(ws + 50343936);   // 8 MB
  float2* mlbuf = (float2*)(ws + 0);          // 1 MB (WqkvT dead after QKV gemm)
  // Wo split-K4 bf16 partials: dead Qkv+Vtb region, exactly 4 x 8 MB
  ushort* WoP0  = (ushort*)(ws + 58732544);
  ushort* WoP1  = (ushort*)(ws + 67121152);
  ushort* WoP2  = (ushort*)(ws + 75509760);
  ushort* WoP3  = (ushort*)(ws + 83898368);
  // FC2 split-K4 bf16 partials: dead {WqkvT+WoT}, {W1T}, {Xn}, {Attn} regions
  ushort* F2P0  = (ushort*)(ws + 0);
  ushort* F2P1  = (ushort*)(ws + 8388608);
  ushort* F2P2  = (ushort*)(ws + 25178112);
  ushort* F2P3  = (ushort*)(ws + 33566720);

  const dim3 blk(256);

  prep_weights<<<dim3(12300), blk, 0, stream>>>(Wq, Wk, Wv, Wo, W1, W2, bq, bk, bv,
                                                WqkvT, WoT, W1T, W2T, Bqkv);
  ln_kernel<<<dim3(MM), blk, 0, stream>>>(x, ln1_g, ln1_b, Xn);
  // QKV GEMM: Q,K -> Qkv ; V -> Vtb (transposed in epilogue)
  gemm_bf16<false, false, true, true><<<dim3(24, 32), blk, 0, stream>>>(
      Xn, WqkvT, Bqkv, nullptr, Qkv, Vtb, NQKV, 1024);
  attn_partial<<<dim3(1024), dim3(512), 0, stream>>>(Qkv, Vtb, OP0, OP1, mlbuf);
  attn_combine<<<dim3(MM), blk, 0, stream>>>(OP0, OP1, mlbuf, Attn);
  gemm_splitk<<<dim3(8, 32, 4), blk, 0, stream>>>(Attn, WoT, WoP0, WoP1, WoP2, WoP3, 1024, 1024, 256);
  reduce_wo_ln<<<dim3(MM), blk, 0, stream>>>(WoP0, WoP1, WoP2, WoP3, x, bo, ln2_g, ln2_b, X1f, Xn);
  gemm_bf16<true, false, true, false><<<dim3(32, 32), blk, 0, stream>>>(
      Xn, W1T, b1, nullptr, Hid, nullptr, HIDN, 1024);
  gemm_splitk<<<dim3(8, 32, 4), blk, 0, stream>>>(Hid, W2T, F2P0, F2P1, F2P2, F2P3, 1024, 4096, 1024);
  reduce_fc2<<<dim3(MM), blk, 0, stream>>>(F2P0, F2P1, F2P2, F2P3, X1f, b2, out);
}

// Round 8
// 281.856 us; speedup vs baseline: 10.6316x; 1.0038x over previous
//
#include <hip/hip_runtime.h>

typedef float f32x4 __attribute__((ext_vector_type(4)));
typedef __bf16 bf16x8 __attribute__((ext_vector_type(8)));

constexpr int TT   = 2048;
constexpr int CC   = 1024;
constexpr int HIDN = 4096;
constexpr int MM   = 4096;   // B*T rows
constexpr int NQKV = 3072;

union U84 { uint32_t u[4]; bf16x8 v; };

__device__ inline uint32_t cvt_pk_bf16(float lo, float hi) {
  uint32_t r;
  asm("v_cvt_pk_bf16_f32 %0, %1, %2" : "=v"(r) : "v"(lo), "v"(hi));
  return r;
}
__device__ inline ushort f2bf(float f) { return (ushort)(cvt_pk_bf16(f, 0.f) & 0xffffu); }
__device__ inline float bfbits2f(uint32_t bits) {
  union { uint32_t u; float f; } c; c.u = bits; return c.f;
}
__device__ inline float exp2_fast(float x) {
  float r;
  asm("v_exp_f32 %0, %1" : "=v"(r) : "v"(x));
  return r;
}

#define AS1C(p) ((__attribute__((address_space(1))) void*)(p))
#define AS3(p)  ((__attribute__((address_space(3))) void*)(p))

// ---------------- fused prep: weight transposes + bias concat + LN1 ----------------
__global__ __launch_bounds__(256) void prep_weights(const float* __restrict__ Wq,
                                                    const float* __restrict__ Wk,
                                                    const float* __restrict__ Wv,
                                                    const float* __restrict__ Wo,
                                                    const float* __restrict__ W1,
                                                    const float* __restrict__ W2,
                                                    const float* __restrict__ bq,
                                                    const float* __restrict__ bk,
                                                    const float* __restrict__ bv,
                                                    const float* __restrict__ x,
                                                    const float* __restrict__ g1,
                                                    const float* __restrict__ b1v,
                                                    ushort* __restrict__ WqkvT,
                                                    ushort* __restrict__ WoT,
                                                    ushort* __restrict__ W1T,
                                                    ushort* __restrict__ W2T,
                                                    float* __restrict__ Bqkv,
                                                    ushort* __restrict__ Xn) {
  const int id = blockIdx.x;
  const int t = threadIdx.x;
  if (id >= 12300) {   // LN1: rows 0..4095
    const int row = id - 12300;
    float4 v = reinterpret_cast<const float4*>(x + (size_t)row * CC)[t];
    float s  = v.x + v.y + v.z + v.w;
    float ss = v.x * v.x + v.y * v.y + v.z * v.z + v.w * v.w;
#pragma unroll
    for (int off = 32; off; off >>= 1) {
      s  += __shfl_down(s, off);
      ss += __shfl_down(ss, off);
    }
    __shared__ float red[16];
    const int wid = t >> 6, lane = t & 63;
    if (lane == 0) { red[wid] = s; red[8 + wid] = ss; }
    __syncthreads();
    if (t == 0) {
      red[0] = red[0] + red[1] + red[2] + red[3];
      red[8] = red[8] + red[9] + red[10] + red[11];
    }
    __syncthreads();
    const float mu   = red[0] * (1.0f / CC);
    const float var  = red[8] * (1.0f / CC) - mu * mu;
    const float rstd = rsqrtf(var + 1e-5f);
    float4 gg = reinterpret_cast<const float4*>(g1)[t];
    float4 bb = reinterpret_cast<const float4*>(b1v)[t];
    uint2 st;
    st.x = cvt_pk_bf16((v.x - mu) * rstd * gg.x + bb.x, (v.y - mu) * rstd * gg.y + bb.y);
    st.y = cvt_pk_bf16((v.z - mu) * rstd * gg.z + bb.z, (v.w - mu) * rstd * gg.w + bb.w);
    *reinterpret_cast<uint2*>(Xn + (size_t)row * CC + t * 4) = st;
    return;
  }
  if (id >= 12288) {   // bias concat: 12 blocks
    const int i = (id - 12288) * 256 + t;
    Bqkv[i] = (i < 1024) ? bq[i] : ((i < 2048) ? bk[i - 1024] : bv[i - 2048]);
    return;
  }
  const float* W; ushort* out; int Kd, Nd, bx, by, rowOff = 0;
  if (id < 4096) {
    const int which = id >> 10, sub = id & 1023;
    bx = sub & 31; by = sub >> 5; Kd = 1024; Nd = 1024;
    if (which == 0)      { W = Wq; out = WqkvT; rowOff = 0; }
    else if (which == 1) { W = Wk; out = WqkvT; rowOff = 1024; }
    else if (which == 2) { W = Wv; out = WqkvT; rowOff = 2048; }
    else                 { W = Wo; out = WoT; }
  } else if (id < 8192) {
    const int sub = id - 4096; bx = sub & 127; by = sub >> 7;
    W = W1; out = W1T; Kd = 1024; Nd = 4096;
  } else {
    const int sub = id - 8192; bx = sub & 31; by = sub >> 5;
    W = W2; out = W2T; Kd = 4096; Nd = 1024;
  }
  const int n0 = bx * 32, k0 = by * 32;
  __shared__ float Ts[32][33];
  {
    const int r = t >> 3, cb = (t & 7) * 4;
    float4 v = *reinterpret_cast<const float4*>(W + (size_t)(k0 + r) * Nd + n0 + cb);
    Ts[r][cb + 0] = v.x; Ts[r][cb + 1] = v.y; Ts[r][cb + 2] = v.z; Ts[r][cb + 3] = v.w;
  }
  __syncthreads();
  {
    const int nl = t >> 3, kb = (t & 7) * 4;
    uint2 st;
    st.x = cvt_pk_bf16(Ts[kb + 0][nl], Ts[kb + 1][nl]);
    st.y = cvt_pk_bf16(Ts[kb + 2][nl], Ts[kb + 3][nl]);
    *reinterpret_cast<uint2*>(out + (size_t)(rowOff + n0 + nl) * Kd + k0 + kb) = st;
  }
}

// ---------------- bf16 MFMA GEMM, coalesced LDS-transpose epilogue ----------------
// VOUT: column-quadrants >= 2048 are the V projection -> written transposed to Vt.
template <bool RELU, bool VOUT>
__global__ __launch_bounds__(256) void gemm_bf16(const ushort* __restrict__ A,
                                                 const ushort* __restrict__ Bt,
                                                 const float* __restrict__ bias,
                                                 ushort* __restrict__ outp,
                                                 ushort* __restrict__ Vt,
                                                 int N, int K) {
  __shared__ ushort Smem[8192];   // staging: As = [0,4096), Bs = [4096,8192) ushorts
  ushort* Asm = Smem;
  ushort* Bsm = Smem + 4096;
  const int t = threadIdx.x;
  const int lane = t & 63, w = t >> 6;
  const int g = lane >> 4, i16 = lane & 15;
  const int wrow = w >> 1, wcol = w & 1;
  const int nwg  = gridDim.x * gridDim.y;
  const int orig = blockIdx.y * gridDim.x + blockIdx.x;
  const int sw   = (orig & 7) * (nwg >> 3) + (orig >> 3);
  const int row0 = (sw / gridDim.x) * 128, col0 = (sw % gridDim.x) * 128;

  f32x4 acc[4][4] = {};

  const int srow = t >> 2, sc = (t & 3) * 8;
  const ushort* aS1 = A + (size_t)(row0 + srow) * K + sc;
  const ushort* aS2 = A + (size_t)(row0 + 64 + srow) * K + sc;
  const ushort* bS1 = Bt + (size_t)(col0 + srow) * K + sc;
  const ushort* bS2 = Bt + (size_t)(col0 + 64 + srow) * K + sc;
  char* aL1 = (char*)Asm + w * 1024;
  char* aL2 = (char*)Asm + 4096 + w * 1024;
  char* bL1 = (char*)Bsm + w * 1024;
  char* bL2 = (char*)Bsm + 4096 + w * 1024;

  for (int k0 = 0; k0 < K; k0 += 32) {
    __syncthreads();
    __builtin_amdgcn_global_load_lds(AS1C(aS1 + k0), AS3(aL1), 16, 0, 0);
    __builtin_amdgcn_global_load_lds(AS1C(aS2 + k0), AS3(aL2), 16, 0, 0);
    __builtin_amdgcn_global_load_lds(AS1C(bS1 + k0), AS3(bL1), 16, 0, 0);
    __builtin_amdgcn_global_load_lds(AS1C(bS2 + k0), AS3(bL2), 16, 0, 0);
    __syncthreads();

    bf16x8 a4[4], b4[4];
#pragma unroll
    for (int mf = 0; mf < 4; ++mf) {
      const int r = wrow * 64 + mf * 16 + i16;
      a4[mf] = *reinterpret_cast<const bf16x8*>((const char*)Asm + r * 64 + g * 16);
    }
#pragma unroll
    for (int nf = 0; nf < 4; ++nf) {
      const int c = wcol * 64 + nf * 16 + i16;
      b4[nf] = *reinterpret_cast<const bf16x8*>((const char*)Bsm + c * 64 + g * 16);
    }
#pragma unroll
    for (int mf = 0; mf < 4; ++mf)
#pragma unroll
      for (int nf = 0; nf < 4; ++nf)
        acc[mf][nf] = __builtin_amdgcn_mfma_f32_16x16x32_bf16(a4[mf], b4[nf], acc[mf][nf], 0, 0, 0);
  }

  __syncthreads();   // staging LDS now dead; safe to reuse as epilogue scratch

  const int qcol0 = col0 + wcol * 64;   // this wave's 64-col quadrant base

  if (VOUT && qcol0 >= 2048) {
    // V projection quadrant: write transposed (scattered, unavoidable)
#pragma unroll
    for (int nf = 0; nf < 4; ++nf) {
      const int ncol = qcol0 + nf * 16 + i16;
      const float bb = bias[ncol];
      const int d = ncol - 2048;
      const int hh = d >> 6, dd = d & 63;
#pragma unroll
      for (int mf = 0; mf < 4; ++mf) {
        const int mrow = row0 + wrow * 64 + mf * 16 + 4 * g;
        const int bb_ = mrow >> 11, tok = mrow & 2047;
        uint2 st;
        st.x = cvt_pk_bf16(acc[mf][nf][0] + bb, acc[mf][nf][1] + bb);
        st.y = cvt_pk_bf16(acc[mf][nf][2] + bb, acc[mf][nf][3] + bb);
        *reinterpret_cast<uint2*>(Vt + (size_t)((bb_ * 16 + hh) * 64 + dd) * TT + tok) = st;
      }
    }
    return;
  }

  // coalesced epilogue: per-wave 4 KB LDS scratch, 16x64 f32 chunks, XOR-4 swizzle
  float* Lf = (float*)((char*)Smem + w * 4096);
  const int rr = lane >> 2, q = lane & 3;
#pragma unroll
  for (int mf = 0; mf < 4; ++mf) {
#pragma unroll
    for (int nf = 0; nf < 4; ++nf)
#pragma unroll
      for (int r = 0; r < 4; ++r) {
        const int row = 4 * g + r;
        Lf[row * 64 + ((16 * nf + i16) ^ ((row & 7) << 2))] = acc[mf][nf][r];
      }
    asm volatile("s_waitcnt lgkmcnt(0)" ::: "memory");
    uint32_t u[8];
#pragma unroll
    for (int j = 0; j < 4; ++j) {
      f32x4 v = *reinterpret_cast<const f32x4*>(Lf + rr * 64 + ((q * 16 + 4 * j) ^ ((rr & 7) << 2)));
      const float4 b4 = *reinterpret_cast<const float4*>(bias + qcol0 + q * 16 + 4 * j);
      float e0 = v[0] + b4.x, e1 = v[1] + b4.y, e2 = v[2] + b4.z, e3 = v[3] + b4.w;
      if (RELU) {
        e0 = fmaxf(e0, 0.f); e1 = fmaxf(e1, 0.f);
        e2 = fmaxf(e2, 0.f); e3 = fmaxf(e3, 0.f);
      }
      u[2 * j + 0] = cvt_pk_bf16(e0, e1);
      u[2 * j + 1] = cvt_pk_bf16(e2, e3);
    }
    const int mrow = row0 + wrow * 64 + mf * 16 + rr;
    ushort* orow = outp + (size_t)mrow * N + qcol0 + q * 16;
    uint4 s0; s0.x = u[0]; s0.y = u[1]; s0.z = u[2]; s0.w = u[3];
    uint4 s1; s1.x = u[4]; s1.y = u[5]; s1.z = u[6]; s1.w = u[7];
    *reinterpret_cast<uint4*>(orow) = s0;
    *reinterpret_cast<uint4*>(orow + 8) = s1;
    asm volatile("s_waitcnt lgkmcnt(0)" ::: "memory");   // chunk reads done before next writes
  }
}

// ---------------- split-K (4-way) bf16 MFMA GEMM, bf16 partials, coalesced epilogue ----------------
__global__ __launch_bounds__(256) void gemm_splitk(const ushort* __restrict__ A,
                                                   const ushort* __restrict__ Bt,
                                                   ushort* __restrict__ P0,
                                                   ushort* __restrict__ P1,
                                                   ushort* __restrict__ P2,
                                                   ushort* __restrict__ P3,
                                                   int N, int K, int Kchunk) {
  __shared__ ushort Smem[8192];
  ushort* Asm = Smem;
  ushort* Bsm = Smem + 4096;
  const int t = threadIdx.x;
  const int lane = t & 63, w = t >> 6;
  const int g = lane >> 4, i16 = lane & 15;
  const int wrow = w >> 1, wcol = w & 1;
  const int nwg  = gridDim.x * gridDim.y;
  const int orig = blockIdx.y * gridDim.x + blockIdx.x;
  const int sw   = (orig & 7) * (nwg >> 3) + (orig >> 3);
  const int row0 = (sw / gridDim.x) * 128, col0 = (sw % gridDim.x) * 128;
  const int kstart = blockIdx.z * Kchunk;
  ushort* __restrict__ P = (blockIdx.z == 0) ? P0 : (blockIdx.z == 1) ? P1
                          : (blockIdx.z == 2) ? P2 : P3;

  f32x4 acc[4][4] = {};

  const int srow = t >> 2, sc = (t & 3) * 8;
  const ushort* aS1 = A + (size_t)(row0 + srow) * K + sc;
  const ushort* aS2 = A + (size_t)(row0 + 64 + srow) * K + sc;
  const ushort* bS1 = Bt + (size_t)(col0 + srow) * K + sc;
  const ushort* bS2 = Bt + (size_t)(col0 + 64 + srow) * K + sc;
  char* aL1 = (char*)Asm + w * 1024;
  char* aL2 = (char*)Asm + 4096 + w * 1024;
  char* bL1 = (char*)Bsm + w * 1024;
  char* bL2 = (char*)Bsm + 4096 + w * 1024;

  for (int k0 = kstart; k0 < kstart + Kchunk; k0 += 32) {
    __syncthreads();
    __builtin_amdgcn_global_load_lds(AS1C(aS1 + k0), AS3(aL1), 16, 0, 0);
    __builtin_amdgcn_global_load_lds(AS1C(aS2 + k0), AS3(aL2), 16, 0, 0);
    __builtin_amdgcn_global_load_lds(AS1C(bS1 + k0), AS3(bL1), 16, 0, 0);
    __builtin_amdgcn_global_load_lds(AS1C(bS2 + k0), AS3(bL2), 16, 0, 0);
    __syncthreads();

    bf16x8 a4[4], b4[4];
#pragma unroll
    for (int mf = 0; mf < 4; ++mf) {
      const int r = wrow * 64 + mf * 16 + i16;
      a4[mf] = *reinterpret_cast<const bf16x8*>((const char*)Asm + r * 64 + g * 16);
    }
#pragma unroll
    for (int nf = 0; nf < 4; ++nf) {
      const int c = wcol * 64 + nf * 16 + i16;
      b4[nf] = *reinterpret_cast<const bf16x8*>((const char*)Bsm + c * 64 + g * 16);
    }
#pragma unroll
    for (int mf = 0; mf < 4; ++mf)
#pragma unroll
      for (int nf = 0; nf < 4; ++nf)
        acc[mf][nf] = __builtin_amdgcn_mfma_f32_16x16x32_bf16(a4[mf], b4[nf], acc[mf][nf], 0, 0, 0);
  }

  __syncthreads();

  float* Lf = (float*)((char*)Smem + w * 4096);
  const int qcol0 = col0 + wcol * 64;
  const int rr = lane >> 2, q = lane & 3;
#pragma unroll
  for (int mf = 0; mf < 4; ++mf) {
#pragma unroll
    for (int nf = 0; nf < 4; ++nf)
#pragma unroll
      for (int r = 0; r < 4; ++r) {
        const int row = 4 * g + r;
        Lf[row * 64 + ((16 * nf + i16) ^ ((row & 7) << 2))] = acc[mf][nf][r];
      }
    asm volatile("s_waitcnt lgkmcnt(0)" ::: "memory");
    uint32_t u[8];
#pragma unroll
    for (int j = 0; j < 4; ++j) {
      f32x4 v = *reinterpret_cast<const f32x4*>(Lf + rr * 64 + ((q * 16 + 4 * j) ^ ((rr & 7) << 2)));
      u[2 * j + 0] = cvt_pk_bf16(v[0], v[1]);
      u[2 * j + 1] = cvt_pk_bf16(v[2], v[3]);
    }
    const int mrow = row0 + wrow * 64 + mf * 16 + rr;
    ushort* orow = P + (size_t)mrow * N + qcol0 + q * 16;
    uint4 s0; s0.x = u[0]; s0.y = u[1]; s0.z = u[2]; s0.w = u[3];
    uint4 s1; s1.x = u[4]; s1.y = u[5]; s1.z = u[6]; s1.w = u[7];
    *reinterpret_cast<uint4*>(orow) = s0;
    *reinterpret_cast<uint4*>(orow + 8) = s1;
    asm volatile("s_waitcnt lgkmcnt(0)" ::: "memory");
  }
}

__device__ inline float bfsum4(uint32_t a, uint32_t b, uint32_t c, uint32_t d, bool hi) {
  if (hi) return bfbits2f(a & 0xffff0000u) + bfbits2f(b & 0xffff0000u) +
                 bfbits2f(c & 0xffff0000u) + bfbits2f(d & 0xffff0000u);
  return bfbits2f(a << 16) + bfbits2f(b << 16) + bfbits2f(c << 16) + bfbits2f(d << 16);
}

// ---------------- Wo reduce (4 partials) + residual + LN2 fused ----------------
__global__ __launch_bounds__(256) void reduce_wo_ln(const ushort* __restrict__ P0,
                                                    const ushort* __restrict__ P1,
                                                    const ushort* __restrict__ P2,
                                                    const ushort* __restrict__ P3,
                                                    const float* __restrict__ x,
                                                    const float* __restrict__ bo,
                                                    const float* __restrict__ g,
                                                    const float* __restrict__ b,
                                                    float* __restrict__ X1f,
                                                    ushort* __restrict__ Xn) {
  const int row = blockIdx.x, t = threadIdx.x;
  const size_t off = (size_t)row * CC + t * 4;
  float4 v  = *reinterpret_cast<const float4*>(x + off);
  const uint2 q0 = *reinterpret_cast<const uint2*>(P0 + off);
  const uint2 q1 = *reinterpret_cast<const uint2*>(P1 + off);
  const uint2 q2 = *reinterpret_cast<const uint2*>(P2 + off);
  const uint2 q3 = *reinterpret_cast<const uint2*>(P3 + off);
  float4 bb = reinterpret_cast<const float4*>(bo)[t];
  v.x += bfsum4(q0.x, q1.x, q2.x, q3.x, false) + bb.x;
  v.y += bfsum4(q0.x, q1.x, q2.x, q3.x, true)  + bb.y;
  v.z += bfsum4(q0.y, q1.y, q2.y, q3.y, false) + bb.z;
  v.w += bfsum4(q0.y, q1.y, q2.y, q3.y, true)  + bb.w;
  *reinterpret_cast<float4*>(X1f + off) = v;

  float s  = v.x + v.y + v.z + v.w;
  float ss = v.x * v.x + v.y * v.y + v.z * v.z + v.w * v.w;
#pragma unroll
  for (int o = 32; o; o >>= 1) {
    s  += __shfl_down(s, o);
    ss += __shfl_down(ss, o);
  }
  __shared__ float red[16];
  const int wid = t >> 6, lane = t & 63;
  if (lane == 0) { red[wid] = s; red[8 + wid] = ss; }
  __syncthreads();
  if (t == 0) {
    red[0] = red[0] + red[1] + red[2] + red[3];
    red[8] = red[8] + red[9] + red[10] + red[11];
  }
  __syncthreads();
  const float mu   = red[0] * (1.0f / CC);
  const float var  = red[8] * (1.0f / CC) - mu * mu;
  const float rstd = rsqrtf(var + 1e-5f);
  float4 gg = reinterpret_cast<const float4*>(g)[t];
  float4 lb = reinterpret_cast<const float4*>(b)[t];
  uint2 st;
  st.x = cvt_pk_bf16((v.x - mu) * rstd * gg.x + lb.x, (v.y - mu) * rstd * gg.y + lb.y);
  st.y = cvt_pk_bf16((v.z - mu) * rstd * gg.z + lb.z, (v.w - mu) * rstd * gg.w + lb.w);
  *reinterpret_cast<uint2*>(Xn + off) = st;
}

// ---------------- FC2 reduce (4 partials) + bias + residual -> final out ----------------
__global__ __launch_bounds__(256) void reduce_fc2(const ushort* __restrict__ P0,
                                                  const ushort* __restrict__ P1,
                                                  const ushort* __restrict__ P2,
                                                  const ushort* __restrict__ P3,
                                                  const float* __restrict__ X1,
                                                  const float* __restrict__ b2,
                                                  float* __restrict__ out) {
  const int row = blockIdx.x, t = threadIdx.x;
  const size_t off = (size_t)row * CC + t * 4;
  float4 v  = *reinterpret_cast<const float4*>(X1 + off);
  const uint2 q0 = *reinterpret_cast<const uint2*>(P0 + off);
  const uint2 q1 = *reinterpret_cast<const uint2*>(P1 + off);
  const uint2 q2 = *reinterpret_cast<const uint2*>(P2 + off);
  const uint2 q3 = *reinterpret_cast<const uint2*>(P3 + off);
  float4 bb = reinterpret_cast<const float4*>(b2)[t];
  v.x += bfsum4(q0.x, q1.x, q2.x, q3.x, false) + bb.x;
  v.y += bfsum4(q0.x, q1.x, q2.x, q3.x, true)  + bb.y;
  v.z += bfsum4(q0.y, q1.y, q2.y, q3.y, false) + bb.z;
  v.w += bfsum4(q0.y, q1.y, q2.y, q3.y, true)  + bb.w;
  *reinterpret_cast<float4*>(out + off) = v;
}

// ---------------- MFMA flash attention: QBLK=128, 8 waves, KV-split x2 ----------------
__global__ __launch_bounds__(512) void attn_partial(const ushort* __restrict__ qkv,
                                                    const ushort* __restrict__ Vt,
                                                    ushort* __restrict__ O0,
                                                    ushort* __restrict__ O1,
                                                    float2* __restrict__ ml) {
  __shared__ ushort Ks[64 * 64];
  __shared__ ushort Vs[64 * 64];
  __shared__ uint32_t Ps[8][16][36];   // per-wave P strip
  const int t = threadIdx.x, lane = t & 63, w = t >> 6;   // w in 0..7
  const int g = lane >> 4, iq = lane & 15;
  const int flat = blockIdx.x;
  const int work = (flat & 7) * 128 + (flat >> 3);
  const int bh = work >> 5;
  const int rem = work & 31;
  const int z = rem >> 4;
  const int qt = rem & 15;
  const int b = bh >> 4, h = bh & 15;
  ushort* __restrict__ Obuf = z ? O1 : O0;

  bf16x8 qfrag[2];
  {
    const ushort* qrow = qkv + (size_t)(b * TT + qt * 128 + w * 16 + iq) * NQKV + h * 64;
    const float qs = 0.125f * 1.44269504f;
#pragma unroll
    for (int kk = 0; kk < 2; ++kk) {
      uint4 raw = *reinterpret_cast<const uint4*>(qrow + kk * 32 + g * 8);
      uint32_t rr[4] = {raw.x, raw.y, raw.z, raw.w};
      U84 tmp;
#pragma unroll
      for (int c = 0; c < 4; ++c) {
        float lo = bfbits2f(rr[c] << 16) * qs;
        float hi = bfbits2f(rr[c] & 0xffff0000u) * qs;
        tmp.u[c] = cvt_pk_bf16(lo, hi);
      }
      qfrag[kk] = tmp.v;
    }
  }

  const int sr1 = t >> 3, sc1 = t & 7;
  const int csw = (sc1 ^ (sr1 & 7)) * 8;
  const ushort* kbase = qkv + 1024 + h * 64;
  const ushort* vbase = Vt + (size_t)(bh * 64) * TT;
  char* kL = (char*)Ks + w * 1024;
  char* vL = (char*)Vs + w * 1024;

  uint32_t (*pw)[36] = Ps[w];
  const int wsw = (iq & 8) << 1;
  const int xsb = wsw << 2;
  const char* prow = (const char*)&pw[iq][0];

  float mrun = -3e38f, lrun = 0.f;
  f32x4 ot[4] = {};

  const int kt0 = z * 16;
  for (int kt = kt0; kt < kt0 + 16; ++kt) {
    __syncthreads();
    {
      const size_t tok = (size_t)(b * TT + kt * 64);
      __builtin_amdgcn_global_load_lds(AS1C(kbase + (tok + sr1) * NQKV + csw), AS3(kL), 16, 0, 0);
      __builtin_amdgcn_global_load_lds(AS1C(vbase + (size_t)sr1 * TT + kt * 64 + csw), AS3(vL), 16, 0, 0);
    }
    __syncthreads();

    f32x4 sfr[4] = {};
    __builtin_amdgcn_s_setprio(1);
#pragma unroll
    for (int kk = 0; kk < 2; ++kk)
#pragma unroll
      for (int jf = 0; jf < 4; ++jf) {
        const int row = iq + 16 * jf;
        const int off = row * 128 + ((kk * 64 + g * 16) ^ ((row & 7) << 4));
        bf16x8 a = *reinterpret_cast<const bf16x8*>((const char*)Ks + off);
        sfr[jf] = __builtin_amdgcn_mfma_f32_16x16x32_bf16(a, qfrag[kk], sfr[jf], 0, 0, 0);
      }
    __builtin_amdgcn_s_setprio(0);

    float tm0 = fmaxf(fmaxf(sfr[0][0], sfr[0][1]), fmaxf(sfr[0][2], sfr[0][3]));
    float tm1 = fmaxf(fmaxf(sfr[1][0], sfr[1][1]), fmaxf(sfr[1][2], sfr[1][3]));
    float tm2 = fmaxf(fmaxf(sfr[2][0], sfr[2][1]), fmaxf(sfr[2][2], sfr[2][3]));
    float tm3 = fmaxf(fmaxf(sfr[3][0], sfr[3][1]), fmaxf(sfr[3][2], sfr[3][3]));
    float tmax = fmaxf(fmaxf(tm0, tm1), fmaxf(tm2, tm3));
    tmax = fmaxf(tmax, __shfl_xor(tmax, 16, 64));
    tmax = fmaxf(tmax, __shfl_xor(tmax, 32, 64));

    if (!__all(tmax <= mrun + 8.f)) {
      const float mnew  = fmaxf(mrun, tmax);
      const float alpha = exp2_fast(mrun - mnew);
      lrun *= alpha;
#pragma unroll
      for (int df = 0; df < 4; ++df)
#pragma unroll
        for (int r = 0; r < 4; ++r) ot[df][r] *= alpha;
      mrun = mnew;
    }

#pragma unroll
    for (int f = 0; f < 4; ++f) {
      float p0 = exp2_fast(sfr[f][0] - mrun);
      float p1 = exp2_fast(sfr[f][1] - mrun);
      float p2 = exp2_fast(sfr[f][2] - mrun);
      float p3 = exp2_fast(sfr[f][3] - mrun);
      lrun += (p0 + p1) + (p2 + p3);
      pw[iq][(8 * f + 2 * g + 0) ^ wsw] = cvt_pk_bf16(p0, p1);
      pw[iq][(8 * f + 2 * g + 1) ^ wsw] = cvt_pk_bf16(p2, p3);
    }
    asm volatile("s_waitcnt lgkmcnt(0)" ::: "memory");

    __builtin_amdgcn_s_setprio(1);
#pragma unroll
    for (int kk = 0; kk < 2; ++kk) {
      bf16x8 pb = *reinterpret_cast<const bf16x8*>(prow + ((kk * 64 + g * 16) ^ xsb));
#pragma unroll
      for (int df = 0; df < 4; ++df) {
        const int row = iq + 16 * df;
        const int off = row * 128 + ((kk * 64 + g * 16) ^ ((row & 7) << 4));
        bf16x8 a = *reinterpret_cast<const bf16x8*>((const char*)Vs + off);
        ot[df] = __builtin_amdgcn_mfma_f32_16x16x32_bf16(a, pb, ot[df], 0, 0, 0);
      }
    }
    __builtin_amdgcn_s_setprio(0);
  }

  lrun += __shfl_xor(lrun, 16, 64);
  lrun += __shfl_xor(lrun, 32, 64);
  const int grow = b * TT + qt * 128 + w * 16 + iq;
  const float inv = 1.f / lrun;
  ushort* orow = Obuf + (size_t)grow * CC + h * 64;
#pragma unroll
  for (int df = 0; df < 4; ++df) {
    uint2 st;
    st.x = cvt_pk_bf16(ot[df][0] * inv, ot[df][1] * inv);
    st.y = cvt_pk_bf16(ot[df][2] * inv, ot[df][3] * inv);
    *reinterpret_cast<uint2*>(orow + df * 16 + g * 4) = st;
  }
  if (g == 0) ml[(size_t)z * (MM * 16) + grow * 16 + h] = make_float2(mrun, lrun);
}

// ---------------- combine the two KV-split partials -> Attn (bf16) ----------------
__global__ __launch_bounds__(256) void attn_combine(const ushort* __restrict__ O0,
                                                    const ushort* __restrict__ O1,
                                                    const float2* __restrict__ ml,
                                                    ushort* __restrict__ attnb) {
  const int row = blockIdx.x, t = threadIdx.x;
  const int h = t >> 4;
  const float2 a = ml[(size_t)row * 16 + h];
  const float2 c = ml[(size_t)MM * 16 + (size_t)row * 16 + h];
  const float m  = fmaxf(a.x, c.x);
  const float w0 = exp2_fast(a.x - m) * a.y;
  const float w1 = exp2_fast(c.x - m) * c.y;
  const float inv = 1.f / (w0 + w1);
  const float s0 = w0 * inv, s1 = w1 * inv;
  const size_t off = (size_t)row * CC + t * 4;
  const uint2 r0 = *reinterpret_cast<const uint2*>(O0 + off);
  const uint2 r1 = *reinterpret_cast<const uint2*>(O1 + off);
  const float o0 = bfbits2f(r0.x << 16)         * s0 + bfbits2f(r1.x << 16)         * s1;
  const float o1 = bfbits2f(r0.x & 0xffff0000u) * s0 + bfbits2f(r1.x & 0xffff0000u) * s1;
  const float o2 = bfbits2f(r0.y << 16)         * s0 + bfbits2f(r1.y << 16)         * s1;
  const float o3 = bfbits2f(r0.y & 0xffff0000u) * s0 + bfbits2f(r1.y & 0xffff0000u) * s1;
  uint2 st;
  st.x = cvt_pk_bf16(o0, o1);
  st.y = cvt_pk_bf16(o2, o3);
  *reinterpret_cast<uint2*>(attnb + off) = st;
}

// --------------------------------- launcher -------------------------------------
extern "C" void kernel_launch(void* const* d_in, const int* in_sizes, int n_in,
                              void* d_out, int out_size, void* d_ws, size_t ws_size,
                              hipStream_t stream) {
  const float* x     = (const float*)d_in[0];
  const float* ln1_g = (const float*)d_in[1];
  const float* ln1_b = (const float*)d_in[2];
  const float* ln2_g = (const float*)d_in[3];
  const float* ln2_b = (const float*)d_in[4];
  const float* Wq = (const float*)d_in[5];
  const float* bq = (const float*)d_in[6];
  const float* Wk = (const float*)d_in[7];
  const float* bk = (const float*)d_in[8];
  const float* Wv = (const float*)d_in[9];
  const float* bv = (const float*)d_in[10];
  const float* Wo = (const float*)d_in[11];
  const float* bo = (const float*)d_in[12];
  const float* W1 = (const float*)d_in[13];
  const float* b1 = (const float*)d_in[14];
  const float* W2 = (const float*)d_in[15];
  const float* b2 = (const float*)d_in[16];
  float* out = (float*)d_out;
  char* ws = (char*)d_ws;

  // workspace layout (92.3 MB total, unchanged footprint)
  ushort* WqkvT = (ushort*)(ws + 0);          // 3072x1024 bf16 (6 MB)
  ushort* WoT   = (ushort*)(ws + 6291456);    // 1024x1024 bf16 (2 MB)
  ushort* W1T   = (ushort*)(ws + 8388608);    // 4096x1024 bf16 (8 MB)
  ushort* W2T   = (ushort*)(ws + 16777216);   // 1024x4096 bf16 (8 MB)
  float*  Bqkv  = (float*) (ws + 25165824);   // 3072 f32
  ushort* Xn    = (ushort*)(ws + 25178112);   // 4096x1024 bf16 (8 MB)
  ushort* Attn  = (ushort*)(ws + 33566720);   // 4096x1024 bf16 (8 MB)
  float*  X1f   = (float*) (ws + 41955328);   // 4096x1024 f32 (16 MB)
  ushort* Qkv   = (ushort*)(ws + 58732544);   // 4096x3072 bf16 (24 MB)
  ushort* Vtb   = (ushort*)(ws + 83898368);   // 2048x2048 bf16 (8 MB)
  ushort* Hid   = (ushort*)(ws + 58732544);   // 4096x4096 bf16 (reuses Qkv+Vtb)
  ushort* OP0   = (ushort*)(ws + 41955328);   // attn partials (X1f region, dead here)
  ushort* OP1   = (ushort*)(ws + 50343936);
  float2* mlbuf = (float2*)(ws + 0);          // 1 MB (WqkvT dead after QKV gemm)
  ushort* WoP0  = (ushort*)(ws + 58732544);   // Wo split-K4 partials (dead Qkv+Vtb)
  ushort* WoP1  = (ushort*)(ws + 67121152);
  ushort* WoP2  = (ushort*)(ws + 75509760);
  ushort* WoP3  = (ushort*)(ws + 83898368);
  ushort* F2P0  = (ushort*)(ws + 0);          // FC2 split-K4 partials (dead regions)
  ushort* F2P1  = (ushort*)(ws + 8388608);
  ushort* F2P2  = (ushort*)(ws + 25178112);
  ushort* F2P3  = (ushort*)(ws + 33566720);

  const dim3 blk(256);

  prep_weights<<<dim3(16396), blk, 0, stream>>>(Wq, Wk, Wv, Wo, W1, W2, bq, bk, bv,
                                                x, ln1_g, ln1_b,
                                                WqkvT, WoT, W1T, W2T, Bqkv, Xn);
  gemm_bf16<false, true><<<dim3(24, 32), blk, 0, stream>>>(
      Xn, WqkvT, Bqkv, Qkv, Vtb, NQKV, 1024);
  attn_partial<<<dim3(1024), dim3(512), 0, stream>>>(Qkv, Vtb, OP0, OP1, mlbuf);
  attn_combine<<<dim3(MM), blk, 0, stream>>>(OP0, OP1, mlbuf, Attn);
  gemm_splitk<<<dim3(8, 32, 4), blk, 0, stream>>>(Attn, WoT, WoP0, WoP1, WoP2, WoP3, 1024, 1024, 256);
  reduce_wo_ln<<<dim3(MM), blk, 0, stream>>>(WoP0, WoP1, WoP2, WoP3, x, bo, ln2_g, ln2_b, X1f, Xn);
  gemm_bf16<true, false><<<dim3(32, 32), blk, 0, stream>>>(
      Xn, W1T, b1, Hid, nullptr, HIDN, 1024);
  gemm_splitk<<<dim3(8, 32, 4), blk, 0, stream>>>(Hid, W2T, F2P0, F2P1, F2P2, F2P3, 1024, 4096, 1024);
  reduce_fc2<<<dim3(MM), blk, 0, stream>>>(F2P0, F2P1, F2P2, F2P3, X1f, b2, out);
}

// Round 9
// 257.826 us; speedup vs baseline: 11.6225x; 1.0932x over previous
//
#include <hip/hip_runtime.h>

typedef float f32x4 __attribute__((ext_vector_type(4)));
typedef __bf16 bf16x8 __attribute__((ext_vector_type(8)));

constexpr int TT   = 2048;
constexpr int CC   = 1024;
constexpr int HIDN = 4096;
constexpr int MM   = 4096;   // B*T rows
constexpr int NQKV = 3072;

union U84 { uint32_t u[4]; bf16x8 v; };

__device__ inline uint32_t cvt_pk_bf16(float lo, float hi) {
  uint32_t r;
  asm("v_cvt_pk_bf16_f32 %0, %1, %2" : "=v"(r) : "v"(lo), "v"(hi));
  return r;
}
__device__ inline ushort f2bf(float f) { return (ushort)(cvt_pk_bf16(f, 0.f) & 0xffffu); }
__device__ inline float bfbits2f(uint32_t bits) {
  union { uint32_t u; float f; } c; c.u = bits; return c.f;
}
__device__ inline float exp2_fast(float x) {
  float r;
  asm("v_exp_f32 %0, %1" : "=v"(r) : "v"(x));
  return r;
}

#define AS1C(p) ((__attribute__((address_space(1))) void*)(p))
#define AS3(p)  ((__attribute__((address_space(3))) void*)(p))

// ---------------- fused prep: weight transposes + bias concat + LN1 ----------------
__global__ __launch_bounds__(256) void prep_weights(const float* __restrict__ Wq,
                                                    const float* __restrict__ Wk,
                                                    const float* __restrict__ Wv,
                                                    const float* __restrict__ Wo,
                                                    const float* __restrict__ W1,
                                                    const float* __restrict__ W2,
                                                    const float* __restrict__ bq,
                                                    const float* __restrict__ bk,
                                                    const float* __restrict__ bv,
                                                    const float* __restrict__ x,
                                                    const float* __restrict__ g1,
                                                    const float* __restrict__ b1v,
                                                    ushort* __restrict__ WqkvT,
                                                    ushort* __restrict__ WoT,
                                                    ushort* __restrict__ W1T,
                                                    ushort* __restrict__ W2T,
                                                    float* __restrict__ Bqkv,
                                                    ushort* __restrict__ Xn) {
  const int id = blockIdx.x;
  const int t = threadIdx.x;
  if (id >= 12300) {   // LN1: rows 0..4095
    const int row = id - 12300;
    float4 v = reinterpret_cast<const float4*>(x + (size_t)row * CC)[t];
    float s  = v.x + v.y + v.z + v.w;
    float ss = v.x * v.x + v.y * v.y + v.z * v.z + v.w * v.w;
#pragma unroll
    for (int off = 32; off; off >>= 1) {
      s  += __shfl_down(s, off);
      ss += __shfl_down(ss, off);
    }
    __shared__ float red[16];
    const int wid = t >> 6, lane = t & 63;
    if (lane == 0) { red[wid] = s; red[8 + wid] = ss; }
    __syncthreads();
    if (t == 0) {
      red[0] = red[0] + red[1] + red[2] + red[3];
      red[8] = red[8] + red[9] + red[10] + red[11];
    }
    __syncthreads();
    const float mu   = red[0] * (1.0f / CC);
    const float var  = red[8] * (1.0f / CC) - mu * mu;
    const float rstd = rsqrtf(var + 1e-5f);
    float4 gg = reinterpret_cast<const float4*>(g1)[t];
    float4 bb = reinterpret_cast<const float4*>(b1v)[t];
    uint2 st;
    st.x = cvt_pk_bf16((v.x - mu) * rstd * gg.x + bb.x, (v.y - mu) * rstd * gg.y + bb.y);
    st.y = cvt_pk_bf16((v.z - mu) * rstd * gg.z + bb.z, (v.w - mu) * rstd * gg.w + bb.w);
    *reinterpret_cast<uint2*>(Xn + (size_t)row * CC + t * 4) = st;
    return;
  }
  if (id >= 12288) {   // bias concat: 12 blocks
    const int i = (id - 12288) * 256 + t;
    Bqkv[i] = (i < 1024) ? bq[i] : ((i < 2048) ? bk[i - 1024] : bv[i - 2048]);
    return;
  }
  const float* W; ushort* out; int Kd, Nd, bx, by, rowOff = 0;
  if (id < 4096) {
    const int which = id >> 10, sub = id & 1023;
    bx = sub & 31; by = sub >> 5; Kd = 1024; Nd = 1024;
    if (which == 0)      { W = Wq; out = WqkvT; rowOff = 0; }
    else if (which == 1) { W = Wk; out = WqkvT; rowOff = 1024; }
    else if (which == 2) { W = Wv; out = WqkvT; rowOff = 2048; }
    else                 { W = Wo; out = WoT; }
  } else if (id < 8192) {
    const int sub = id - 4096; bx = sub & 127; by = sub >> 7;
    W = W1; out = W1T; Kd = 1024; Nd = 4096;
  } else {
    const int sub = id - 8192; bx = sub & 31; by = sub >> 5;
    W = W2; out = W2T; Kd = 4096; Nd = 1024;
  }
  const int n0 = bx * 32, k0 = by * 32;
  __shared__ float Ts[32][33];
  {
    const int r = t >> 3, cb = (t & 7) * 4;
    float4 v = *reinterpret_cast<const float4*>(W + (size_t)(k0 + r) * Nd + n0 + cb);
    Ts[r][cb + 0] = v.x; Ts[r][cb + 1] = v.y; Ts[r][cb + 2] = v.z; Ts[r][cb + 3] = v.w;
  }
  __syncthreads();
  {
    const int nl = t >> 3, kb = (t & 7) * 4;
    uint2 st;
    st.x = cvt_pk_bf16(Ts[kb + 0][nl], Ts[kb + 1][nl]);
    st.y = cvt_pk_bf16(Ts[kb + 2][nl], Ts[kb + 3][nl]);
    *reinterpret_cast<uint2*>(out + (size_t)(rowOff + n0 + nl) * Kd + k0 + kb) = st;
  }
}

// ================= 256x256-tile 8-wave GEMM, counted-vmcnt pipeline =================
// C = A[M,K] @ Bt[N,K]^T. BK=32, 3 LDS buffers (96 KB), 2 MFMA phases/K-tile,
// raw s_barrier (no implicit vmcnt drain), vmcnt(8) steady state (2 tiles in flight),
// XOR-swizzled LDS (pre-swizzled global source, linear LDS dest), setprio on MFMA.
// Sync ledger: STAGE at iter kt writes buf[(kt+2)%3], whose readers (iter kt-1)
// all retired at iter kt-1's end barrier, which precedes this STAGE program-order.
template <bool RELU, bool VOUT, bool PARTIAL>
__global__ __launch_bounds__(512, 2) void gemm_8w(const ushort* __restrict__ A,
                                                  const ushort* __restrict__ Bt,
                                                  const float* __restrict__ bias,
                                                  ushort* __restrict__ outp,
                                                  ushort* __restrict__ Vt,
                                                  ushort* __restrict__ P1,
                                                  ushort* __restrict__ P2,
                                                  ushort* __restrict__ P3,
                                                  int N, int K, int Kchunk) {
  __shared__ ushort lds[49152];   // 3 buffers x (A 16 KB + B 16 KB)
  const int t = threadIdx.x, lane = t & 63, w = t >> 6;
  const int g = lane >> 4, i16 = lane & 15;
  const int wr = w >> 2, wc = w & 3;            // 2 x 4 wave grid; wave C: 128x64
  const int nwg  = gridDim.x * gridDim.y;
  const int orig = blockIdx.y * gridDim.x + blockIdx.x;
  const int sw   = (orig & 7) * (nwg >> 3) + (orig >> 3);
  const int row0 = (sw / gridDim.x) * 256, col0 = (sw % gridDim.x) * 256;
  const int kstart = PARTIAL ? blockIdx.z * Kchunk : 0;
  const int NT = (PARTIAL ? Kchunk : K) >> 5;
  ushort* __restrict__ Out = outp;
  if (PARTIAL) Out = (blockIdx.z == 0) ? outp : (blockIdx.z == 1) ? P1
              : (blockIdx.z == 2) ? P2 : P3;

  // staging: 2 chunks (16 B) per matrix per thread; source k-slot pre-swizzled
  const int c1 = t, c2 = t + 512;
  const int r1 = c1 >> 2, s1 = (c1 & 3) ^ ((r1 >> 1) & 3);
  const int r2 = c2 >> 2, s2 = (c2 & 3) ^ ((r2 >> 1) & 3);
  const ushort* aG1 = A + (size_t)(row0 + r1) * K + kstart + s1 * 8;
  const ushort* aG2 = A + (size_t)(row0 + r2) * K + kstart + s2 * 8;
  const ushort* bG1 = Bt + (size_t)(col0 + r1) * K + kstart + s1 * 8;
  const ushort* bG2 = Bt + (size_t)(col0 + r2) * K + kstart + s2 * 8;

  // fragment byte offsets (read-side swizzle matches source pre-swizzle)
  int aoff[8], boff[4];
#pragma unroll
  for (int mf = 0; mf < 8; ++mf) {
    const int R = wr * 128 + mf * 16 + i16;
    aoff[mf] = R * 64 + ((g ^ ((R >> 1) & 3)) << 4);
  }
#pragma unroll
  for (int nf = 0; nf < 4; ++nf) {
    const int Cn = wc * 64 + nf * 16 + i16;
    boff[nf] = Cn * 64 + ((g ^ ((Cn >> 1) & 3)) << 4);
  }

  f32x4 acc[8][4] = {};

  auto STAGE = [&](int bi, int kt) {
    char* aB = (char*)lds + bi * 32768;
    char* bB = aB + 16384;
    const int ko = kt * 32;
    __builtin_amdgcn_global_load_lds(AS1C(aG1 + ko), AS3(aB + w * 1024), 16, 0, 0);
    __builtin_amdgcn_global_load_lds(AS1C(aG2 + ko), AS3(aB + 8192 + w * 1024), 16, 0, 0);
    __builtin_amdgcn_global_load_lds(AS1C(bG1 + ko), AS3(bB + w * 1024), 16, 0, 0);
    __builtin_amdgcn_global_load_lds(AS1C(bG2 + ko), AS3(bB + 8192 + w * 1024), 16, 0, 0);
  };

  STAGE(0, 0);
  if (NT > 1) STAGE(1, 1);

  for (int kt = 0; kt < NT; ++kt) {
    const int cur = kt % 3;
    if (kt + 2 < NT) STAGE((kt + 2) % 3, kt + 2);   // buffer freed at iter kt-1's end barrier
    if (kt + 2 < NT)      asm volatile("s_waitcnt vmcnt(8)" ::: "memory");   // tile kt landed
    else if (kt + 1 < NT) asm volatile("s_waitcnt vmcnt(4)" ::: "memory");
    else                  asm volatile("s_waitcnt vmcnt(0)" ::: "memory");
    asm volatile("s_barrier" ::: "memory");          // b1: tile kt visible to all waves
    __builtin_amdgcn_sched_barrier(0);

    const char* aB = (const char*)lds + cur * 32768;
    const char* bB = aB + 16384;
    bf16x8 b4[4], a4[4];
#pragma unroll
    for (int nf = 0; nf < 4; ++nf) b4[nf] = *reinterpret_cast<const bf16x8*>(bB + boff[nf]);
#pragma unroll
    for (int mf = 0; mf < 4; ++mf) a4[mf] = *reinterpret_cast<const bf16x8*>(aB + aoff[mf]);
    __builtin_amdgcn_s_setprio(1);
#pragma unroll
    for (int mf = 0; mf < 4; ++mf)
#pragma unroll
      for (int nf = 0; nf < 4; ++nf)
        acc[mf][nf] = __builtin_amdgcn_mfma_f32_16x16x32_bf16(a4[mf], b4[nf], acc[mf][nf], 0, 0, 0);
    __builtin_amdgcn_s_setprio(0);
    asm volatile("s_barrier" ::: "memory");          // mid: pace cross-wave interleave
    __builtin_amdgcn_sched_barrier(0);
#pragma unroll
    for (int mf = 0; mf < 4; ++mf) a4[mf] = *reinterpret_cast<const bf16x8*>(aB + aoff[mf + 4]);
    __builtin_amdgcn_s_setprio(1);
#pragma unroll
    for (int mf = 0; mf < 4; ++mf)
#pragma unroll
      for (int nf = 0; nf < 4; ++nf)
        acc[mf + 4][nf] = __builtin_amdgcn_mfma_f32_16x16x32_bf16(a4[mf], b4[nf], acc[mf + 4][nf], 0, 0, 0);
    __builtin_amdgcn_s_setprio(0);
    asm volatile("s_barrier" ::: "memory");          // end: all reads of buf cur retired
    __builtin_amdgcn_sched_barrier(0);
  }

  // ---------------- epilogue ----------------
  const int qcol0 = col0 + wc * 64;

  if (VOUT && qcol0 >= 2048) {
    // V projection quadrant: write transposed into Vt[bh*64+d][token]
#pragma unroll
    for (int nf = 0; nf < 4; ++nf) {
      const int ncol = qcol0 + nf * 16 + i16;
      const float bb = bias[ncol];
      const int d = ncol - 2048;
      const int hh = d >> 6, dd = d & 63;
#pragma unroll
      for (int mf = 0; mf < 8; ++mf) {
        const int mrow = row0 + wr * 128 + mf * 16 + 4 * g;
        const int bb_ = mrow >> 11, tok = mrow & 2047;
        uint2 st;
        st.x = cvt_pk_bf16(acc[mf][nf][0] + bb, acc[mf][nf][1] + bb);
        st.y = cvt_pk_bf16(acc[mf][nf][2] + bb, acc[mf][nf][3] + bb);
        *reinterpret_cast<uint2*>(Vt + (size_t)((bb_ * 16 + hh) * 64 + dd) * TT + tok) = st;
      }
    }
    return;
  }

  // coalesced epilogue: per-wave 4 KB LDS scratch (staging LDS is dead)
  float* Lf = (float*)((char*)lds + w * 4096);
  const int rr2 = lane >> 2, q = lane & 3;
#pragma unroll
  for (int mf = 0; mf < 8; ++mf) {
#pragma unroll
    for (int nf = 0; nf < 4; ++nf)
#pragma unroll
      for (int r = 0; r < 4; ++r) {
        const int row = 4 * g + r;
        Lf[row * 64 + ((16 * nf + i16) ^ ((row & 7) << 2))] = acc[mf][nf][r];
      }
    asm volatile("s_waitcnt lgkmcnt(0)" ::: "memory");
    uint32_t u[8];
#pragma unroll
    for (int j = 0; j < 4; ++j) {
      f32x4 v = *reinterpret_cast<const f32x4*>(Lf + rr2 * 64 + ((q * 16 + 4 * j) ^ ((rr2 & 7) << 2)));
      float e0 = v[0], e1 = v[1], e2 = v[2], e3 = v[3];
      if (!PARTIAL) {
        const float4 b4 = *reinterpret_cast<const float4*>(bias + qcol0 + q * 16 + 4 * j);
        e0 += b4.x; e1 += b4.y; e2 += b4.z; e3 += b4.w;
        if (RELU) {
          e0 = fmaxf(e0, 0.f); e1 = fmaxf(e1, 0.f);
          e2 = fmaxf(e2, 0.f); e3 = fmaxf(e3, 0.f);
        }
      }
      u[2 * j + 0] = cvt_pk_bf16(e0, e1);
      u[2 * j + 1] = cvt_pk_bf16(e2, e3);
    }
    const int mrow = row0 + wr * 128 + mf * 16 + rr2;
    ushort* orow = Out + (size_t)mrow * N + qcol0 + q * 16;
    uint4 s0; s0.x = u[0]; s0.y = u[1]; s0.z = u[2]; s0.w = u[3];
    uint4 s1; s1.x = u[4]; s1.y = u[5]; s1.z = u[6]; s1.w = u[7];
    *reinterpret_cast<uint4*>(orow) = s0;
    *reinterpret_cast<uint4*>(orow + 8) = s1;
    asm volatile("s_waitcnt lgkmcnt(0)" ::: "memory");
  }
}

// ---------------- split-K (4-way) 128-tile bf16 GEMM (kept for Wo) ----------------
__global__ __launch_bounds__(256) void gemm_splitk(const ushort* __restrict__ A,
                                                   const ushort* __restrict__ Bt,
                                                   ushort* __restrict__ P0,
                                                   ushort* __restrict__ P1,
                                                   ushort* __restrict__ P2,
                                                   ushort* __restrict__ P3,
                                                   int N, int K, int Kchunk) {
  __shared__ ushort Smem[8192];
  ushort* Asm = Smem;
  ushort* Bsm = Smem + 4096;
  const int t = threadIdx.x;
  const int lane = t & 63, w = t >> 6;
  const int g = lane >> 4, i16 = lane & 15;
  const int wrow = w >> 1, wcol = w & 1;
  const int nwg  = gridDim.x * gridDim.y;
  const int orig = blockIdx.y * gridDim.x + blockIdx.x;
  const int sw   = (orig & 7) * (nwg >> 3) + (orig >> 3);
  const int row0 = (sw / gridDim.x) * 128, col0 = (sw % gridDim.x) * 128;
  const int kstart = blockIdx.z * Kchunk;
  ushort* __restrict__ P = (blockIdx.z == 0) ? P0 : (blockIdx.z == 1) ? P1
                          : (blockIdx.z == 2) ? P2 : P3;

  f32x4 acc[4][4] = {};

  const int srow = t >> 2, sc = (t & 3) * 8;
  const ushort* aS1 = A + (size_t)(row0 + srow) * K + sc;
  const ushort* aS2 = A + (size_t)(row0 + 64 + srow) * K + sc;
  const ushort* bS1 = Bt + (size_t)(col0 + srow) * K + sc;
  const ushort* bS2 = Bt + (size_t)(col0 + 64 + srow) * K + sc;
  char* aL1 = (char*)Asm + w * 1024;
  char* aL2 = (char*)Asm + 4096 + w * 1024;
  char* bL1 = (char*)Bsm + w * 1024;
  char* bL2 = (char*)Bsm + 4096 + w * 1024;

  for (int k0 = kstart; k0 < kstart + Kchunk; k0 += 32) {
    __syncthreads();
    __builtin_amdgcn_global_load_lds(AS1C(aS1 + k0), AS3(aL1), 16, 0, 0);
    __builtin_amdgcn_global_load_lds(AS1C(aS2 + k0), AS3(aL2), 16, 0, 0);
    __builtin_amdgcn_global_load_lds(AS1C(bS1 + k0), AS3(bL1), 16, 0, 0);
    __builtin_amdgcn_global_load_lds(AS1C(bS2 + k0), AS3(bL2), 16, 0, 0);
    __syncthreads();

    bf16x8 a4[4], b4[4];
#pragma unroll
    for (int mf = 0; mf < 4; ++mf) {
      const int r = wrow * 64 + mf * 16 + i16;
      a4[mf] = *reinterpret_cast<const bf16x8*>((const char*)Asm + r * 64 + g * 16);
    }
#pragma unroll
    for (int nf = 0; nf < 4; ++nf) {
      const int c = wcol * 64 + nf * 16 + i16;
      b4[nf] = *reinterpret_cast<const bf16x8*>((const char*)Bsm + c * 64 + g * 16);
    }
#pragma unroll
    for (int mf = 0; mf < 4; ++mf)
#pragma unroll
      for (int nf = 0; nf < 4; ++nf)
        acc[mf][nf] = __builtin_amdgcn_mfma_f32_16x16x32_bf16(a4[mf], b4[nf], acc[mf][nf], 0, 0, 0);
  }

  __syncthreads();

  float* Lf = (float*)((char*)Smem + w * 4096);
  const int qcol0 = col0 + wcol * 64;
  const int rr = lane >> 2, q = lane & 3;
#pragma unroll
  for (int mf = 0; mf < 4; ++mf) {
#pragma unroll
    for (int nf = 0; nf < 4; ++nf)
#pragma unroll
      for (int r = 0; r < 4; ++r) {
        const int row = 4 * g + r;
        Lf[row * 64 + ((16 * nf + i16) ^ ((row & 7) << 2))] = acc[mf][nf][r];
      }
    asm volatile("s_waitcnt lgkmcnt(0)" ::: "memory");
    uint32_t u[8];
#pragma unroll
    for (int j = 0; j < 4; ++j) {
      f32x4 v = *reinterpret_cast<const f32x4*>(Lf + rr * 64 + ((q * 16 + 4 * j) ^ ((rr & 7) << 2)));
      u[2 * j + 0] = cvt_pk_bf16(v[0], v[1]);
      u[2 * j + 1] = cvt_pk_bf16(v[2], v[3]);
    }
    const int mrow = row0 + wrow * 64 + mf * 16 + rr;
    ushort* orow = P + (size_t)mrow * N + qcol0 + q * 16;
    uint4 s0; s0.x = u[0]; s0.y = u[1]; s0.z = u[2]; s0.w = u[3];
    uint4 s1; s1.x = u[4]; s1.y = u[5]; s1.z = u[6]; s1.w = u[7];
    *reinterpret_cast<uint4*>(orow) = s0;
    *reinterpret_cast<uint4*>(orow + 8) = s1;
    asm volatile("s_waitcnt lgkmcnt(0)" ::: "memory");
  }
}

__device__ inline float bfsum4(uint32_t a, uint32_t b, uint32_t c, uint32_t d, bool hi) {
  if (hi) return bfbits2f(a & 0xffff0000u) + bfbits2f(b & 0xffff0000u) +
                 bfbits2f(c & 0xffff0000u) + bfbits2f(d & 0xffff0000u);
  return bfbits2f(a << 16) + bfbits2f(b << 16) + bfbits2f(c << 16) + bfbits2f(d << 16);
}

// ---------------- Wo reduce (4 partials) + residual + LN2 fused ----------------
__global__ __launch_bounds__(256) void reduce_wo_ln(const ushort* __restrict__ P0,
                                                    const ushort* __restrict__ P1,
                                                    const ushort* __restrict__ P2,
                                                    const ushort* __restrict__ P3,
                                                    const float* __restrict__ x,
                                                    const float* __restrict__ bo,
                                                    const float* __restrict__ g,
                                                    const float* __restrict__ b,
                                                    float* __restrict__ X1f,
                                                    ushort* __restrict__ Xn) {
  const int row = blockIdx.x, t = threadIdx.x;
  const size_t off = (size_t)row * CC + t * 4;
  float4 v  = *reinterpret_cast<const float4*>(x + off);
  const uint2 q0 = *reinterpret_cast<const uint2*>(P0 + off);
  const uint2 q1 = *reinterpret_cast<const uint2*>(P1 + off);
  const uint2 q2 = *reinterpret_cast<const uint2*>(P2 + off);
  const uint2 q3 = *reinterpret_cast<const uint2*>(P3 + off);
  float4 bb = reinterpret_cast<const float4*>(bo)[t];
  v.x += bfsum4(q0.x, q1.x, q2.x, q3.x, false) + bb.x;
  v.y += bfsum4(q0.x, q1.x, q2.x, q3.x, true)  + bb.y;
  v.z += bfsum4(q0.y, q1.y, q2.y, q3.y, false) + bb.z;
  v.w += bfsum4(q0.y, q1.y, q2.y, q3.y, true)  + bb.w;
  *reinterpret_cast<float4*>(X1f + off) = v;

  float s  = v.x + v.y + v.z + v.w;
  float ss = v.x * v.x + v.y * v.y + v.z * v.z + v.w * v.w;
#pragma unroll
  for (int o = 32; o; o >>= 1) {
    s  += __shfl_down(s, o);
    ss += __shfl_down(ss, o);
  }
  __shared__ float red[16];
  const int wid = t >> 6, lane = t & 63;
  if (lane == 0) { red[wid] = s; red[8 + wid] = ss; }
  __syncthreads();
  if (t == 0) {
    red[0] = red[0] + red[1] + red[2] + red[3];
    red[8] = red[8] + red[9] + red[10] + red[11];
  }
  __syncthreads();
  const float mu   = red[0] * (1.0f / CC);
  const float var  = red[8] * (1.0f / CC) - mu * mu;
  const float rstd = rsqrtf(var + 1e-5f);
  float4 gg = reinterpret_cast<const float4*>(g)[t];
  float4 lb = reinterpret_cast<const float4*>(b)[t];
  uint2 st;
  st.x = cvt_pk_bf16((v.x - mu) * rstd * gg.x + lb.x, (v.y - mu) * rstd * gg.y + lb.y);
  st.y = cvt_pk_bf16((v.z - mu) * rstd * gg.z + lb.z, (v.w - mu) * rstd * gg.w + lb.w);
  *reinterpret_cast<uint2*>(Xn + off) = st;
}

// ---------------- FC2 reduce (4 partials) + bias + residual -> final out ----------------
__global__ __launch_bounds__(256) void reduce_fc2(const ushort* __restrict__ P0,
                                                  const ushort* __restrict__ P1,
                                                  const ushort* __restrict__ P2,
                                                  const ushort* __restrict__ P3,
                                                  const float* __restrict__ X1,
                                                  const float* __restrict__ b2,
                                                  float* __restrict__ out) {
  const int row = blockIdx.x, t = threadIdx.x;
  const size_t off = (size_t)row * CC + t * 4;
  float4 v  = *reinterpret_cast<const float4*>(X1 + off);
  const uint2 q0 = *reinterpret_cast<const uint2*>(P0 + off);
  const uint2 q1 = *reinterpret_cast<const uint2*>(P1 + off);
  const uint2 q2 = *reinterpret_cast<const uint2*>(P2 + off);
  const uint2 q3 = *reinterpret_cast<const uint2*>(P3 + off);
  float4 bb = reinterpret_cast<const float4*>(b2)[t];
  v.x += bfsum4(q0.x, q1.x, q2.x, q3.x, false) + bb.x;
  v.y += bfsum4(q0.x, q1.x, q2.x, q3.x, true)  + bb.y;
  v.z += bfsum4(q0.y, q1.y, q2.y, q3.y, false) + bb.z;
  v.w += bfsum4(q0.y, q1.y, q2.y, q3.y, true)  + bb.w;
  *reinterpret_cast<float4*>(out + off) = v;
}

// ---------------- MFMA flash attention: QBLK=128, 8 waves, KV-split x2 ----------------
__global__ __launch_bounds__(512) void attn_partial(const ushort* __restrict__ qkv,
                                                    const ushort* __restrict__ Vt,
                                                    ushort* __restrict__ O0,
                                                    ushort* __restrict__ O1,
                                                    float2* __restrict__ ml) {
  __shared__ ushort Ks[64 * 64];
  __shared__ ushort Vs[64 * 64];
  __shared__ uint32_t Ps[8][16][36];   // per-wave P strip
  const int t = threadIdx.x, lane = t & 63, w = t >> 6;   // w in 0..7
  const int g = lane >> 4, iq = lane & 15;
  const int flat = blockIdx.x;
  const int work = (flat & 7) * 128 + (flat >> 3);
  const int bh = work >> 5;
  const int rem = work & 31;
  const int z = rem >> 4;
  const int qt = rem & 15;
  const int b = bh >> 4, h = bh & 15;
  ushort* __restrict__ Obuf = z ? O1 : O0;

  bf16x8 qfrag[2];
  {
    const ushort* qrow = qkv + (size_t)(b * TT + qt * 128 + w * 16 + iq) * NQKV + h * 64;
    const float qs = 0.125f * 1.44269504f;
#pragma unroll
    for (int kk = 0; kk < 2; ++kk) {
      uint4 raw = *reinterpret_cast<const uint4*>(qrow + kk * 32 + g * 8);
      uint32_t rr[4] = {raw.x, raw.y, raw.z, raw.w};
      U84 tmp;
#pragma unroll
      for (int c = 0; c < 4; ++c) {
        float lo = bfbits2f(rr[c] << 16) * qs;
        float hi = bfbits2f(rr[c] & 0xffff0000u) * qs;
        tmp.u[c] = cvt_pk_bf16(lo, hi);
      }
      qfrag[kk] = tmp.v;
    }
  }

  const int sr1 = t >> 3, sc1 = t & 7;
  const int csw = (sc1 ^ (sr1 & 7)) * 8;
  const ushort* kbase = qkv + 1024 + h * 64;
  const ushort* vbase = Vt + (size_t)(bh * 64) * TT;
  char* kL = (char*)Ks + w * 1024;
  char* vL = (char*)Vs + w * 1024;

  uint32_t (*pw)[36] = Ps[w];
  const int wsw = (iq & 8) << 1;
  const int xsb = wsw << 2;
  const char* prow = (const char*)&pw[iq][0];

  float mrun = -3e38f, lrun = 0.f;
  f32x4 ot[4] = {};

  const int kt0 = z * 16;
  for (int kt = kt0; kt < kt0 + 16; ++kt) {
    __syncthreads();
    {
      const size_t tok = (size_t)(b * TT + kt * 64);
      __builtin_amdgcn_global_load_lds(AS1C(kbase + (tok + sr1) * NQKV + csw), AS3(kL), 16, 0, 0);
      __builtin_amdgcn_global_load_lds(AS1C(vbase + (size_t)sr1 * TT + kt * 64 + csw), AS3(vL), 16, 0, 0);
    }
    __syncthreads();

    f32x4 sfr[4] = {};
    __builtin_amdgcn_s_setprio(1);
#pragma unroll
    for (int kk = 0; kk < 2; ++kk)
#pragma unroll
      for (int jf = 0; jf < 4; ++jf) {
        const int row = iq + 16 * jf;
        const int off = row * 128 + ((kk * 64 + g * 16) ^ ((row & 7) << 4));
        bf16x8 a = *reinterpret_cast<const bf16x8*>((const char*)Ks + off);
        sfr[jf] = __builtin_amdgcn_mfma_f32_16x16x32_bf16(a, qfrag[kk], sfr[jf], 0, 0, 0);
      }
    __builtin_amdgcn_s_setprio(0);

    float tm0 = fmaxf(fmaxf(sfr[0][0], sfr[0][1]), fmaxf(sfr[0][2], sfr[0][3]));
    float tm1 = fmaxf(fmaxf(sfr[1][0], sfr[1][1]), fmaxf(sfr[1][2], sfr[1][3]));
    float tm2 = fmaxf(fmaxf(sfr[2][0], sfr[2][1]), fmaxf(sfr[2][2], sfr[2][3]));
    float tm3 = fmaxf(fmaxf(sfr[3][0], sfr[3][1]), fmaxf(sfr[3][2], sfr[3][3]));
    float tmax = fmaxf(fmaxf(tm0, tm1), fmaxf(tm2, tm3));
    tmax = fmaxf(tmax, __shfl_xor(tmax, 16, 64));
    tmax = fmaxf(tmax, __shfl_xor(tmax, 32, 64));

    if (!__all(tmax <= mrun + 8.f)) {
      const float mnew  = fmaxf(mrun, tmax);
      const float alpha = exp2_fast(mrun - mnew);
      lrun *= alpha;
#pragma unroll
      for (int df = 0; df < 4; ++df)
#pragma unroll
        for (int r = 0; r < 4; ++r) ot[df][r] *= alpha;
      mrun = mnew;
    }

#pragma unroll
    for (int f = 0; f < 4; ++f) {
      float p0 = exp2_fast(sfr[f][0] - mrun);
      float p1 = exp2_fast(sfr[f][1] - mrun);
      float p2 = exp2_fast(sfr[f][2] - mrun);
      float p3 = exp2_fast(sfr[f][3] - mrun);
      lrun += (p0 + p1) + (p2 + p3);
      pw[iq][(8 * f + 2 * g + 0) ^ wsw] = cvt_pk_bf16(p0, p1);
      pw[iq][(8 * f + 2 * g + 1) ^ wsw] = cvt_pk_bf16(p2, p3);
    }
    asm volatile("s_waitcnt lgkmcnt(0)" ::: "memory");

    __builtin_amdgcn_s_setprio(1);
#pragma unroll
    for (int kk = 0; kk < 2; ++kk) {
      bf16x8 pb = *reinterpret_cast<const bf16x8*>(prow + ((kk * 64 + g * 16) ^ xsb));
#pragma unroll
      for (int df = 0; df < 4; ++df) {
        const int row = iq + 16 * df;
        const int off = row * 128 + ((kk * 64 + g * 16) ^ ((row & 7) << 4));
        bf16x8 a = *reinterpret_cast<const bf16x8*>((const char*)Vs + off);
        ot[df] = __builtin_amdgcn_mfma_f32_16x16x32_bf16(a, pb, ot[df], 0, 0, 0);
      }
    }
    __builtin_amdgcn_s_setprio(0);
  }

  lrun += __shfl_xor(lrun, 16, 64);
  lrun += __shfl_xor(lrun, 32, 64);
  const int grow = b * TT + qt * 128 + w * 16 + iq;
  const float inv = 1.f / lrun;
  ushort* orow = Obuf + (size_t)grow * CC + h * 64;
#pragma unroll
  for (int df = 0; df < 4; ++df) {
    uint2 st;
    st.x = cvt_pk_bf16(ot[df][0] * inv, ot[df][1] * inv);
    st.y = cvt_pk_bf16(ot[df][2] * inv, ot[df][3] * inv);
    *reinterpret_cast<uint2*>(orow + df * 16 + g * 4) = st;
  }
  if (g == 0) ml[(size_t)z * (MM * 16) + grow * 16 + h] = make_float2(mrun, lrun);
}

// ---------------- combine the two KV-split partials -> Attn (bf16) ----------------
__global__ __launch_bounds__(256) void attn_combine(const ushort* __restrict__ O0,
                                                    const ushort* __restrict__ O1,
                                                    const float2* __restrict__ ml,
                                                    ushort* __restrict__ attnb) {
  const int row = blockIdx.x, t = threadIdx.x;
  const int h = t >> 4;
  const float2 a = ml[(size_t)row * 16 + h];
  const float2 c = ml[(size_t)MM * 16 + (size_t)row * 16 + h];
  const float m  = fmaxf(a.x, c.x);
  const float w0 = exp2_fast(a.x - m) * a.y;
  const float w1 = exp2_fast(c.x - m) * c.y;
  const float inv = 1.f / (w0 + w1);
  const float s0 = w0 * inv, s1 = w1 * inv;
  const size_t off = (size_t)row * CC + t * 4;
  const uint2 r0 = *reinterpret_cast<const uint2*>(O0 + off);
  const uint2 r1 = *reinterpret_cast<const uint2*>(O1 + off);
  const float o0 = bfbits2f(r0.x << 16)         * s0 + bfbits2f(r1.x << 16)         * s1;
  const float o1 = bfbits2f(r0.x & 0xffff0000u) * s0 + bfbits2f(r1.x & 0xffff0000u) * s1;
  const float o2 = bfbits2f(r0.y << 16)         * s0 + bfbits2f(r1.y << 16)         * s1;
  const float o3 = bfbits2f(r0.y & 0xffff0000u) * s0 + bfbits2f(r1.y & 0xffff0000u) * s1;
  uint2 st;
  st.x = cvt_pk_bf16(o0, o1);
  st.y = cvt_pk_bf16(o2, o3);
  *reinterpret_cast<uint2*>(attnb + off) = st;
}

// --------------------------------- launcher -------------------------------------
extern "C" void kernel_launch(void* const* d_in, const int* in_sizes, int n_in,
                              void* d_out, int out_size, void* d_ws, size_t ws_size,
                              hipStream_t stream) {
  const float* x     = (const float*)d_in[0];
  const float* ln1_g = (const float*)d_in[1];
  const float* ln1_b = (const float*)d_in[2];
  const float* ln2_g = (const float*)d_in[3];
  const float* ln2_b = (const float*)d_in[4];
  const float* Wq = (const float*)d_in[5];
  const float* bq = (const float*)d_in[6];
  const float* Wk = (const float*)d_in[7];
  const float* bk = (const float*)d_in[8];
  const float* Wv = (const float*)d_in[9];
  const float* bv = (const float*)d_in[10];
  const float* Wo = (const float*)d_in[11];
  const float* bo = (const float*)d_in[12];
  const float* W1 = (const float*)d_in[13];
  const float* b1 = (const float*)d_in[14];
  const float* W2 = (const float*)d_in[15];
  const float* b2 = (const float*)d_in[16];
  float* out = (float*)d_out;
  char* ws = (char*)d_ws;

  // workspace layout (92.3 MB total, unchanged footprint)
  ushort* WqkvT = (ushort*)(ws + 0);          // 3072x1024 bf16 (6 MB)
  ushort* WoT   = (ushort*)(ws + 6291456);    // 1024x1024 bf16 (2 MB)
  ushort* W1T   = (ushort*)(ws + 8388608);    // 4096x1024 bf16 (8 MB)
  ushort* W2T   = (ushort*)(ws + 16777216);   // 1024x4096 bf16 (8 MB)
  float*  Bqkv  = (float*) (ws + 25165824);   // 3072 f32
  ushort* Xn    = (ushort*)(ws + 25178112);   // 4096x1024 bf16 (8 MB)
  ushort* Attn  = (ushort*)(ws + 33566720);   // 4096x1024 bf16 (8 MB)
  float*  X1f   = (float*) (ws + 41955328);   // 4096x1024 f32 (16 MB)
  ushort* Qkv   = (ushort*)(ws + 58732544);   // 4096x3072 bf16 (24 MB)
  ushort* Vtb   = (ushort*)(ws + 83898368);   // 2048x2048 bf16 (8 MB)
  ushort* Hid   = (ushort*)(ws + 58732544);   // 4096x4096 bf16 (reuses Qkv+Vtb)
  ushort* OP0   = (ushort*)(ws + 41955328);   // attn partials (X1f region, dead here)
  ushort* OP1   = (ushort*)(ws + 50343936);
  float2* mlbuf = (float2*)(ws + 0);          // 1 MB (WqkvT dead after QKV gemm)
  ushort* WoP0  = (ushort*)(ws + 58732544);   // Wo split-K4 partials (dead Qkv+Vtb)
  ushort* WoP1  = (ushort*)(ws + 67121152);
  ushort* WoP2  = (ushort*)(ws + 75509760);
  ushort* WoP3  = (ushort*)(ws + 83898368);
  ushort* F2P0  = (ushort*)(ws + 0);          // FC2 split-K4 partials (dead regions)
  ushort* F2P1  = (ushort*)(ws + 8388608);
  ushort* F2P2  = (ushort*)(ws + 25178112);
  ushort* F2P3  = (ushort*)(ws + 33566720);

  const dim3 blk(256);

  prep_weights<<<dim3(16396), blk, 0, stream>>>(Wq, Wk, Wv, Wo, W1, W2, bq, bk, bv,
                                                x, ln1_g, ln1_b,
                                                WqkvT, WoT, W1T, W2T, Bqkv, Xn);
  // QKV: 256^2 8-wave pipelined GEMM; V columns written transposed to Vtb
  gemm_8w<false, true, false><<<dim3(12, 16), dim3(512), 0, stream>>>(
      Xn, WqkvT, Bqkv, Qkv, Vtb, nullptr, nullptr, nullptr, NQKV, 1024, 0);
  attn_partial<<<dim3(1024), dim3(512), 0, stream>>>(Qkv, Vtb, OP0, OP1, mlbuf);
  attn_combine<<<dim3(MM), blk, 0, stream>>>(OP0, OP1, mlbuf, Attn);
  gemm_splitk<<<dim3(8, 32, 4), blk, 0, stream>>>(Attn, WoT, WoP0, WoP1, WoP2, WoP3, 1024, 1024, 256);
  reduce_wo_ln<<<dim3(MM), blk, 0, stream>>>(WoP0, WoP1, WoP2, WoP3, x, bo, ln2_g, ln2_b, X1f, Xn);
  // FC1: 256^2 8-wave pipelined GEMM + ReLU
  gemm_8w<true, false, false><<<dim3(16, 16), dim3(512), 0, stream>>>(
      Xn, W1T, b1, Hid, nullptr, nullptr, nullptr, nullptr, HIDN, 1024, 0);
  // FC2: 256^2 8-wave pipelined GEMM, split-K4, bf16 partials
  gemm_8w<false, false, true><<<dim3(4, 16, 4), dim3(512), 0, stream>>>(
      Hid, W2T, nullptr, F2P0, nullptr, F2P1, F2P2, F2P3, 1024, 4096, 1024);
  reduce_fc2<<<dim3(MM), blk, 0, stream>>>(F2P0, F2P1, F2P2, F2P3, X1f, b2, out);
}

// Round 10
// 255.906 us; speedup vs baseline: 11.7097x; 1.0075x over previous
//
#include <hip/hip_runtime.h>

typedef float f32x4 __attribute__((ext_vector_type(4)));
typedef __bf16 bf16x8 __attribute__((ext_vector_type(8)));

constexpr int TT   = 2048;
constexpr int CC   = 1024;
constexpr int HIDN = 4096;
constexpr int MM   = 4096;   // B*T rows
constexpr int NQKV = 3072;

union U84 { uint32_t u[4]; bf16x8 v; };

__device__ inline uint32_t cvt_pk_bf16(float lo, float hi) {
  uint32_t r;
  asm("v_cvt_pk_bf16_f32 %0, %1, %2" : "=v"(r) : "v"(lo), "v"(hi));
  return r;
}
__device__ inline ushort f2bf(float f) { return (ushort)(cvt_pk_bf16(f, 0.f) & 0xffffu); }
__device__ inline float bfbits2f(uint32_t bits) {
  union { uint32_t u; float f; } c; c.u = bits; return c.f;
}
__device__ inline float exp2_fast(float x) {
  float r;
  asm("v_exp_f32 %0, %1" : "=v"(r) : "v"(x));
  return r;
}

#define AS1C(p) ((__attribute__((address_space(1))) void*)(p))
#define AS3(p)  ((__attribute__((address_space(3))) void*)(p))

// ---------------- fused prep: weight transposes + bias concat + LN1 ----------------
__global__ __launch_bounds__(256) void prep_weights(const float* __restrict__ Wq,
                                                    const float* __restrict__ Wk,
                                                    const float* __restrict__ Wv,
                                                    const float* __restrict__ Wo,
                                                    const float* __restrict__ W1,
                                                    const float* __restrict__ W2,
                                                    const float* __restrict__ bq,
                                                    const float* __restrict__ bk,
                                                    const float* __restrict__ bv,
                                                    const float* __restrict__ x,
                                                    const float* __restrict__ g1,
                                                    const float* __restrict__ b1v,
                                                    ushort* __restrict__ WqkvT,
                                                    ushort* __restrict__ WoT,
                                                    ushort* __restrict__ W1T,
                                                    ushort* __restrict__ W2T,
                                                    float* __restrict__ Bqkv,
                                                    ushort* __restrict__ Xn) {
  const int id = blockIdx.x;
  const int t = threadIdx.x;
  if (id >= 12300) {   // LN1: rows 0..4095
    const int row = id - 12300;
    float4 v = reinterpret_cast<const float4*>(x + (size_t)row * CC)[t];
    float s  = v.x + v.y + v.z + v.w;
    float ss = v.x * v.x + v.y * v.y + v.z * v.z + v.w * v.w;
#pragma unroll
    for (int off = 32; off; off >>= 1) {
      s  += __shfl_down(s, off);
      ss += __shfl_down(ss, off);
    }
    __shared__ float red[16];
    const int wid = t >> 6, lane = t & 63;
    if (lane == 0) { red[wid] = s; red[8 + wid] = ss; }
    __syncthreads();
    if (t == 0) {
      red[0] = red[0] + red[1] + red[2] + red[3];
      red[8] = red[8] + red[9] + red[10] + red[11];
    }
    __syncthreads();
    const float mu   = red[0] * (1.0f / CC);
    const float var  = red[8] * (1.0f / CC) - mu * mu;
    const float rstd = rsqrtf(var + 1e-5f);
    float4 gg = reinterpret_cast<const float4*>(g1)[t];
    float4 bb = reinterpret_cast<const float4*>(b1v)[t];
    uint2 st;
    st.x = cvt_pk_bf16((v.x - mu) * rstd * gg.x + bb.x, (v.y - mu) * rstd * gg.y + bb.y);
    st.y = cvt_pk_bf16((v.z - mu) * rstd * gg.z + bb.z, (v.w - mu) * rstd * gg.w + bb.w);
    *reinterpret_cast<uint2*>(Xn + (size_t)row * CC + t * 4) = st;
    return;
  }
  if (id >= 12288) {   // bias concat: 12 blocks
    const int i = (id - 12288) * 256 + t;
    Bqkv[i] = (i < 1024) ? bq[i] : ((i < 2048) ? bk[i - 1024] : bv[i - 2048]);
    return;
  }
  const float* W; ushort* out; int Kd, Nd, bx, by, rowOff = 0;
  if (id < 4096) {
    const int which = id >> 10, sub = id & 1023;
    bx = sub & 31; by = sub >> 5; Kd = 1024; Nd = 1024;
    if (which == 0)      { W = Wq; out = WqkvT; rowOff = 0; }
    else if (which == 1) { W = Wk; out = WqkvT; rowOff = 1024; }
    else if (which == 2) { W = Wv; out = WqkvT; rowOff = 2048; }
    else                 { W = Wo; out = WoT; }
  } else if (id < 8192) {
    const int sub = id - 4096; bx = sub & 127; by = sub >> 7;
    W = W1; out = W1T; Kd = 1024; Nd = 4096;
  } else {
    const int sub = id - 8192; bx = sub & 31; by = sub >> 5;
    W = W2; out = W2T; Kd = 4096; Nd = 1024;
  }
  const int n0 = bx * 32, k0 = by * 32;
  __shared__ float Ts[32][33];
  {
    const int r = t >> 3, cb = (t & 7) * 4;
    float4 v = *reinterpret_cast<const float4*>(W + (size_t)(k0 + r) * Nd + n0 + cb);
    Ts[r][cb + 0] = v.x; Ts[r][cb + 1] = v.y; Ts[r][cb + 2] = v.z; Ts[r][cb + 3] = v.w;
  }
  __syncthreads();
  {
    const int nl = t >> 3, kb = (t & 7) * 4;
    uint2 st;
    st.x = cvt_pk_bf16(Ts[kb + 0][nl], Ts[kb + 1][nl]);
    st.y = cvt_pk_bf16(Ts[kb + 2][nl], Ts[kb + 3][nl]);
    *reinterpret_cast<uint2*>(out + (size_t)(rowOff + n0 + nl) * Kd + k0 + kb) = st;
  }
}

// ================= 256x256-tile 8-wave GEMM, counted-vmcnt pipeline =================
template <bool RELU, bool VOUT, bool PARTIAL>
__global__ __launch_bounds__(512, 2) void gemm_8w(const ushort* __restrict__ A,
                                                  const ushort* __restrict__ Bt,
                                                  const float* __restrict__ bias,
                                                  ushort* __restrict__ outp,
                                                  ushort* __restrict__ Vt,
                                                  ushort* __restrict__ P1,
                                                  ushort* __restrict__ P2,
                                                  ushort* __restrict__ P3,
                                                  int N, int K, int Kchunk) {
  __shared__ ushort lds[49152];   // 3 buffers x (A 16 KB + B 16 KB)
  const int t = threadIdx.x, lane = t & 63, w = t >> 6;
  const int g = lane >> 4, i16 = lane & 15;
  const int wr = w >> 2, wc = w & 3;            // 2 x 4 wave grid; wave C: 128x64
  const int nwg  = gridDim.x * gridDim.y;
  const int orig = blockIdx.y * gridDim.x + blockIdx.x;
  const int sw   = (orig & 7) * (nwg >> 3) + (orig >> 3);
  const int row0 = (sw / gridDim.x) * 256, col0 = (sw % gridDim.x) * 256;
  const int kstart = PARTIAL ? blockIdx.z * Kchunk : 0;
  const int NT = (PARTIAL ? Kchunk : K) >> 5;
  ushort* __restrict__ Out = outp;
  if (PARTIAL) Out = (blockIdx.z == 0) ? outp : (blockIdx.z == 1) ? P1
              : (blockIdx.z == 2) ? P2 : P3;

  const int c1 = t, c2 = t + 512;
  const int r1 = c1 >> 2, s1 = (c1 & 3) ^ ((r1 >> 1) & 3);
  const int r2 = c2 >> 2, s2 = (c2 & 3) ^ ((r2 >> 1) & 3);
  const ushort* aG1 = A + (size_t)(row0 + r1) * K + kstart + s1 * 8;
  const ushort* aG2 = A + (size_t)(row0 + r2) * K + kstart + s2 * 8;
  const ushort* bG1 = Bt + (size_t)(col0 + r1) * K + kstart + s1 * 8;
  const ushort* bG2 = Bt + (size_t)(col0 + r2) * K + kstart + s2 * 8;

  int aoff[8], boff[4];
#pragma unroll
  for (int mf = 0; mf < 8; ++mf) {
    const int R = wr * 128 + mf * 16 + i16;
    aoff[mf] = R * 64 + ((g ^ ((R >> 1) & 3)) << 4);
  }
#pragma unroll
  for (int nf = 0; nf < 4; ++nf) {
    const int Cn = wc * 64 + nf * 16 + i16;
    boff[nf] = Cn * 64 + ((g ^ ((Cn >> 1) & 3)) << 4);
  }

  f32x4 acc[8][4] = {};

  auto STAGE = [&](int bi, int kt) {
    char* aB = (char*)lds + bi * 32768;
    char* bB = aB + 16384;
    const int ko = kt * 32;
    __builtin_amdgcn_global_load_lds(AS1C(aG1 + ko), AS3(aB + w * 1024), 16, 0, 0);
    __builtin_amdgcn_global_load_lds(AS1C(aG2 + ko), AS3(aB + 8192 + w * 1024), 16, 0, 0);
    __builtin_amdgcn_global_load_lds(AS1C(bG1 + ko), AS3(bB + w * 1024), 16, 0, 0);
    __builtin_amdgcn_global_load_lds(AS1C(bG2 + ko), AS3(bB + 8192 + w * 1024), 16, 0, 0);
  };

  STAGE(0, 0);
  if (NT > 1) STAGE(1, 1);

  for (int kt = 0; kt < NT; ++kt) {
    const int cur = kt % 3;
    if (kt + 2 < NT) STAGE((kt + 2) % 3, kt + 2);
    if (kt + 2 < NT)      asm volatile("s_waitcnt vmcnt(8)" ::: "memory");
    else if (kt + 1 < NT) asm volatile("s_waitcnt vmcnt(4)" ::: "memory");
    else                  asm volatile("s_waitcnt vmcnt(0)" ::: "memory");
    asm volatile("s_barrier" ::: "memory");
    __builtin_amdgcn_sched_barrier(0);

    const char* aB = (const char*)lds + cur * 32768;
    const char* bB = aB + 16384;
    bf16x8 b4[4], a4[4];
#pragma unroll
    for (int nf = 0; nf < 4; ++nf) b4[nf] = *reinterpret_cast<const bf16x8*>(bB + boff[nf]);
#pragma unroll
    for (int mf = 0; mf < 4; ++mf) a4[mf] = *reinterpret_cast<const bf16x8*>(aB + aoff[mf]);
    __builtin_amdgcn_s_setprio(1);
#pragma unroll
    for (int mf = 0; mf < 4; ++mf)
#pragma unroll
      for (int nf = 0; nf < 4; ++nf)
        acc[mf][nf] = __builtin_amdgcn_mfma_f32_16x16x32_bf16(a4[mf], b4[nf], acc[mf][nf], 0, 0, 0);
    __builtin_amdgcn_s_setprio(0);
    asm volatile("s_barrier" ::: "memory");
    __builtin_amdgcn_sched_barrier(0);
#pragma unroll
    for (int mf = 0; mf < 4; ++mf) a4[mf] = *reinterpret_cast<const bf16x8*>(aB + aoff[mf + 4]);
    __builtin_amdgcn_s_setprio(1);
#pragma unroll
    for (int mf = 0; mf < 4; ++mf)
#pragma unroll
      for (int nf = 0; nf < 4; ++nf)
        acc[mf + 4][nf] = __builtin_amdgcn_mfma_f32_16x16x32_bf16(a4[mf], b4[nf], acc[mf + 4][nf], 0, 0, 0);
    __builtin_amdgcn_s_setprio(0);
    asm volatile("s_barrier" ::: "memory");
    __builtin_amdgcn_sched_barrier(0);
  }

  const int qcol0 = col0 + wc * 64;

  if (VOUT && qcol0 >= 2048) {
#pragma unroll
    for (int nf = 0; nf < 4; ++nf) {
      const int ncol = qcol0 + nf * 16 + i16;
      const float bb = bias[ncol];
      const int d = ncol - 2048;
      const int hh = d >> 6, dd = d & 63;
#pragma unroll
      for (int mf = 0; mf < 8; ++mf) {
        const int mrow = row0 + wr * 128 + mf * 16 + 4 * g;
        const int bb_ = mrow >> 11, tok = mrow & 2047;
        uint2 st;
        st.x = cvt_pk_bf16(acc[mf][nf][0] + bb, acc[mf][nf][1] + bb);
        st.y = cvt_pk_bf16(acc[mf][nf][2] + bb, acc[mf][nf][3] + bb);
        *reinterpret_cast<uint2*>(Vt + (size_t)((bb_ * 16 + hh) * 64 + dd) * TT + tok) = st;
      }
    }
    return;
  }

  float* Lf = (float*)((char*)lds + w * 4096);
  const int rr2 = lane >> 2, q = lane & 3;
#pragma unroll
  for (int mf = 0; mf < 8; ++mf) {
#pragma unroll
    for (int nf = 0; nf < 4; ++nf)
#pragma unroll
      for (int r = 0; r < 4; ++r) {
        const int row = 4 * g + r;
        Lf[row * 64 + ((16 * nf + i16) ^ ((row & 7) << 2))] = acc[mf][nf][r];
      }
    asm volatile("s_waitcnt lgkmcnt(0)" ::: "memory");
    uint32_t u[8];
#pragma unroll
    for (int j = 0; j < 4; ++j) {
      f32x4 v = *reinterpret_cast<const f32x4*>(Lf + rr2 * 64 + ((q * 16 + 4 * j) ^ ((rr2 & 7) << 2)));
      float e0 = v[0], e1 = v[1], e2 = v[2], e3 = v[3];
      if (!PARTIAL) {
        const float4 b4 = *reinterpret_cast<const float4*>(bias + qcol0 + q * 16 + 4 * j);
        e0 += b4.x; e1 += b4.y; e2 += b4.z; e3 += b4.w;
        if (RELU) {
          e0 = fmaxf(e0, 0.f); e1 = fmaxf(e1, 0.f);
          e2 = fmaxf(e2, 0.f); e3 = fmaxf(e3, 0.f);
        }
      }
      u[2 * j + 0] = cvt_pk_bf16(e0, e1);
      u[2 * j + 1] = cvt_pk_bf16(e2, e3);
    }
    const int mrow = row0 + wr * 128 + mf * 16 + rr2;
    ushort* orow = Out + (size_t)mrow * N + qcol0 + q * 16;
    uint4 s0; s0.x = u[0]; s0.y = u[1]; s0.z = u[2]; s0.w = u[3];
    uint4 s1; s1.x = u[4]; s1.y = u[5]; s1.z = u[6]; s1.w = u[7];
    *reinterpret_cast<uint4*>(orow) = s0;
    *reinterpret_cast<uint4*>(orow + 8) = s1;
    asm volatile("s_waitcnt lgkmcnt(0)" ::: "memory");
  }
}

// ---------------- split-K (4-way) 128-tile bf16 GEMM (kept for Wo) ----------------
__global__ __launch_bounds__(256) void gemm_splitk(const ushort* __restrict__ A,
                                                   const ushort* __restrict__ Bt,
                                                   ushort* __restrict__ P0,
                                                   ushort* __restrict__ P1,
                                                   ushort* __restrict__ P2,
                                                   ushort* __restrict__ P3,
                                                   int N, int K, int Kchunk) {
  __shared__ ushort Smem[8192];
  ushort* Asm = Smem;
  ushort* Bsm = Smem + 4096;
  const int t = threadIdx.x;
  const int lane = t & 63, w = t >> 6;
  const int g = lane >> 4, i16 = lane & 15;
  const int wrow = w >> 1, wcol = w & 1;
  const int nwg  = gridDim.x * gridDim.y;
  const int orig = blockIdx.y * gridDim.x + blockIdx.x;
  const int sw   = (orig & 7) * (nwg >> 3) + (orig >> 3);
  const int row0 = (sw / gridDim.x) * 128, col0 = (sw % gridDim.x) * 128;
  const int kstart = blockIdx.z * Kchunk;
  ushort* __restrict__ P = (blockIdx.z == 0) ? P0 : (blockIdx.z == 1) ? P1
                          : (blockIdx.z == 2) ? P2 : P3;

  f32x4 acc[4][4] = {};

  const int srow = t >> 2, sc = (t & 3) * 8;
  const ushort* aS1 = A + (size_t)(row0 + srow) * K + sc;
  const ushort* aS2 = A + (size_t)(row0 + 64 + srow) * K + sc;
  const ushort* bS1 = Bt + (size_t)(col0 + srow) * K + sc;
  const ushort* bS2 = Bt + (size_t)(col0 + 64 + srow) * K + sc;
  char* aL1 = (char*)Asm + w * 1024;
  char* aL2 = (char*)Asm + 4096 + w * 1024;
  char* bL1 = (char*)Bsm + w * 1024;
  char* bL2 = (char*)Bsm + 4096 + w * 1024;

  for (int k0 = kstart; k0 < kstart + Kchunk; k0 += 32) {
    __syncthreads();
    __builtin_amdgcn_global_load_lds(AS1C(aS1 + k0), AS3(aL1), 16, 0, 0);
    __builtin_amdgcn_global_load_lds(AS1C(aS2 + k0), AS3(aL2), 16, 0, 0);
    __builtin_amdgcn_global_load_lds(AS1C(bS1 + k0), AS3(bL1), 16, 0, 0);
    __builtin_amdgcn_global_load_lds(AS1C(bS2 + k0), AS3(bL2), 16, 0, 0);
    __syncthreads();

    bf16x8 a4[4], b4[4];
#pragma unroll
    for (int mf = 0; mf < 4; ++mf) {
      const int r = wrow * 64 + mf * 16 + i16;
      a4[mf] = *reinterpret_cast<const bf16x8*>((const char*)Asm + r * 64 + g * 16);
    }
#pragma unroll
    for (int nf = 0; nf < 4; ++nf) {
      const int c = wcol * 64 + nf * 16 + i16;
      b4[nf] = *reinterpret_cast<const bf16x8*>((const char*)Bsm + c * 64 + g * 16);
    }
#pragma unroll
    for (int mf = 0; mf < 4; ++mf)
#pragma unroll
      for (int nf = 0; nf < 4; ++nf)
        acc[mf][nf] = __builtin_amdgcn_mfma_f32_16x16x32_bf16(a4[mf], b4[nf], acc[mf][nf], 0, 0, 0);
  }

  __syncthreads();

  float* Lf = (float*)((char*)Smem + w * 4096);
  const int qcol0 = col0 + wcol * 64;
  const int rr = lane >> 2, q = lane & 3;
#pragma unroll
  for (int mf = 0; mf < 4; ++mf) {
#pragma unroll
    for (int nf = 0; nf < 4; ++nf)
#pragma unroll
      for (int r = 0; r < 4; ++r) {
        const int row = 4 * g + r;
        Lf[row * 64 + ((16 * nf + i16) ^ ((row & 7) << 2))] = acc[mf][nf][r];
      }
    asm volatile("s_waitcnt lgkmcnt(0)" ::: "memory");
    uint32_t u[8];
#pragma unroll
    for (int j = 0; j < 4; ++j) {
      f32x4 v = *reinterpret_cast<const f32x4*>(Lf + rr * 64 + ((q * 16 + 4 * j) ^ ((rr & 7) << 2)));
      u[2 * j + 0] = cvt_pk_bf16(v[0], v[1]);
      u[2 * j + 1] = cvt_pk_bf16(v[2], v[3]);
    }
    const int mrow = row0 + wrow * 64 + mf * 16 + rr;
    ushort* orow = P + (size_t)mrow * N + qcol0 + q * 16;
    uint4 s0; s0.x = u[0]; s0.y = u[1]; s0.z = u[2]; s0.w = u[3];
    uint4 s1; s1.x = u[4]; s1.y = u[5]; s1.z = u[6]; s1.w = u[7];
    *reinterpret_cast<uint4*>(orow) = s0;
    *reinterpret_cast<uint4*>(orow + 8) = s1;
    asm volatile("s_waitcnt lgkmcnt(0)" ::: "memory");
  }
}

__device__ inline float bfsum4(uint32_t a, uint32_t b, uint32_t c, uint32_t d, bool hi) {
  if (hi) return bfbits2f(a & 0xffff0000u) + bfbits2f(b & 0xffff0000u) +
                 bfbits2f(c & 0xffff0000u) + bfbits2f(d & 0xffff0000u);
  return bfbits2f(a << 16) + bfbits2f(b << 16) + bfbits2f(c << 16) + bfbits2f(d << 16);
}

// ---------------- Wo reduce (4 partials) + residual + LN2 fused ----------------
__global__ __launch_bounds__(256) void reduce_wo_ln(const ushort* __restrict__ P0,
                                                    const ushort* __restrict__ P1,
                                                    const ushort* __restrict__ P2,
                                                    const ushort* __restrict__ P3,
                                                    const float* __restrict__ x,
                                                    const float* __restrict__ bo,
                                                    const float* __restrict__ g,
                                                    const float* __restrict__ b,
                                                    float* __restrict__ X1f,
                                                    ushort* __restrict__ Xn) {
  const int row = blockIdx.x, t = threadIdx.x;
  const size_t off = (size_t)row * CC + t * 4;
  float4 v  = *reinterpret_cast<const float4*>(x + off);
  const uint2 q0 = *reinterpret_cast<const uint2*>(P0 + off);
  const uint2 q1 = *reinterpret_cast<const uint2*>(P1 + off);
  const uint2 q2 = *reinterpret_cast<const uint2*>(P2 + off);
  const uint2 q3 = *reinterpret_cast<const uint2*>(P3 + off);
  float4 bb = reinterpret_cast<const float4*>(bo)[t];
  v.x += bfsum4(q0.x, q1.x, q2.x, q3.x, false) + bb.x;
  v.y += bfsum4(q0.x, q1.x, q2.x, q3.x, true)  + bb.y;
  v.z += bfsum4(q0.y, q1.y, q2.y, q3.y, false) + bb.z;
  v.w += bfsum4(q0.y, q1.y, q2.y, q3.y, true)  + bb.w;
  *reinterpret_cast<float4*>(X1f + off) = v;

  float s  = v.x + v.y + v.z + v.w;
  float ss = v.x * v.x + v.y * v.y + v.z * v.z + v.w * v.w;
#pragma unroll
  for (int o = 32; o; o >>= 1) {
    s  += __shfl_down(s, o);
    ss += __shfl_down(ss, o);
  }
  __shared__ float red[16];
  const int wid = t >> 6, lane = t & 63;
  if (lane == 0) { red[wid] = s; red[8 + wid] = ss; }
  __syncthreads();
  if (t == 0) {
    red[0] = red[0] + red[1] + red[2] + red[3];
    red[8] = red[8] + red[9] + red[10] + red[11];
  }
  __syncthreads();
  const float mu   = red[0] * (1.0f / CC);
  const float var  = red[8] * (1.0f / CC) - mu * mu;
  const float rstd = rsqrtf(var + 1e-5f);
  float4 gg = reinterpret_cast<const float4*>(g)[t];
  float4 lb = reinterpret_cast<const float4*>(b)[t];
  uint2 st;
  st.x = cvt_pk_bf16((v.x - mu) * rstd * gg.x + lb.x, (v.y - mu) * rstd * gg.y + lb.y);
  st.y = cvt_pk_bf16((v.z - mu) * rstd * gg.z + lb.z, (v.w - mu) * rstd * gg.w + lb.w);
  *reinterpret_cast<uint2*>(Xn + off) = st;
}

// ---------------- FC2 reduce (4 partials) + bias + residual -> final out ----------------
__global__ __launch_bounds__(256) void reduce_fc2(const ushort* __restrict__ P0,
                                                  const ushort* __restrict__ P1,
                                                  const ushort* __restrict__ P2,
                                                  const ushort* __restrict__ P3,
                                                  const float* __restrict__ X1,
                                                  const float* __restrict__ b2,
                                                  float* __restrict__ out) {
  const int row = blockIdx.x, t = threadIdx.x;
  const size_t off = (size_t)row * CC + t * 4;
  float4 v  = *reinterpret_cast<const float4*>(X1 + off);
  const uint2 q0 = *reinterpret_cast<const uint2*>(P0 + off);
  const uint2 q1 = *reinterpret_cast<const uint2*>(P1 + off);
  const uint2 q2 = *reinterpret_cast<const uint2*>(P2 + off);
  const uint2 q3 = *reinterpret_cast<const uint2*>(P3 + off);
  float4 bb = reinterpret_cast<const float4*>(b2)[t];
  v.x += bfsum4(q0.x, q1.x, q2.x, q3.x, false) + bb.x;
  v.y += bfsum4(q0.x, q1.x, q2.x, q3.x, true)  + bb.y;
  v.z += bfsum4(q0.y, q1.y, q2.y, q3.y, false) + bb.z;
  v.w += bfsum4(q0.y, q1.y, q2.y, q3.y, true)  + bb.w;
  *reinterpret_cast<float4*>(out + off) = v;
}

// ======== MFMA flash attention: QBLK=256 (8 waves x 32 q), dbuf K/V, counted vmcnt ========
// Grid 512 blocks = exactly 2/CU. Per tile: STAGE(next) -> vmcnt(2) -> s_barrier ->
// {QK, softmax, P-strip, PV} x 2 query-halves -> s_barrier. Never vmcnt(0) until tail.
__global__ __launch_bounds__(512, 4) void attn_partial(const ushort* __restrict__ qkv,
                                                       const ushort* __restrict__ Vt,
                                                       ushort* __restrict__ O0,
                                                       ushort* __restrict__ O1,
                                                       float2* __restrict__ ml) {
  __shared__ ushort Ks[2][4096];
  __shared__ ushort Vs[2][4096];
  __shared__ uint32_t Ps[8][16][36];   // per-wave P strip, shared sequentially by 2 q-halves
  const int t = threadIdx.x, lane = t & 63, w = t >> 6;   // w in 0..7
  const int g = lane >> 4, iq = lane & 15;
  const int flat = blockIdx.x;
  const int work = (flat & 7) * 64 + (flat >> 3);   // XCD-chunked remap (bijective, 512)
  const int bh = work >> 4;
  const int rem = work & 15;
  const int z = rem >> 3;
  const int qt = rem & 7;
  const int b = bh >> 4, h = bh & 15;
  ushort* __restrict__ Obuf = z ? O1 : O0;

  // Q fragments for both query-halves; scale = 1/8 * log2(e) (exp2-domain softmax)
  bf16x8 qfrag[2][2];
#pragma unroll
  for (int qh = 0; qh < 2; ++qh) {
    const ushort* qrow = qkv + (size_t)(b * TT + qt * 256 + w * 32 + qh * 16 + iq) * NQKV + h * 64;
    const float qs = 0.125f * 1.44269504f;
#pragma unroll
    for (int kk = 0; kk < 2; ++kk) {
      uint4 raw = *reinterpret_cast<const uint4*>(qrow + kk * 32 + g * 8);
      uint32_t rr[4] = {raw.x, raw.y, raw.z, raw.w};
      U84 tmp;
#pragma unroll
      for (int c = 0; c < 4; ++c) {
        float lo = bfbits2f(rr[c] << 16) * qs;
        float hi = bfbits2f(rr[c] & 0xffff0000u) * qs;
        tmp.u[c] = cvt_pk_bf16(lo, hi);
      }
      qfrag[qh][kk] = tmp.v;
    }
  }

  // staging: 512 threads x 16B = one full 64x64 bf16 tile per matrix per call
  const int sr1 = t >> 3, sc1 = t & 7;
  const int csw = (sc1 ^ (sr1 & 7)) * 8;         // pre-swizzled global col (linear LDS dest)
  const ushort* kbase = qkv + 1024 + h * 64;
  const ushort* vbase = Vt + (size_t)(bh * 64) * TT;

  auto STAGE = [&](int bi, int kt) {
    const size_t tok = (size_t)(b * TT + kt * 64);
    __builtin_amdgcn_global_load_lds(AS1C(kbase + (tok + sr1) * NQKV + csw),
                                     AS3((char*)&Ks[bi][0] + w * 1024), 16, 0, 0);
    __builtin_amdgcn_global_load_lds(AS1C(vbase + (size_t)sr1 * TT + kt * 64 + csw),
                                     AS3((char*)&Vs[bi][0] + w * 1024), 16, 0, 0);
  };

  uint32_t (*pw)[36] = Ps[w];
  const int wsw = (iq & 8) << 1;
  const int xsb = wsw << 2;
  const char* prow = (const char*)&pw[iq][0];

  float mrun[2] = {-3e38f, -3e38f}, lrun[2] = {0.f, 0.f};
  f32x4 ot[2][4] = {};

  const int kt0 = z * 16, ktE = kt0 + 16;
  STAGE(0, kt0);

  for (int kt = kt0; kt < ktE; ++kt) {
    const int cur = kt & 1;
    if (kt + 1 < ktE) {
      STAGE(cur ^ 1, kt + 1);   // buf cur^1's readers retired at iter kt-1's end barrier
      asm volatile("s_waitcnt vmcnt(2)" ::: "memory");   // tile kt landed; next stays in flight
    } else {
      asm volatile("s_waitcnt vmcnt(0)" ::: "memory");
    }
    asm volatile("s_barrier" ::: "memory");
    __builtin_amdgcn_sched_barrier(0);
    const char* Kc = (const char*)&Ks[cur][0];
    const char* Vc = (const char*)&Vs[cur][0];

#pragma unroll
    for (int qh = 0; qh < 2; ++qh) {
      // S^T = K @ Q^T
      f32x4 sfr[4] = {};
      __builtin_amdgcn_s_setprio(1);
#pragma unroll
      for (int kk = 0; kk < 2; ++kk)
#pragma unroll
        for (int jf = 0; jf < 4; ++jf) {
          const int row = iq + 16 * jf;
          const int off = row * 128 + ((kk * 64 + g * 16) ^ ((row & 7) << 4));
          bf16x8 a = *reinterpret_cast<const bf16x8*>(Kc + off);
          sfr[jf] = __builtin_amdgcn_mfma_f32_16x16x32_bf16(a, qfrag[qh][kk], sfr[jf], 0, 0, 0);
        }
      __builtin_amdgcn_s_setprio(0);

      // online softmax (exp2 domain), defer-max THR=8; lsum stays lane-partial
      float tm0 = fmaxf(fmaxf(sfr[0][0], sfr[0][1]), fmaxf(sfr[0][2], sfr[0][3]));
      float tm1 = fmaxf(fmaxf(sfr[1][0], sfr[1][1]), fmaxf(sfr[1][2], sfr[1][3]));
      float tm2 = fmaxf(fmaxf(sfr[2][0], sfr[2][1]), fmaxf(sfr[2][2], sfr[2][3]));
      float tm3 = fmaxf(fmaxf(sfr[3][0], sfr[3][1]), fmaxf(sfr[3][2], sfr[3][3]));
      float tmax = fmaxf(fmaxf(tm0, tm1), fmaxf(tm2, tm3));
      tmax = fmaxf(tmax, __shfl_xor(tmax, 16, 64));
      tmax = fmaxf(tmax, __shfl_xor(tmax, 32, 64));

      if (!__all(tmax <= mrun[qh] + 8.f)) {
        const float mnew  = fmaxf(mrun[qh], tmax);
        const float alpha = exp2_fast(mrun[qh] - mnew);
        lrun[qh] *= alpha;
#pragma unroll
        for (int df = 0; df < 4; ++df)
#pragma unroll
          for (int r = 0; r < 4; ++r) ot[qh][df][r] *= alpha;
        mrun[qh] = mnew;
      }

#pragma unroll
      for (int f = 0; f < 4; ++f) {
        float p0 = exp2_fast(sfr[f][0] - mrun[qh]);
        float p1 = exp2_fast(sfr[f][1] - mrun[qh]);
        float p2 = exp2_fast(sfr[f][2] - mrun[qh]);
        float p3 = exp2_fast(sfr[f][3] - mrun[qh]);
        lrun[qh] += (p0 + p1) + (p2 + p3);
        pw[iq][(8 * f + 2 * g + 0) ^ wsw] = cvt_pk_bf16(p0, p1);
        pw[iq][(8 * f + 2 * g + 1) ^ wsw] = cvt_pk_bf16(p2, p3);
      }
      asm volatile("s_waitcnt lgkmcnt(0)" ::: "memory");   // wave-local strip visible

      // PV: O^T = Vt @ P^T
      __builtin_amdgcn_s_setprio(1);
#pragma unroll
      for (int kk = 0; kk < 2; ++kk) {
        bf16x8 pb = *reinterpret_cast<const bf16x8*>(prow + ((kk * 64 + g * 16) ^ xsb));
#pragma unroll
        for (int df = 0; df < 4; ++df) {
          const int row = iq + 16 * df;
          const int off = row * 128 + ((kk * 64 + g * 16) ^ ((row & 7) << 4));
          bf16x8 a = *reinterpret_cast<const bf16x8*>(Vc + off);
          ot[qh][df] = __builtin_amdgcn_mfma_f32_16x16x32_bf16(a, pb, ot[qh][df], 0, 0, 0);
        }
      }
      __builtin_amdgcn_s_setprio(0);
    }

    asm volatile("s_barrier" ::: "memory");   // all reads of buf cur retired
    __builtin_amdgcn_sched_barrier(0);
  }

  // epilogue: finish deferred lsum reduce, write per-split partials + (m,l)
#pragma unroll
  for (int qh = 0; qh < 2; ++qh) {
    float l = lrun[qh];
    l += __shfl_xor(l, 16, 64);
    l += __shfl_xor(l, 32, 64);
    const int grow = b * TT + qt * 256 + w * 32 + qh * 16 + iq;
    const float inv = 1.f / l;
    ushort* orow = Obuf + (size_t)grow * CC + h * 64;
#pragma unroll
    for (int df = 0; df < 4; ++df) {
      uint2 st;
      st.x = cvt_pk_bf16(ot[qh][df][0] * inv, ot[qh][df][1] * inv);
      st.y = cvt_pk_bf16(ot[qh][df][2] * inv, ot[qh][df][3] * inv);
      *reinterpret_cast<uint2*>(orow + df * 16 + g * 4) = st;
    }
    if (g == 0) ml[(size_t)z * (MM * 16) + (size_t)grow * 16 + h] = make_float2(mrun[qh], l);
  }
}

// ---------------- combine the two KV-split partials -> Attn (bf16) ----------------
__global__ __launch_bounds__(256) void attn_combine(const ushort* __restrict__ O0,
                                                    const ushort* __restrict__ O1,
                                                    const float2* __restrict__ ml,
                                                    ushort* __restrict__ attnb) {
  const int row = blockIdx.x, t = threadIdx.x;
  const int h = t >> 4;
  const float2 a = ml[(size_t)row * 16 + h];
  const float2 c = ml[(size_t)MM * 16 + (size_t)row * 16 + h];
  const float m  = fmaxf(a.x, c.x);
  const float w0 = exp2_fast(a.x - m) * a.y;
  const float w1 = exp2_fast(c.x - m) * c.y;
  const float inv = 1.f / (w0 + w1);
  const float s0 = w0 * inv, s1 = w1 * inv;
  const size_t off = (size_t)row * CC + t * 4;
  const uint2 r0 = *reinterpret_cast<const uint2*>(O0 + off);
  const uint2 r1 = *reinterpret_cast<const uint2*>(O1 + off);
  const float o0 = bfbits2f(r0.x << 16)         * s0 + bfbits2f(r1.x << 16)         * s1;
  const float o1 = bfbits2f(r0.x & 0xffff0000u) * s0 + bfbits2f(r1.x & 0xffff0000u) * s1;
  const float o2 = bfbits2f(r0.y << 16)         * s0 + bfbits2f(r1.y << 16)         * s1;
  const float o3 = bfbits2f(r0.y & 0xffff0000u) * s0 + bfbits2f(r1.y & 0xffff0000u) * s1;
  uint2 st;
  st.x = cvt_pk_bf16(o0, o1);
  st.y = cvt_pk_bf16(o2, o3);
  *reinterpret_cast<uint2*>(attnb + off) = st;
}

// --------------------------------- launcher -------------------------------------
extern "C" void kernel_launch(void* const* d_in, const int* in_sizes, int n_in,
                              void* d_out, int out_size, void* d_ws, size_t ws_size,
                              hipStream_t stream) {
  const float* x     = (const float*)d_in[0];
  const float* ln1_g = (const float*)d_in[1];
  const float* ln1_b = (const float*)d_in[2];
  const float* ln2_g = (const float*)d_in[3];
  const float* ln2_b = (const float*)d_in[4];
  const float* Wq = (const float*)d_in[5];
  const float* bq = (const float*)d_in[6];
  const float* Wk = (const float*)d_in[7];
  const float* bk = (const float*)d_in[8];
  const float* Wv = (const float*)d_in[9];
  const float* bv = (const float*)d_in[10];
  const float* Wo = (const float*)d_in[11];
  const float* bo = (const float*)d_in[12];
  const float* W1 = (const float*)d_in[13];
  const float* b1 = (const float*)d_in[14];
  const float* W2 = (const float*)d_in[15];
  const float* b2 = (const float*)d_in[16];
  float* out = (float*)d_out;
  char* ws = (char*)d_ws;

  // workspace layout (92.3 MB total, unchanged footprint)
  ushort* WqkvT = (ushort*)(ws + 0);          // 3072x1024 bf16 (6 MB)
  ushort* WoT   = (ushort*)(ws + 6291456);    // 1024x1024 bf16 (2 MB)
  ushort* W1T   = (ushort*)(ws + 8388608);    // 4096x1024 bf16 (8 MB)
  ushort* W2T   = (ushort*)(ws + 16777216);   // 1024x4096 bf16 (8 MB)
  float*  Bqkv  = (float*) (ws + 25165824);   // 3072 f32
  ushort* Xn    = (ushort*)(ws + 25178112);   // 4096x1024 bf16 (8 MB)
  ushort* Attn  = (ushort*)(ws + 33566720);   // 4096x1024 bf16 (8 MB)
  float*  X1f   = (float*) (ws + 41955328);   // 4096x1024 f32 (16 MB)
  ushort* Qkv   = (ushort*)(ws + 58732544);   // 4096x3072 bf16 (24 MB)
  ushort* Vtb   = (ushort*)(ws + 83898368);   // 2048x2048 bf16 (8 MB)
  ushort* Hid   = (ushort*)(ws + 58732544);   // 4096x4096 bf16 (reuses Qkv+Vtb)
  ushort* OP0   = (ushort*)(ws + 41955328);   // attn partials (X1f region, dead here)
  ushort* OP1   = (ushort*)(ws + 50343936);
  float2* mlbuf = (float2*)(ws + 0);          // 1 MB (WqkvT dead after QKV gemm)
  ushort* WoP0  = (ushort*)(ws + 58732544);   // Wo split-K4 partials (dead Qkv+Vtb)
  ushort* WoP1  = (ushort*)(ws + 67121152);
  ushort* WoP2  = (ushort*)(ws + 75509760);
  ushort* WoP3  = (ushort*)(ws + 83898368);
  ushort* F2P0  = (ushort*)(ws + 0);          // FC2 split-K4 partials (dead regions)
  ushort* F2P1  = (ushort*)(ws + 8388608);
  ushort* F2P2  = (ushort*)(ws + 25178112);
  ushort* F2P3  = (ushort*)(ws + 33566720);

  const dim3 blk(256);

  prep_weights<<<dim3(16396), blk, 0, stream>>>(Wq, Wk, Wv, Wo, W1, W2, bq, bk, bv,
                                                x, ln1_g, ln1_b,
                                                WqkvT, WoT, W1T, W2T, Bqkv, Xn);
  // QKV: 256^2 8-wave pipelined GEMM; V columns written transposed to Vtb
  gemm_8w<false, true, false><<<dim3(12, 16), dim3(512), 0, stream>>>(
      Xn, WqkvT, Bqkv, Qkv, Vtb, nullptr, nullptr, nullptr, NQKV, 1024, 0);
  attn_partial<<<dim3(512), dim3(512), 0, stream>>>(Qkv, Vtb, OP0, OP1, mlbuf);
  attn_combine<<<dim3(MM), blk, 0, stream>>>(OP0, OP1, mlbuf, Attn);
  gemm_splitk<<<dim3(8, 32, 4), blk, 0, stream>>>(Attn, WoT, WoP0, WoP1, WoP2, WoP3, 1024, 1024, 256);
  reduce_wo_ln<<<dim3(MM), blk, 0, stream>>>(WoP0, WoP1, WoP2, WoP3, x, bo, ln2_g, ln2_b, X1f, Xn);
  // FC1: 256^2 8-wave pipelined GEMM + ReLU
  gemm_8w<true, false, false><<<dim3(16, 16), dim3(512), 0, stream>>>(
      Xn, W1T, b1, Hid, nullptr, nullptr, nullptr, nullptr, HIDN, 1024, 0);
  // FC2: 256^2 8-wave pipelined GEMM, split-K4, bf16 partials
  gemm_8w<false, false, true><<<dim3(4, 16, 4), dim3(512), 0, stream>>>(
      Hid, W2T, nullptr, F2P0, nullptr, F2P1, F2P2, F2P3, 1024, 4096, 1024);
  reduce_fc2<<<dim3(MM), blk, 0, stream>>>(F2P0, F2P1, F2P2, F2P3, X1f, b2, out);
}